// Round 1
// baseline (2476.113 us; speedup 1.0000x reference)
//
#include <hip/hip_runtime.h>
#include <hip/hip_bf16.h>

#define LEAKY(v) ((v) >= 0.f ? (v) : 0.01f * (v))

// ---------------------------------------------------------------------------
// prep + exact AdaptiveAvgPool1d:
// P[n,i,k] = mean_{m<16} X[n, (k&3)*16+m, i>>4, (i&15)*64 + (k>>2)]
// X layout (N,C,T,V) = (4,64,64,1024)
// ---------------------------------------------------------------------------
__global__ __launch_bounds__(256) void prep_pool(const float* __restrict__ X,
                                                 float* __restrict__ P) {
  const int i = blockIdx.x;   // 0..1023 (v index of output)
  const int n = blockIdx.y;   // 0..3
  const int t = i >> 4;
  const int vvb = (i & 15) * 64;
  __shared__ float tile[64][65];  // [c][vv']
  const int tid = threadIdx.x;
  const long base = (((long)n * 64) * 64 + t) * 1024 + vvb;  // X[n,0,t,vvb]
#pragma unroll
  for (int it = 0; it < 16; ++it) {
    int idx = tid + it * 256;
    int c = idx >> 6, w = idx & 63;
    tile[c][w] = X[base + (long)c * 64 * 1024 + w];
  }
  __syncthreads();
  const int k = tid;
  const int w = k >> 2, cb = (k & 3) * 16;
  float s = 0.f;
#pragma unroll
  for (int m = 0; m < 16; ++m) s += tile[cb + m][w];
  P[((long)n * 1024 + i) * 256 + k] = s * (1.f / 16.f);
}

// ---------------------------------------------------------------------------
// Generic fp32 tiled GEMM: C = act(alpha * op(A) @ op(B) + bias)
// BM=BN=64, BK=16, 256 threads, 4x4 per thread.
// All M,N multiples of 64; K multiple of 16 (true for every call here).
// Batch offset: ptr + (b/bdiv)*s?o + (b%bdiv)*s?i
// ---------------------------------------------------------------------------
template <bool TA, bool TB, int ACT>
__global__ __launch_bounds__(256) void gemm_f32(
    const float* __restrict__ A, const float* __restrict__ B,
    float* __restrict__ C, const float* __restrict__ bias,
    int M, int N, int K, int lda, int ldb, int ldc,
    int bdiv, long sAo, long sAi, long sBo, long sBi, long sCo, long sCi,
    float alpha) {
  const int b = blockIdx.z;
  const int bo = b / bdiv, bi = b - bo * bdiv;
  const float* Ab = A + (long)bo * sAo + (long)bi * sAi;
  const float* Bb = B + (long)bo * sBo + (long)bi * sBi;
  float* Cb = C + (long)bo * sCo + (long)bi * sCi;
  const int m0 = blockIdx.y * 64, n0 = blockIdx.x * 64;
  const int tid = threadIdx.x;
  __shared__ float As[16][68];
  __shared__ float Bs[16][68];
  float acc[4][4] = {{0.f}};
  const int row4 = (tid >> 4) * 4;
  const int col4 = (tid & 15) * 4;
  for (int k0 = 0; k0 < K; k0 += 16) {
    __syncthreads();
    if (!TA) {
      const int m = tid >> 2, kq = (tid & 3) * 4;
      const float4 v = *(const float4*)&Ab[(long)(m0 + m) * lda + k0 + kq];
      As[kq + 0][m] = v.x; As[kq + 1][m] = v.y;
      As[kq + 2][m] = v.z; As[kq + 3][m] = v.w;
    } else {
      const int k = tid >> 4, mq = (tid & 15) * 4;
      const float4 v = *(const float4*)&Ab[(long)(k0 + k) * lda + m0 + mq];
      *(float4*)&As[k][mq] = v;
    }
    if (!TB) {
      const int k = tid >> 4, nq = (tid & 15) * 4;
      const float4 v = *(const float4*)&Bb[(long)(k0 + k) * ldb + n0 + nq];
      *(float4*)&Bs[k][nq] = v;
    } else {
      const int nn = tid >> 2, kq = (tid & 3) * 4;
      const float4 v = *(const float4*)&Bb[(long)(n0 + nn) * ldb + k0 + kq];
      Bs[kq + 0][nn] = v.x; Bs[kq + 1][nn] = v.y;
      Bs[kq + 2][nn] = v.z; Bs[kq + 3][nn] = v.w;
    }
    __syncthreads();
#pragma unroll
    for (int k = 0; k < 16; ++k) {
      const float4 av = *(const float4*)&As[k][row4];
      const float4 bv = *(const float4*)&Bs[k][col4];
      const float a[4] = {av.x, av.y, av.z, av.w};
      const float bb[4] = {bv.x, bv.y, bv.z, bv.w};
#pragma unroll
      for (int i = 0; i < 4; ++i)
#pragma unroll
        for (int j = 0; j < 4; ++j) acc[i][j] = fmaf(a[i], bb[j], acc[i][j]);
    }
  }
  float bx[4] = {0.f, 0.f, 0.f, 0.f};
  if (bias) {
#pragma unroll
    for (int j = 0; j < 4; ++j) bx[j] = bias[n0 + col4 + j];
  }
#pragma unroll
  for (int i = 0; i < 4; ++i) {
    float r[4];
#pragma unroll
    for (int j = 0; j < 4; ++j) {
      float v = alpha * acc[i][j] + bx[j];
      if (ACT == 1) v = LEAKY(v);
      r[j] = v;
    }
    *(float4*)&Cb[(long)(m0 + row4 + i) * ldc + n0 + col4] =
        make_float4(r[0], r[1], r[2], r[3]);
  }
}

// ---------------------------------------------------------------------------
// BatchNorm over flattened (16384, 512): stats then fused normalize + leaky
// ---------------------------------------------------------------------------
__global__ __launch_bounds__(256) void bn_stats(const float* __restrict__ X,
                                                float* __restrict__ ST) {
  const int tid = threadIdx.x;
  const float* p = X + (long)blockIdx.x * 128 * 512;
  float s0 = 0.f, q0 = 0.f, s1 = 0.f, q1 = 0.f;
  for (int r = 0; r < 128; ++r) {
    const float a = p[r * 512 + tid];
    const float b = p[r * 512 + tid + 256];
    s0 += a; q0 += a * a; s1 += b; q1 += b * b;
  }
  atomicAdd(&ST[tid], s0);
  atomicAdd(&ST[512 + tid], q0);
  atomicAdd(&ST[tid + 256], s1);
  atomicAdd(&ST[512 + tid + 256], q1);
}

__global__ __launch_bounds__(256) void bn_apply(const float* __restrict__ X,
                                                float* __restrict__ Y,
                                                const float* __restrict__ ST,
                                                const float* __restrict__ g,
                                                const float* __restrict__ be) {
  const long p = ((long)blockIdx.x * 256 + threadIdx.x) * 4;
  const int c = (int)(p & 511);
  const float4 x = *(const float4*)&X[p];
  float r[4] = {x.x, x.y, x.z, x.w};
#pragma unroll
  for (int j = 0; j < 4; ++j) {
    const int col = c + j;
    const float mu = ST[col] * (1.f / 16384.f);
    const float var = ST[512 + col] * (1.f / 16384.f) - mu * mu;
    const float rstd = rsqrtf(var + 1e-5f);
    float v = (r[j] - mu) * rstd * g[col] + be[col];
    r[j] = LEAKY(v);
  }
  *(float4*)&Y[p] = make_float4(r[0], r[1], r[2], r[3]);
}

// ---------------------------------------------------------------------------
// fp32 flash attention: H=8 heads of 64 dims, L=1024, scale 1/8.
// One block = one (n, h, 64-row Q block). LDS exactly 64 KiB, conflict-free.
// ---------------------------------------------------------------------------
__global__ __launch_bounds__(256) void flash_attn(const float* __restrict__ Q,
                                                  const float* __restrict__ K,
                                                  const float* __restrict__ V,
                                                  float* __restrict__ O) {
  const int qb = blockIdx.x, h = blockIdx.y, n = blockIdx.z;
  const int tid = threadIdx.x;
  const int tx = tid & 15, ty = tid >> 4;
  const int r0 = ty * 4, c0 = tx * 4;
  __shared__ float Qs[64][64];   // [row][d]
  __shared__ float Kst[64][64];  // [d][kcol]  (transposed)
  __shared__ float Vs[64][64];   // [krow][d]
  __shared__ float Ps[64][64];   // [row][kcol]
  const long base = ((long)n * 1024) * 512 + h * 64;
#pragma unroll
  for (int it = 0; it < 4; ++it) {
    int idx = tid + it * 256;
    int r = idx >> 4, c4 = (idx & 15) * 4;
    float4 v = *(const float4*)&Q[base + (long)(qb * 64 + r) * 512 + c4];
    v.x *= 0.125f; v.y *= 0.125f; v.z *= 0.125f; v.w *= 0.125f;
    *(float4*)&Qs[r][c4] = v;
  }
  float m_r[4], l_r[4], acc[4][4] = {{0.f}};
#pragma unroll
  for (int i = 0; i < 4; ++i) { m_r[i] = -1e30f; l_r[i] = 0.f; }

  for (int kt = 0; kt < 16; ++kt) {
    __syncthreads();
#pragma unroll
    for (int it = 0; it < 4; ++it) {
      int idx = tid + it * 256;
      int r = idx >> 4, c4 = (idx & 15) * 4;
      const float4 kv = *(const float4*)&K[base + (long)(kt * 64 + r) * 512 + c4];
      Kst[c4 + 0][r] = kv.x; Kst[c4 + 1][r] = kv.y;
      Kst[c4 + 2][r] = kv.z; Kst[c4 + 3][r] = kv.w;
      *(float4*)&Vs[r][c4] =
          *(const float4*)&V[base + (long)(kt * 64 + r) * 512 + c4];
    }
    __syncthreads();
    float s[4][4] = {{0.f}};
#pragma unroll 16
    for (int d = 0; d < 64; ++d) {
      float qv[4], kv[4];
#pragma unroll
      for (int i = 0; i < 4; ++i) qv[i] = Qs[r0 + i][d];
      const float4 k4 = *(const float4*)&Kst[d][c0];
      kv[0] = k4.x; kv[1] = k4.y; kv[2] = k4.z; kv[3] = k4.w;
#pragma unroll
      for (int i = 0; i < 4; ++i)
#pragma unroll
        for (int j = 0; j < 4; ++j) s[i][j] = fmaf(qv[i], kv[j], s[i][j]);
    }
#pragma unroll
    for (int i = 0; i < 4; ++i) {
      float mt = fmaxf(fmaxf(s[i][0], s[i][1]), fmaxf(s[i][2], s[i][3]));
#pragma unroll
      for (int mask = 1; mask < 16; mask <<= 1)
        mt = fmaxf(mt, __shfl_xor(mt, mask, 64));
      const float mn = fmaxf(m_r[i], mt);
      const float f = __expf(m_r[i] - mn);
      m_r[i] = mn;
      float ps = 0.f;
#pragma unroll
      for (int j = 0; j < 4; ++j) {
        const float pv = __expf(s[i][j] - mn);
        s[i][j] = pv;
        ps += pv;
      }
#pragma unroll
      for (int mask = 1; mask < 16; mask <<= 1) ps += __shfl_xor(ps, mask, 64);
      l_r[i] = l_r[i] * f + ps;
#pragma unroll
      for (int j = 0; j < 4; ++j) acc[i][j] *= f;
      *(float4*)&Ps[r0 + i][c0] = make_float4(s[i][0], s[i][1], s[i][2], s[i][3]);
    }
    __syncthreads();
#pragma unroll 16
    for (int c = 0; c < 64; ++c) {
      float pv[4], vv[4];
#pragma unroll
      for (int i = 0; i < 4; ++i) pv[i] = Ps[r0 + i][c];
      const float4 v4 = *(const float4*)&Vs[c][c0];
      vv[0] = v4.x; vv[1] = v4.y; vv[2] = v4.z; vv[3] = v4.w;
#pragma unroll
      for (int i = 0; i < 4; ++i)
#pragma unroll
        for (int j = 0; j < 4; ++j) acc[i][j] = fmaf(pv[i], vv[j], acc[i][j]);
    }
  }
#pragma unroll
  for (int i = 0; i < 4; ++i) {
    const float inv = 1.f / l_r[i];
    *(float4*)&O[base + (long)(qb * 64 + r0 + i) * 512 + c0] =
        make_float4(acc[i][0] * inv, acc[i][1] * inv, acc[i][2] * inv,
                    acc[i][3] * inv);
  }
}

// ---------------------------------------------------------------------------
// Row softmax over 2048-wide rows of d_out (one block per row)
// ---------------------------------------------------------------------------
__global__ __launch_bounds__(256) void softmax_rows(float* __restrict__ D) {
  float* p = D + (long)blockIdx.x * 2048;
  const int tid = threadIdx.x;
  const int wv = tid >> 6, ln = tid & 63;
  float v[8];
  float mx = -1e30f;
#pragma unroll
  for (int k = 0; k < 8; ++k) {
    v[k] = p[tid + k * 256];
    mx = fmaxf(mx, v[k]);
  }
#pragma unroll
  for (int mask = 1; mask < 64; mask <<= 1) mx = fmaxf(mx, __shfl_xor(mx, mask, 64));
  __shared__ float red[8];
  if (ln == 0) red[wv] = mx;
  __syncthreads();
  mx = fmaxf(fmaxf(red[0], red[1]), fmaxf(red[2], red[3]));
  float s = 0.f;
#pragma unroll
  for (int k = 0; k < 8; ++k) {
    v[k] = __expf(v[k] - mx);
    s += v[k];
  }
#pragma unroll
  for (int mask = 1; mask < 64; mask <<= 1) s += __shfl_xor(s, mask, 64);
  if (ln == 0) red[4 + wv] = s;
  __syncthreads();
  s = red[4] + red[5] + red[6] + red[7];
  const float inv = 1.f / s;
#pragma unroll
  for (int k = 0; k < 8; ++k) p[tid + k * 256] = v[k] * inv;
}

// ---------------------------------------------------------------------------
// Column sums + column normalization (A @ D^{-1})
// ---------------------------------------------------------------------------
__global__ __launch_bounds__(256) void colsum_kernel(const float* __restrict__ D,
                                                     float* __restrict__ CS) {
  const int j = blockIdx.x * 256 + threadIdx.x;
  const int n = blockIdx.z;
  const long base = ((long)n * 2048 + blockIdx.y * 256) * 2048 + j;
  float s = 0.f;
  for (int i = 0; i < 256; ++i) s += D[base + (long)i * 2048];
  atomicAdd(&CS[n * 2048 + j], s);
}

__global__ __launch_bounds__(256) void scale_kernel(float* __restrict__ D,
                                                    const float* __restrict__ CS) {
  const long p = ((long)blockIdx.x * 256 + threadIdx.x) * 4;
  const int n = (int)(p >> 22);
  const int j = (int)(p & 2047);
  float4 v = *(float4*)&D[p];
  const float* c = &CS[n * 2048 + j];
  v.x *= (c[0] > 0.f ? 1.f / c[0] : 0.f);
  v.y *= (c[1] > 0.f ? 1.f / c[1] : 0.f);
  v.z *= (c[2] > 0.f ? 1.f / c[2] : 0.f);
  v.w *= (c[3] > 0.f ? 1.f / c[3] : 0.f);
  *(float4*)&D[p] = v;
}

// ---------------------------------------------------------------------------
extern "C" void kernel_launch(void* const* d_in, const int* in_sizes, int n_in,
                              void* d_out, int out_size, void* d_ws,
                              size_t ws_size, hipStream_t stream) {
  const float* x1 = (const float*)d_in[0];
  const float* x2 = (const float*)d_in[1];
  const float* enc1 = (const float*)d_in[2];
  const float* enc2 = (const float*)d_in[3];
  const float* mlp_w1 = (const float*)d_in[4];
  const float* mlp_b1 = (const float*)d_in[5];
  const float* mlp_w2 = (const float*)d_in[6];
  const float* mlp_b2 = (const float*)d_in[7];
  const float* mlp_g = (const float*)d_in[8];
  const float* mlp_be = (const float*)d_in[9];
  const float* nlp_w1 = (const float*)d_in[10];
  const float* nlp_b1 = (const float*)d_in[11];
  const float* nlp_w2 = (const float*)d_in[12];
  const float* nlp_b2 = (const float*)d_in[13];
  const float* nlp_g = (const float*)d_in[14];
  const float* nlp_be = (const float*)d_in[15];
  const float* a1_wq_w = (const float*)d_in[16];
  const float* a1_wq_b = (const float*)d_in[17];
  const float* a1_wk_w = (const float*)d_in[18];
  const float* a1_wk_b = (const float*)d_in[19];
  const float* a1_wv_w = (const float*)d_in[20];
  const float* a1_wv_b = (const float*)d_in[21];
  const float* a1_fc_w = (const float*)d_in[22];
  const float* a1_fc_b = (const float*)d_in[23];
  const float* a2_wq_w = (const float*)d_in[24];
  const float* a2_wq_b = (const float*)d_in[25];
  const float* a2_wk_w = (const float*)d_in[26];
  const float* a2_wk_b = (const float*)d_in[27];
  const float* a2_wv_w = (const float*)d_in[28];
  const float* a2_wv_b = (const float*)d_in[29];
  const float* a2_fc_w = (const float*)d_in[30];
  const float* a2_fc_b = (const float*)d_in[31];
  float* out = (float*)d_out;

  float* ws = (float*)d_ws;
  float* P1 = ws;                  // 1<<20 floats
  float* P2 = P1 + (1L << 20);     // 1<<20
  float* A_ = P2 + (1L << 20);     // 8<<20
  float* B_ = A_ + (8L << 20);     // 8<<20
  float* C_ = B_ + (8L << 20);     // 8<<20
  float* E1 = C_ + (8L << 20);     // 2<<20
  float* E2 = E1 + (2L << 20);     // 2<<20
  float* ST = E2 + (2L << 20);     // 1024
  float* CS = ST + 1024;           // 8192
  float* Qb = C_;
  float* Kb = C_ + (2L << 20);
  float* Vb = C_ + (4L << 20);
  float* AO = C_ + (6L << 20);
  float* a1p = P1;  // (4,1024,512) spans P1+P2
  float* a2p = A_;  // first 2M floats of A_

  const dim3 T(256);
  const long sNE = 4096L * 512;   // per-n node-enc stride
  const long sE = 1024L * 512;    // per-n edge stride
  const long sP = 1024L * 256;    // per-n pooled stride

  // 1. prep/pool
  prep_pool<<<dim3(1024, 4), T, 0, stream>>>(x1, P1);
  prep_pool<<<dim3(1024, 4), T, 0, stream>>>(x2, P2);

  // 2. ne1 = [enc1@P1 | enc2@P1] -> A_
  gemm_f32<false, false, 0><<<dim3(4, 64, 4), T, 0, stream>>>(
      enc1, P1, A_, nullptr, 4096, 256, 1024, 1024, 256, 512, 1, 0, 0, sP, 0,
      sNE, 0, 1.f);
  gemm_f32<false, false, 0><<<dim3(4, 64, 4), T, 0, stream>>>(
      enc2, P1, A_ + 256, nullptr, 4096, 256, 1024, 1024, 256, 512, 1, 0, 0,
      sP, 0, sNE, 0, 1.f);
  // 3. MLP1: mid=leaky(ne1@w1+b1) -> B_; lin2 -> C_; BN -> A_ (=h1)
  gemm_f32<false, false, 1><<<dim3(8, 256, 1), T, 0, stream>>>(
      A_, mlp_w1, B_, mlp_b1, 16384, 512, 512, 512, 512, 512, 1, 0, 0, 0, 0, 0,
      0, 1.f);
  gemm_f32<false, false, 0><<<dim3(8, 256, 1), T, 0, stream>>>(
      B_, mlp_w2, C_, mlp_b2, 16384, 512, 512, 512, 512, 512, 1, 0, 0, 0, 0, 0,
      0, 1.f);
  hipMemsetAsync(ST, 0, 1024 * sizeof(float), stream);
  bn_stats<<<128, T, 0, stream>>>(C_, ST);
  bn_apply<<<8192, T, 0, stream>>>(C_, A_, ST, mlp_g, mlp_be);

  // 4. ne2 -> B_; MLP2 -> h2 in B_
  gemm_f32<false, false, 0><<<dim3(4, 64, 4), T, 0, stream>>>(
      enc1, P2, B_, nullptr, 4096, 256, 1024, 1024, 256, 512, 1, 0, 0, sP, 0,
      sNE, 0, 1.f);
  gemm_f32<false, false, 0><<<dim3(4, 64, 4), T, 0, stream>>>(
      enc2, P2, B_ + 256, nullptr, 4096, 256, 1024, 1024, 256, 512, 1, 0, 0,
      sP, 0, sNE, 0, 1.f);
  gemm_f32<false, false, 1><<<dim3(8, 256, 1), T, 0, stream>>>(
      B_, nlp_w1, C_, nlp_b1, 16384, 512, 512, 512, 512, 512, 1, 0, 0, 0, 0, 0,
      0, 1.f);
  gemm_f32<false, false, 0><<<dim3(8, 256, 1), T, 0, stream>>>(
      C_, nlp_w2, B_, nlp_b2, 16384, 512, 512, 512, 512, 512, 1, 0, 0, 0, 0, 0,
      0, 1.f);
  hipMemsetAsync(ST, 0, 1024 * sizeof(float), stream);
  bn_stats<<<128, T, 0, stream>>>(B_, ST);
  bn_apply<<<8192, T, 0, stream>>>(B_, B_, ST, nlp_g, nlp_be);

  // 5. edge decode: e1 = enc1^T @ h1 / 1024; e2 = enc1^T @ h2 / 1024
  gemm_f32<true, false, 0><<<dim3(8, 16, 4), T, 0, stream>>>(
      enc1, A_, E1, nullptr, 1024, 512, 4096, 1024, 512, 512, 1, 0, 0, sNE, 0,
      sE, 0, 1.f / 1024.f);
  gemm_f32<true, false, 0><<<dim3(8, 16, 4), T, 0, stream>>>(
      enc1, B_, E2, nullptr, 1024, 512, 4096, 1024, 512, 512, 1, 0, 0, sNE, 0,
      sE, 0, 1.f / 1024.f);

  // 6. att1: q=e2, k=v=e1
  gemm_f32<false, false, 0><<<dim3(8, 64, 1), T, 0, stream>>>(
      E2, a1_wq_w, Qb, a1_wq_b, 4096, 512, 512, 512, 512, 512, 1, 0, 0, 0, 0,
      0, 0, 1.f);
  gemm_f32<false, false, 0><<<dim3(8, 64, 1), T, 0, stream>>>(
      E1, a1_wk_w, Kb, a1_wk_b, 4096, 512, 512, 512, 512, 512, 1, 0, 0, 0, 0,
      0, 0, 1.f);
  gemm_f32<false, false, 0><<<dim3(8, 64, 1), T, 0, stream>>>(
      E1, a1_wv_w, Vb, a1_wv_b, 4096, 512, 512, 512, 512, 512, 1, 0, 0, 0, 0,
      0, 0, 1.f);
  flash_attn<<<dim3(16, 8, 4), T, 0, stream>>>(Qb, Kb, Vb, AO);
  gemm_f32<false, false, 0><<<dim3(8, 64, 1), T, 0, stream>>>(
      AO, a1_fc_w, a1p, a1_fc_b, 4096, 512, 512, 512, 512, 512, 1, 0, 0, 0, 0,
      0, 0, 1.f);

  // 7. att2: q=e1, k=v=e2
  gemm_f32<false, false, 0><<<dim3(8, 64, 1), T, 0, stream>>>(
      E1, a2_wq_w, Qb, a2_wq_b, 4096, 512, 512, 512, 512, 512, 1, 0, 0, 0, 0,
      0, 0, 1.f);
  gemm_f32<false, false, 0><<<dim3(8, 64, 1), T, 0, stream>>>(
      E2, a2_wk_w, Kb, a2_wk_b, 4096, 512, 512, 512, 512, 512, 1, 0, 0, 0, 0,
      0, 0, 1.f);
  gemm_f32<false, false, 0><<<dim3(8, 64, 1), T, 0, stream>>>(
      E2, a2_wv_w, Vb, a2_wv_b, 4096, 512, 512, 512, 512, 512, 1, 0, 0, 0, 0,
      0, 0, 1.f);
  flash_attn<<<dim3(16, 8, 4), T, 0, stream>>>(Qb, Kb, Vb, AO);
  gemm_f32<false, false, 0><<<dim3(8, 64, 1), T, 0, stream>>>(
      AO, a2_fc_w, a2p, a2_fc_b, 4096, 512, 512, 512, 512, 512, 1, 0, 0, 0, 0,
      0, 0, 1.f);

  // 8. logits quadrants into d_out: c1=[a1;a2], c2=[a2;a1], L = c1 @ c2^T
  const long sD = 2048L * 2048;
  gemm_f32<false, true, 0><<<dim3(16, 16, 4), T, 0, stream>>>(
      a1p, a2p, out, nullptr, 1024, 1024, 512, 512, 512, 2048, 1, sE, 0, sE, 0,
      sD, 0, 1.f);
  gemm_f32<false, true, 0><<<dim3(16, 16, 4), T, 0, stream>>>(
      a1p, a1p, out + 1024, nullptr, 1024, 1024, 512, 512, 512, 2048, 1, sE, 0,
      sE, 0, sD, 0, 1.f);
  gemm_f32<false, true, 0><<<dim3(16, 16, 4), T, 0, stream>>>(
      a2p, a2p, out + 1024L * 2048, nullptr, 1024, 1024, 512, 512, 512, 2048,
      1, sE, 0, sE, 0, sD, 0, 1.f);
  gemm_f32<false, true, 0><<<dim3(16, 16, 4), T, 0, stream>>>(
      a2p, a1p, out + 1024L * 2048 + 1024, nullptr, 1024, 1024, 512, 512, 512,
      2048, 1, sE, 0, sE, 0, sD, 0, 1.f);

  // 9. softmax rows, then column normalization
  softmax_rows<<<8192, T, 0, stream>>>(out);
  hipMemsetAsync(CS, 0, 8192 * sizeof(float), stream);
  colsum_kernel<<<dim3(8, 8, 4), T, 0, stream>>>(out, CS);
  scale_kernel<<<16384, T, 0, stream>>>(out, CS);
}

// Round 2
// 1005.602 us; speedup vs baseline: 2.4623x; 2.4623x over previous
//
#include <hip/hip_runtime.h>
#include <hip/hip_bf16.h>

#define LEAKY(v) ((v) >= 0.f ? (v) : 0.01f * (v))

typedef __attribute__((ext_vector_type(8))) short short8b;
typedef __attribute__((ext_vector_type(4))) float f32x4;
typedef __attribute__((ext_vector_type(4))) unsigned short us4;

__device__ __forceinline__ unsigned short f2b(float f) {
  unsigned int u = __builtin_bit_cast(unsigned int, f);
  return (unsigned short)((u + 0x7FFFu + ((u >> 16) & 1u)) >> 16);
}
__device__ __forceinline__ float b2f(unsigned short s) {
  return __builtin_bit_cast(float, (unsigned int)s << 16);
}

__device__ __forceinline__ void gload16(const unsigned short* g, unsigned short* l) {
  __builtin_amdgcn_global_load_lds(
      (const __attribute__((address_space(1))) unsigned int*)(g),
      (__attribute__((address_space(3))) unsigned int*)(l), 16, 0, 0);
}

// ---------------------------------------------------------------------------
// prep + exact AdaptiveAvgPool1d -> bf16
// P[n,i,k] = mean_{m<16} X[n, (k&3)*16+m, i>>4, (i&15)*64 + (k>>2)]
// ---------------------------------------------------------------------------
__global__ __launch_bounds__(256) void prep_pool(const float* __restrict__ X,
                                                 unsigned short* __restrict__ P) {
  const int i = blockIdx.x, n = blockIdx.y;
  const int t = i >> 4;
  const int vvb = (i & 15) * 64;
  __shared__ float tile[64][65];
  const int tid = threadIdx.x;
  const long base = (((long)n * 64) * 64 + t) * 1024 + vvb;
#pragma unroll
  for (int it = 0; it < 16; ++it) {
    int idx = tid + it * 256;
    int c = idx >> 6, w = idx & 63;
    tile[c][w] = X[base + (long)c * 64 * 1024 + w];
  }
  __syncthreads();
  const int k = tid;
  const int w = k >> 2, cb = (k & 3) * 16;
  float s = 0.f;
#pragma unroll
  for (int m = 0; m < 16; ++m) s += tile[cb + m][w];
  P[((long)n * 1024 + i) * 256 + k] = f2b(s * (1.f / 16.f));
}

// ---------------------------------------------------------------------------
// fp32 (R x C) -> bf16 (C x R) transpose
// ---------------------------------------------------------------------------
__global__ __launch_bounds__(256) void transpose_f2b(
    const float* __restrict__ in, unsigned short* __restrict__ out, int R, int C) {
  __shared__ float t[64][65];
  const int c0 = blockIdx.x * 64, r0 = blockIdx.y * 64;
  const int tid = threadIdx.x;
#pragma unroll
  for (int it = 0; it < 4; ++it) {
    int idx = tid + it * 256;
    int r = idx >> 4, c4 = (idx & 15) * 4;
    float4 v = *(const float4*)&in[(long)(r0 + r) * C + c0 + c4];
    t[c4 + 0][r] = v.x; t[c4 + 1][r] = v.y;
    t[c4 + 2][r] = v.z; t[c4 + 3][r] = v.w;
  }
  __syncthreads();
#pragma unroll
  for (int it = 0; it < 4; ++it) {
    int idx = tid + it * 256;
    int c = idx >> 4, r4 = (idx & 15) * 4;
    us4 o;
    o[0] = f2b(t[c][r4 + 0]); o[1] = f2b(t[c][r4 + 1]);
    o[2] = f2b(t[c][r4 + 2]); o[3] = f2b(t[c][r4 + 3]);
    *(us4*)&out[(long)(c0 + c) * R + r0 + r4] = o;
  }
}

// fused 12x 512x512 weight transpose+convert
struct WPtrs { const float* p[12]; };
__global__ __launch_bounds__(256) void wtrans(WPtrs wp, unsigned short* __restrict__ out) {
  const float* in = wp.p[blockIdx.z];
  unsigned short* ob = out + (long)blockIdx.z * 262144;
  __shared__ float t[64][65];
  const int c0 = blockIdx.x * 64, r0 = blockIdx.y * 64;
  const int tid = threadIdx.x;
#pragma unroll
  for (int it = 0; it < 4; ++it) {
    int idx = tid + it * 256;
    int r = idx >> 4, c4 = (idx & 15) * 4;
    float4 v = *(const float4*)&in[(long)(r0 + r) * 512 + c0 + c4];
    t[c4 + 0][r] = v.x; t[c4 + 1][r] = v.y;
    t[c4 + 2][r] = v.z; t[c4 + 3][r] = v.w;
  }
  __syncthreads();
#pragma unroll
  for (int it = 0; it < 4; ++it) {
    int idx = tid + it * 256;
    int c = idx >> 4, r4 = (idx & 15) * 4;
    us4 o;
    o[0] = f2b(t[c][r4 + 0]); o[1] = f2b(t[c][r4 + 1]);
    o[2] = f2b(t[c][r4 + 2]); o[3] = f2b(t[c][r4 + 3]);
    *(us4*)&ob[(long)(c0 + c) * 512 + r0 + r4] = o;
  }
}

// bf16 (R x C) -> bf16 (C x R) transpose, batched over z
__global__ __launch_bounds__(256) void transpose_b2b(
    const unsigned short* __restrict__ in, unsigned short* __restrict__ out,
    int R, int C, long sIn, long sOut) {
  const unsigned short* ib = in + (long)blockIdx.z * sIn;
  unsigned short* ob = out + (long)blockIdx.z * sOut;
  __shared__ unsigned short t[64][65];
  const int c0 = blockIdx.x * 64, r0 = blockIdx.y * 64;
  const int tid = threadIdx.x;
#pragma unroll
  for (int it = 0; it < 2; ++it) {
    int idx = tid + it * 256;
    int r = idx >> 3, c8 = (idx & 7) * 8;
    short8b v = *(const short8b*)&ib[(long)(r0 + r) * C + c0 + c8];
#pragma unroll
    for (int j = 0; j < 8; ++j) t[c8 + j][r] = (unsigned short)v[j];
  }
  __syncthreads();
#pragma unroll
  for (int it = 0; it < 4; ++it) {
    int idx = tid + it * 256;
    int c = idx >> 4, r4 = (idx & 15) * 4;
    us4 o;
    o[0] = t[c][r4 + 0]; o[1] = t[c][r4 + 1];
    o[2] = t[c][r4 + 2]; o[3] = t[c][r4 + 3];
    *(us4*)&out[(long)blockIdx.z * 0 + 0], // no-op placeholder removed below
    *(us4*)&ob[(long)(c0 + c) * R + r0 + r4] = o;
  }
}

// straight fp32 -> bf16 convert (n4 = count/4)
__global__ __launch_bounds__(256) void convert_f2b(const float* __restrict__ in,
                                                   unsigned short* __restrict__ out,
                                                   long n4) {
  long i = (long)blockIdx.x * 256 + threadIdx.x;
  if (i < n4) {
    float4 v = ((const float4*)in)[i];
    us4 o;
    o[0] = f2b(v.x); o[1] = f2b(v.y); o[2] = f2b(v.z); o[3] = f2b(v.w);
    ((us4*)out)[i] = o;
  }
}

// ---------------------------------------------------------------------------
// bf16 MFMA GEMM, 128x128 tile, BK=64, 4 waves (2x2 of 64x64).
// A: M x K row-major bf16.  B: N x K row-major bf16 (i.e. B^T layout).
// C: fp32 or bf16, ldc, optional fp32 bias over N, optional leaky, alpha.
// M = gridDim.y*128, N = gridDim.x*128; K % 64 == 0.
// ---------------------------------------------------------------------------
template <int ACT, int OUTBF>
__global__ __launch_bounds__(256) void gemm_mfma(
    const unsigned short* __restrict__ A, const unsigned short* __restrict__ B,
    void* __restrict__ Cv, const float* __restrict__ bias, int K, int lda,
    int ldb, int ldc, long sA, long sB, long sC, float alpha) {
  const int m0 = blockIdx.y * 128, n0 = blockIdx.x * 128;
  const unsigned short* Ab = A + (long)blockIdx.z * sA;
  const unsigned short* Bb = B + (long)blockIdx.z * sB;
  const int tid = threadIdx.x;
  const int lane = tid & 63, w = tid >> 6;
  const int wr = (w >> 1) * 64, wc = (w & 1) * 64;
  __shared__ unsigned short As[128 * 64];
  __shared__ unsigned short Bs[128 * 64];
  f32x4 acc[4][4];
#pragma unroll
  for (int i = 0; i < 4; ++i)
#pragma unroll
    for (int j = 0; j < 4; ++j) acc[i][j] = (f32x4){0.f, 0.f, 0.f, 0.f};
  const int srow = tid >> 3, scol = (tid & 7) * 8;
  const int rl = lane & 15, kl = (lane >> 4) * 8;
  for (int k0 = 0; k0 < K; k0 += 64) {
    __syncthreads();
#pragma unroll
    for (int it = 0; it < 4; ++it) {
      gload16(Ab + (long)(m0 + it * 32 + srow) * lda + k0 + scol,
              As + w * 512 + it * 2048);
      gload16(Bb + (long)(n0 + it * 32 + srow) * ldb + k0 + scol,
              Bs + w * 512 + it * 2048);
    }
    __syncthreads();
#pragma unroll
    for (int kk = 0; kk < 64; kk += 32) {
      short8b af[4], bfr[4];
#pragma unroll
      for (int m = 0; m < 4; ++m)
        af[m] = *(const short8b*)&As[(wr + m * 16 + rl) * 64 + kk + kl];
#pragma unroll
      for (int nn = 0; nn < 4; ++nn)
        bfr[nn] = *(const short8b*)&Bs[(wc + nn * 16 + rl) * 64 + kk + kl];
#pragma unroll
      for (int m = 0; m < 4; ++m)
#pragma unroll
        for (int nn = 0; nn < 4; ++nn)
          acc[m][nn] = __builtin_amdgcn_mfma_f32_16x16x32_bf16(
              af[m], bfr[nn], acc[m][nn], 0, 0, 0);
    }
  }
  const int rrow = (lane >> 4) * 4;
  float bv[4];
#pragma unroll
  for (int nn = 0; nn < 4; ++nn)
    bv[nn] = bias ? bias[n0 + wc + nn * 16 + rl] : 0.f;
#pragma unroll
  for (int m = 0; m < 4; ++m)
#pragma unroll
    for (int nn = 0; nn < 4; ++nn)
#pragma unroll
      for (int r = 0; r < 4; ++r) {
        float v = alpha * acc[m][nn][r] + bv[nn];
        if (ACT == 1) v = LEAKY(v);
        long off = (long)blockIdx.z * sC +
                   (long)(m0 + wr + m * 16 + rrow + r) * ldc + n0 + wc +
                   nn * 16 + rl;
        if (OUTBF)
          ((unsigned short*)Cv)[off] = f2b(v);
        else
          ((float*)Cv)[off] = v;
      }
}

// ---------------------------------------------------------------------------
// BatchNorm over flattened (16384, 512), bf16 in/out
// ---------------------------------------------------------------------------
__global__ __launch_bounds__(256) void bn_stats_b(const unsigned short* __restrict__ X,
                                                  float* __restrict__ ST) {
  const int tid = threadIdx.x;
  const unsigned short* p = X + (long)blockIdx.x * 128 * 512;
  float s0 = 0.f, q0 = 0.f, s1 = 0.f, q1 = 0.f;
  for (int r = 0; r < 128; ++r) {
    const float a = b2f(p[r * 512 + tid]);
    const float b = b2f(p[r * 512 + tid + 256]);
    s0 += a; q0 += a * a; s1 += b; q1 += b * b;
  }
  atomicAdd(&ST[tid], s0);
  atomicAdd(&ST[512 + tid], q0);
  atomicAdd(&ST[tid + 256], s1);
  atomicAdd(&ST[512 + tid + 256], q1);
}

__global__ __launch_bounds__(256) void bn_apply_b(
    const unsigned short* __restrict__ X, unsigned short* __restrict__ Y,
    const float* __restrict__ ST, const float* __restrict__ g,
    const float* __restrict__ be) {
  const long p = ((long)blockIdx.x * 256 + threadIdx.x) * 4;
  const int c = (int)(p & 511);
  us4 x = *(const us4*)&X[p];
  us4 y;
#pragma unroll
  for (int j = 0; j < 4; ++j) {
    const int col = c + j;
    const float mu = ST[col] * (1.f / 16384.f);
    const float var = ST[512 + col] * (1.f / 16384.f) - mu * mu;
    float v = (b2f(x[j]) - mu) * rsqrtf(var + 1e-5f) * g[col] + be[col];
    y[j] = f2b(LEAKY(v));
  }
  *(us4*)&Y[p] = y;
}

// ---------------------------------------------------------------------------
// fp32 flash attention (in fp32, out bf16): H=8 x 64 dims, L=1024, scale 1/8
// ---------------------------------------------------------------------------
__global__ __launch_bounds__(256) void flash_attn(const float* __restrict__ Q,
                                                  const float* __restrict__ K,
                                                  const float* __restrict__ V,
                                                  unsigned short* __restrict__ O) {
  const int qb = blockIdx.x, h = blockIdx.y, n = blockIdx.z;
  const int tid = threadIdx.x;
  const int tx = tid & 15, ty = tid >> 4;
  const int r0 = ty * 4, c0 = tx * 4;
  __shared__ float Qs[64][64];
  __shared__ float Kst[64][64];
  __shared__ float Vs[64][64];
  __shared__ float Ps[64][64];
  const long base = ((long)n * 1024) * 512 + h * 64;
#pragma unroll
  for (int it = 0; it < 4; ++it) {
    int idx = tid + it * 256;
    int r = idx >> 4, c4 = (idx & 15) * 4;
    float4 v = *(const float4*)&Q[base + (long)(qb * 64 + r) * 512 + c4];
    v.x *= 0.125f; v.y *= 0.125f; v.z *= 0.125f; v.w *= 0.125f;
    *(float4*)&Qs[r][c4] = v;
  }
  float m_r[4], l_r[4], acc[4][4] = {{0.f}};
#pragma unroll
  for (int i = 0; i < 4; ++i) { m_r[i] = -1e30f; l_r[i] = 0.f; }

  for (int kt = 0; kt < 16; ++kt) {
    __syncthreads();
#pragma unroll
    for (int it = 0; it < 4; ++it) {
      int idx = tid + it * 256;
      int r = idx >> 4, c4 = (idx & 15) * 4;
      const float4 kv = *(const float4*)&K[base + (long)(kt * 64 + r) * 512 + c4];
      Kst[c4 + 0][r] = kv.x; Kst[c4 + 1][r] = kv.y;
      Kst[c4 + 2][r] = kv.z; Kst[c4 + 3][r] = kv.w;
      *(float4*)&Vs[r][c4] =
          *(const float4*)&V[base + (long)(kt * 64 + r) * 512 + c4];
    }
    __syncthreads();
    float s[4][4] = {{0.f}};
#pragma unroll 16
    for (int d = 0; d < 64; ++d) {
      float qv[4], kv[4];
#pragma unroll
      for (int i = 0; i < 4; ++i) qv[i] = Qs[r0 + i][d];
      const float4 k4 = *(const float4*)&Kst[d][c0];
      kv[0] = k4.x; kv[1] = k4.y; kv[2] = k4.z; kv[3] = k4.w;
#pragma unroll
      for (int i = 0; i < 4; ++i)
#pragma unroll
        for (int j = 0; j < 4; ++j) s[i][j] = fmaf(qv[i], kv[j], s[i][j]);
    }
#pragma unroll
    for (int i = 0; i < 4; ++i) {
      float mt = fmaxf(fmaxf(s[i][0], s[i][1]), fmaxf(s[i][2], s[i][3]));
#pragma unroll
      for (int mask = 1; mask < 16; mask <<= 1)
        mt = fmaxf(mt, __shfl_xor(mt, mask, 64));
      const float mn = fmaxf(m_r[i], mt);
      const float f = __expf(m_r[i] - mn);
      m_r[i] = mn;
      float ps = 0.f;
#pragma unroll
      for (int j = 0; j < 4; ++j) {
        const float pv = __expf(s[i][j] - mn);
        s[i][j] = pv;
        ps += pv;
      }
#pragma unroll
      for (int mask = 1; mask < 16; mask <<= 1) ps += __shfl_xor(ps, mask, 64);
      l_r[i] = l_r[i] * f + ps;
#pragma unroll
      for (int j = 0; j < 4; ++j) acc[i][j] *= f;
      *(float4*)&Ps[r0 + i][c0] = make_float4(s[i][0], s[i][1], s[i][2], s[i][3]);
    }
    __syncthreads();
#pragma unroll 16
    for (int c = 0; c < 64; ++c) {
      float pv[4], vv[4];
#pragma unroll
      for (int i = 0; i < 4; ++i) pv[i] = Ps[r0 + i][c];
      const float4 v4 = *(const float4*)&Vs[c][c0];
      vv[0] = v4.x; vv[1] = v4.y; vv[2] = v4.z; vv[3] = v4.w;
#pragma unroll
      for (int i = 0; i < 4; ++i)
#pragma unroll
        for (int j = 0; j < 4; ++j) acc[i][j] = fmaf(pv[i], vv[j], acc[i][j]);
    }
  }
#pragma unroll
  for (int i = 0; i < 4; ++i) {
    const float inv = 1.f / l_r[i];
    us4 o;
    o[0] = f2b(acc[i][0] * inv); o[1] = f2b(acc[i][1] * inv);
    o[2] = f2b(acc[i][2] * inv); o[3] = f2b(acc[i][3] * inv);
    *(us4*)&O[base + (long)(qb * 64 + r0 + i) * 512 + c0] = o;
  }
}

// ---------------------------------------------------------------------------
// Row softmax over 2048-wide rows of d_out
// ---------------------------------------------------------------------------
__global__ __launch_bounds__(256) void softmax_rows(float* __restrict__ D) {
  float* p = D + (long)blockIdx.x * 2048;
  const int tid = threadIdx.x;
  const int wv = tid >> 6, ln = tid & 63;
  float v[8];
  float mx = -1e30f;
#pragma unroll
  for (int k = 0; k < 8; ++k) {
    v[k] = p[tid + k * 256];
    mx = fmaxf(mx, v[k]);
  }
#pragma unroll
  for (int mask = 1; mask < 64; mask <<= 1) mx = fmaxf(mx, __shfl_xor(mx, mask, 64));
  __shared__ float red[8];
  if (ln == 0) red[wv] = mx;
  __syncthreads();
  mx = fmaxf(fmaxf(red[0], red[1]), fmaxf(red[2], red[3]));
  float s = 0.f;
#pragma unroll
  for (int k = 0; k < 8; ++k) {
    v[k] = __expf(v[k] - mx);
    s += v[k];
  }
#pragma unroll
  for (int mask = 1; mask < 64; mask <<= 1) s += __shfl_xor(s, mask, 64);
  if (ln == 0) red[4 + wv] = s;
  __syncthreads();
  s = red[4] + red[5] + red[6] + red[7];
  const float inv = 1.f / s;
#pragma unroll
  for (int k = 0; k < 8; ++k) p[tid + k * 256] = v[k] * inv;
}

__global__ __launch_bounds__(256) void colsum_kernel(const float* __restrict__ D,
                                                     float* __restrict__ CS) {
  const int j = blockIdx.x * 256 + threadIdx.x;
  const int n = blockIdx.z;
  const long base = ((long)n * 2048 + blockIdx.y * 256) * 2048 + j;
  float s = 0.f;
  for (int i = 0; i < 256; ++i) s += D[base + (long)i * 2048];
  atomicAdd(&CS[n * 2048 + j], s);
}

__global__ __launch_bounds__(256) void scale_kernel(float* __restrict__ D,
                                                    const float* __restrict__ CS) {
  const long p = ((long)blockIdx.x * 256 + threadIdx.x) * 4;
  const int n = (int)(p >> 22);
  const int j = (int)(p & 2047);
  float4 v = *(float4*)&D[p];
  const float* c = &CS[n * 2048 + j];
  v.x *= (c[0] > 0.f ? 1.f / c[0] : 0.f);
  v.y *= (c[1] > 0.f ? 1.f / c[1] : 0.f);
  v.z *= (c[2] > 0.f ? 1.f / c[2] : 0.f);
  v.w *= (c[3] > 0.f ? 1.f / c[3] : 0.f);
  *(float4*)&D[p] = v;
}

// ---------------------------------------------------------------------------
extern "C" void kernel_launch(void* const* d_in, const int* in_sizes, int n_in,
                              void* d_out, int out_size, void* d_ws,
                              size_t ws_size, hipStream_t stream) {
  const float* x1 = (const float*)d_in[0];
  const float* x2 = (const float*)d_in[1];
  const float* enc1 = (const float*)d_in[2];
  const float* enc2 = (const float*)d_in[3];
  const float* mlp_b1 = (const float*)d_in[5];
  const float* mlp_b2 = (const float*)d_in[7];
  const float* mlp_g = (const float*)d_in[8];
  const float* mlp_be = (const float*)d_in[9];
  const float* nlp_b1 = (const float*)d_in[11];
  const float* nlp_b2 = (const float*)d_in[13];
  const float* nlp_g = (const float*)d_in[14];
  const float* nlp_be = (const float*)d_in[15];
  float* out = (float*)d_out;

  unsigned short* W = (unsigned short*)d_ws;
  const long M1 = 1L << 20;
  unsigned short* Pb1 = W;
  unsigned short* Pb2 = W + M1;
  unsigned short* Pt1 = W + 2 * M1;
  unsigned short* Pt2 = W + 3 * M1;
  unsigned short* E1B = W + 4 * M1;
  unsigned short* E2B = W + 8 * M1;
  unsigned short* E1T = W + 12 * M1;
  unsigned short* WT = W + 16 * M1;   // 12 x 262144
  unsigned short* BA = W + 20 * M1;   // 8M us
  unsigned short* BB = W + 28 * M1;   // 8M us
  unsigned short* H1T = W + 36 * M1;  // 8M us
  unsigned short* H2T = W + 44 * M1;  // 8M us
  unsigned short* E1 = W + 52 * M1;   // 2M us
  unsigned short* E2 = W + 54 * M1;   // 2M us
  float* ST = (float*)(W + 56 * M1);
  float* CS = ST + 1024;
  float* Qf = (float*)BA;
  float* Kf = (float*)BB;
  float* Vf = (float*)H1T;
  unsigned short* AO = H2T;
  unsigned short* A1P = E2B;
  unsigned short* A2P = E2B + 2 * M1;

  const dim3 T(256);
  const long sP = 262144;        // per-n pooled (1024x256)
  const long sNE = 2097152;      // per-n (4096x512)
  const long sE = 524288;        // per-n (1024x512)
  const long sD = 4194304;       // per-n (2048x2048)

  // --- prep + operand conversion ---
  prep_pool<<<dim3(1024, 4), T, 0, stream>>>(x1, Pb1);
  prep_pool<<<dim3(1024, 4), T, 0, stream>>>(x2, Pb2);
  transpose_b2b<<<dim3(4, 16, 4), T, 0, stream>>>(Pb1, Pt1, 1024, 256, sP, sP);
  transpose_b2b<<<dim3(4, 16, 4), T, 0, stream>>>(Pb2, Pt2, 1024, 256, sP, sP);
  convert_f2b<<<4096, T, 0, stream>>>(enc1, E1B, 1048576);
  convert_f2b<<<4096, T, 0, stream>>>(enc2, E2B, 1048576);
  transpose_f2b<<<dim3(16, 64), T, 0, stream>>>(enc1, E1T, 4096, 1024);
  WPtrs wp;
  wp.p[0] = (const float*)d_in[4];   // mlp_w1
  wp.p[1] = (const float*)d_in[6];   // mlp_w2
  wp.p[2] = (const float*)d_in[10];  // nlp_w1
  wp.p[3] = (const float*)d_in[12];  // nlp_w2
  wp.p[4] = (const float*)d_in[16];  // a1_wq
  wp.p[5] = (const float*)d_in[18];  // a1_wk
  wp.p[6] = (const float*)d_in[20];  // a1_wv
  wp.p[7] = (const float*)d_in[22];  // a1_fc
  wp.p[8] = (const float*)d_in[24];  // a2_wq
  wp.p[9] = (const float*)d_in[26];  // a2_wk
  wp.p[10] = (const float*)d_in[28]; // a2_wv
  wp.p[11] = (const float*)d_in[30]; // a2_fc
  wtrans<<<dim3(8, 8, 12), T, 0, stream>>>(wp, WT);

  // --- branch 1: node_enc -> MLP -> h1t ---
  gemm_mfma<0, 1><<<dim3(2, 32, 4), T, 0, stream>>>(
      E1B, Pt1, BA, nullptr, 1024, 1024, 1024, 512, 0, sP, sNE, 1.f);
  gemm_mfma<0, 1><<<dim3(2, 32, 4), T, 0, stream>>>(
      E2B, Pt1, BA + 256, nullptr, 1024, 1024, 1024, 512, 0, sP, sNE, 1.f);
  gemm_mfma<1, 1><<<dim3(4, 128, 1), T, 0, stream>>>(
      BA, WT + 0 * 262144, BB, mlp_b1, 512, 512, 512, 512, 0, 0, 0, 1.f);
  gemm_mfma<0, 1><<<dim3(4, 128, 1), T, 0, stream>>>(
      BB, WT + 1 * 262144, BA, mlp_b2, 512, 512, 512, 512, 0, 0, 0, 1.f);
  hipMemsetAsync(ST, 0, 1024 * sizeof(float), stream);
  bn_stats_b<<<128, T, 0, stream>>>(BA, ST);
  bn_apply_b<<<8192, T, 0, stream>>>(BA, BB, ST, mlp_g, mlp_be);
  transpose_b2b<<<dim3(8, 64, 4), T, 0, stream>>>(BB, H1T, 4096, 512, sNE, sNE);

  // --- branch 2 ---
  gemm_mfma<0, 1><<<dim3(2, 32, 4), T, 0, stream>>>(
      E1B, Pt2, BA, nullptr, 1024, 1024, 1024, 512, 0, sP, sNE, 1.f);
  gemm_mfma<0, 1><<<dim3(2, 32, 4), T, 0, stream>>>(
      E2B, Pt2, BA + 256, nullptr, 1024, 1024, 1024, 512, 0, sP, sNE, 1.f);
  gemm_mfma<1, 1><<<dim3(4, 128, 1), T, 0, stream>>>(
      BA, WT + 2 * 262144, BB, nlp_b1, 512, 512, 512, 512, 0, 0, 0, 1.f);
  gemm_mfma<0, 1><<<dim3(4, 128, 1), T, 0, stream>>>(
      BB, WT + 3 * 262144, BA, nlp_b2, 512, 512, 512, 512, 0, 0, 0, 1.f);
  hipMemsetAsync(ST, 0, 1024 * sizeof(float), stream);
  bn_stats_b<<<128, T, 0, stream>>>(BA, ST);
  bn_apply_b<<<8192, T, 0, stream>>>(BA, BB, ST, nlp_g, nlp_be);
  transpose_b2b<<<dim3(8, 64, 4), T, 0, stream>>>(BB, H2T, 4096, 512, sNE, sNE);

  // --- edge decode ---
  gemm_mfma<0, 1><<<dim3(4, 8, 4), T, 0, stream>>>(
      E1T, H1T, E1, nullptr, 4096, 4096, 4096, 512, 0, sNE, sE, 1.f / 1024.f);
  gemm_mfma<0, 1><<<dim3(4, 8, 4), T, 0, stream>>>(
      E1T, H2T, E2, nullptr, 4096, 4096, 4096, 512, 0, sNE, sE, 1.f / 1024.f);

  // --- attention 1: q=e2, k=v=e1 ---
  gemm_mfma<0, 0><<<dim3(4, 32, 1), T, 0, stream>>>(
      E2, WT + 4 * 262144, Qf, (const float*)d_in[17], 512, 512, 512, 512, 0, 0, 0, 1.f);
  gemm_mfma<0, 0><<<dim3(4, 32, 1), T, 0, stream>>>(
      E1, WT + 5 * 262144, Kf, (const float*)d_in[19], 512, 512, 512, 512, 0, 0, 0, 1.f);
  gemm_mfma<0, 0><<<dim3(4, 32, 1), T, 0, stream>>>(
      E1, WT + 6 * 262144, Vf, (const float*)d_in[21], 512, 512, 512, 512, 0, 0, 0, 1.f);
  flash_attn<<<dim3(16, 8, 4), T, 0, stream>>>(Qf, Kf, Vf, AO);
  gemm_mfma<0, 1><<<dim3(4, 32, 1), T, 0, stream>>>(
      AO, WT + 7 * 262144, A1P, (const float*)d_in[23], 512, 512, 512, 512, 0, 0, 0, 1.f);

  // --- attention 2: q=e1, k=v=e2 ---
  gemm_mfma<0, 0><<<dim3(4, 32, 1), T, 0, stream>>>(
      E1, WT + 8 * 262144, Qf, (const float*)d_in[25], 512, 512, 512, 512, 0, 0, 0, 1.f);
  gemm_mfma<0, 0><<<dim3(4, 32, 1), T, 0, stream>>>(
      E2, WT + 9 * 262144, Kf, (const float*)d_in[27], 512, 512, 512, 512, 0, 0, 0, 1.f);
  gemm_mfma<0, 0><<<dim3(4, 32, 1), T, 0, stream>>>(
      E2, WT + 10 * 262144, Vf, (const float*)d_in[29], 512, 512, 512, 512, 0, 0, 0, 1.f);
  flash_attn<<<dim3(16, 8, 4), T, 0, stream>>>(Qf, Kf, Vf, AO);
  gemm_mfma<0, 1><<<dim3(4, 32, 1), T, 0, stream>>>(
      AO, WT + 11 * 262144, A2P, (const float*)d_in[31], 512, 512, 512, 512, 0, 0, 0, 1.f);

  // --- logits quadrants into d_out ---
  gemm_mfma<0, 0><<<dim3(8, 8, 4), T, 0, stream>>>(
      A1P, A2P, out, nullptr, 512, 512, 512, 2048, sE, sE, sD, 1.f);
  gemm_mfma<0, 0><<<dim3(8, 8, 4), T, 0, stream>>>(
      A1P, A1P, out + 1024, nullptr, 512, 512, 512, 2048, sE, sE, sD, 1.f);
  gemm_mfma<0, 0><<<dim3(8, 8, 4), T, 0, stream>>>(
      A2P, A2P, out + 1024L * 2048, nullptr, 512, 512, 512, 2048, sE, sE, sD, 1.f);
  gemm_mfma<0, 0><<<dim3(8, 8, 4), T, 0, stream>>>(
      A2P, A1P, out + 1024L * 2048 + 1024, nullptr, 512, 512, 512, 2048, sE, sE, sD, 1.f);

  // --- softmax + column normalization ---
  softmax_rows<<<8192, T, 0, stream>>>(out);
  hipMemsetAsync(CS, 0, 8192 * sizeof(float), stream);
  colsum_kernel<<<dim3(8, 8, 4), T, 0, stream>>>(out, CS);
  scale_kernel<<<16384, T, 0, stream>>>(out, CS);
}

// Round 3
// 723.003 us; speedup vs baseline: 3.4248x; 1.3909x over previous
//
#include <hip/hip_runtime.h>
#include <hip/hip_bf16.h>

#define LEAKY(v) ((v) >= 0.f ? (v) : 0.01f * (v))

typedef __attribute__((ext_vector_type(8))) short short8b;
typedef __attribute__((ext_vector_type(4))) float f32x4;
typedef __attribute__((ext_vector_type(4))) unsigned short us4;

__device__ __forceinline__ unsigned short f2b(float f) {
  unsigned int u = __builtin_bit_cast(unsigned int, f);
  return (unsigned short)((u + 0x7FFFu + ((u >> 16) & 1u)) >> 16);
}
__device__ __forceinline__ float b2f(unsigned short s) {
  return __builtin_bit_cast(float, (unsigned int)s << 16);
}

__device__ __forceinline__ void gload16(const unsigned short* g, unsigned short* l) {
  __builtin_amdgcn_global_load_lds(
      (const __attribute__((address_space(1))) unsigned int*)(g),
      (__attribute__((address_space(3))) unsigned int*)(l), 16, 0, 0);
}

// Stage a 64x64 bf16 tile (rows of 128B) global->LDS with XOR swizzle
// LDS linear; global per-lane col pre-swizzled: LDS[row*128 + 16j] holds
// G[row][16*(j ^ (row&7)) bytes]. 2 gload16 per thread.
__device__ __forceinline__ void stage64(const unsigned short* g, int ldg,
                                        unsigned short* lds, int lane, int w) {
  const int r8 = lane >> 3;                  // 0..7
  const int ce = ((lane & 7) ^ r8) << 3;     // swizzled col, elems
  const int r0 = w * 8 + r8;
  gload16(g + (long)r0 * ldg + ce, lds + w * 512);
  gload16(g + (long)(r0 + 32) * ldg + ce, lds + 2048 + w * 512);
}

// Swizzled read of one 16B MFMA fragment slice: row 0..63, c4 = 16B col idx 0..7
__device__ __forceinline__ short8b ldsw(const unsigned short* base, int row, int c4) {
  return *(const short8b*)&base[row * 64 + (((c4 ^ (row & 7)) << 3))];
}

// ---------------------------------------------------------------------------
// prep + exact AdaptiveAvgPool1d -> bf16
// P[n,i,k] = mean_{m<16} X[n, (k&3)*16+m, i>>4, (i&15)*64 + (k>>2)]
// ---------------------------------------------------------------------------
__global__ __launch_bounds__(256) void prep_pool(const float* __restrict__ X,
                                                 unsigned short* __restrict__ P) {
  const int i = blockIdx.x, n = blockIdx.y;
  const int t = i >> 4;
  const int vvb = (i & 15) * 64;
  __shared__ float tile[64][65];
  const int tid = threadIdx.x;
  const long base = (((long)n * 64) * 64 + t) * 1024 + vvb;
#pragma unroll
  for (int it = 0; it < 16; ++it) {
    int idx = tid + it * 256;
    int c = idx >> 6, w = idx & 63;
    tile[c][w] = X[base + (long)c * 64 * 1024 + w];
  }
  __syncthreads();
  const int k = tid;
  const int w = k >> 2, cb = (k & 3) * 16;
  float s = 0.f;
#pragma unroll
  for (int m = 0; m < 16; ++m) s += tile[cb + m][w];
  P[((long)n * 1024 + i) * 256 + k] = f2b(s * (1.f / 16.f));
}

// ---------------------------------------------------------------------------
// fp32 (R x C) -> bf16 (C x R) transpose
// ---------------------------------------------------------------------------
__global__ __launch_bounds__(256) void transpose_f2b(
    const float* __restrict__ in, unsigned short* __restrict__ out, int R, int C) {
  __shared__ float t[64][65];
  const int c0 = blockIdx.x * 64, r0 = blockIdx.y * 64;
  const int tid = threadIdx.x;
#pragma unroll
  for (int it = 0; it < 4; ++it) {
    int idx = tid + it * 256;
    int r = idx >> 4, c4 = (idx & 15) * 4;
    float4 v = *(const float4*)&in[(long)(r0 + r) * C + c0 + c4];
    t[c4 + 0][r] = v.x; t[c4 + 1][r] = v.y;
    t[c4 + 2][r] = v.z; t[c4 + 3][r] = v.w;
  }
  __syncthreads();
#pragma unroll
  for (int it = 0; it < 4; ++it) {
    int idx = tid + it * 256;
    int c = idx >> 4, r4 = (idx & 15) * 4;
    us4 o;
    o[0] = f2b(t[c][r4 + 0]); o[1] = f2b(t[c][r4 + 1]);
    o[2] = f2b(t[c][r4 + 2]); o[3] = f2b(t[c][r4 + 3]);
    *(us4*)&out[(long)(c0 + c) * R + r0 + r4] = o;
  }
}

// fused 12x 512x512 weight transpose+convert
struct WPtrs { const float* p[12]; };
__global__ __launch_bounds__(256) void wtrans(WPtrs wp, unsigned short* __restrict__ out) {
  const float* in = wp.p[blockIdx.z];
  unsigned short* ob = out + (long)blockIdx.z * 262144;
  __shared__ float t[64][65];
  const int c0 = blockIdx.x * 64, r0 = blockIdx.y * 64;
  const int tid = threadIdx.x;
#pragma unroll
  for (int it = 0; it < 4; ++it) {
    int idx = tid + it * 256;
    int r = idx >> 4, c4 = (idx & 15) * 4;
    float4 v = *(const float4*)&in[(long)(r0 + r) * 512 + c0 + c4];
    t[c4 + 0][r] = v.x; t[c4 + 1][r] = v.y;
    t[c4 + 2][r] = v.z; t[c4 + 3][r] = v.w;
  }
  __syncthreads();
#pragma unroll
  for (int it = 0; it < 4; ++it) {
    int idx = tid + it * 256;
    int c = idx >> 4, r4 = (idx & 15) * 4;
    us4 o;
    o[0] = f2b(t[c][r4 + 0]); o[1] = f2b(t[c][r4 + 1]);
    o[2] = f2b(t[c][r4 + 2]); o[3] = f2b(t[c][r4 + 3]);
    *(us4*)&ob[(long)(c0 + c) * 512 + r0 + r4] = o;
  }
}

// bf16 (R x C) -> bf16 (C x R) transpose, batched over z
__global__ __launch_bounds__(256) void transpose_b2b(
    const unsigned short* __restrict__ in, unsigned short* __restrict__ out,
    int R, int C, long sIn, long sOut) {
  const unsigned short* ib = in + (long)blockIdx.z * sIn;
  unsigned short* ob = out + (long)blockIdx.z * sOut;
  __shared__ unsigned short t[64][65];
  const int c0 = blockIdx.x * 64, r0 = blockIdx.y * 64;
  const int tid = threadIdx.x;
#pragma unroll
  for (int it = 0; it < 2; ++it) {
    int idx = tid + it * 256;
    int r = idx >> 3, c8 = (idx & 7) * 8;
    short8b v = *(const short8b*)&ib[(long)(r0 + r) * C + c0 + c8];
#pragma unroll
    for (int j = 0; j < 8; ++j) t[c8 + j][r] = (unsigned short)v[j];
  }
  __syncthreads();
#pragma unroll
  for (int it = 0; it < 4; ++it) {
    int idx = tid + it * 256;
    int c = idx >> 4, r4 = (idx & 15) * 4;
    us4 o;
    o[0] = t[c][r4 + 0]; o[1] = t[c][r4 + 1];
    o[2] = t[c][r4 + 2]; o[3] = t[c][r4 + 3];
    *(us4*)&ob[(long)(c0 + c) * R + r0 + r4] = o;
  }
}

// straight fp32 -> bf16 convert (n4 = count/4)
__global__ __launch_bounds__(256) void convert_f2b(const float* __restrict__ in,
                                                   unsigned short* __restrict__ out,
                                                   long n4) {
  long i = (long)blockIdx.x * 256 + threadIdx.x;
  if (i < n4) {
    float4 v = ((const float4*)in)[i];
    us4 o;
    o[0] = f2b(v.x); o[1] = f2b(v.y); o[2] = f2b(v.z); o[3] = f2b(v.w);
    ((us4*)out)[i] = o;
  }
}

// ---------------------------------------------------------------------------
// bf16 MFMA GEMM, 128x128 tile, BK=64, 4 waves (2x2 of 64x64).
// A: M x K row-major bf16.  B: N x K row-major bf16 (i.e. B^T layout).
// CMODE: 0 = fp32 out, 1 = bf16 out, 2 = bf16 out in attn-V^T layout
//        (out[(row>>10)*524288 + col*1024 + (row&1023)], i.e. (n, hd, l)).
// ---------------------------------------------------------------------------
template <int ACT, int CMODE>
__global__ __launch_bounds__(256) void gemm_mfma(
    const unsigned short* __restrict__ A, const unsigned short* __restrict__ B,
    void* __restrict__ Cv, const float* __restrict__ bias, int K, int lda,
    int ldb, int ldc, long sA, long sB, long sC, float alpha) {
  const int m0 = blockIdx.y * 128, n0 = blockIdx.x * 128;
  const unsigned short* Ab = A + (long)blockIdx.z * sA;
  const unsigned short* Bb = B + (long)blockIdx.z * sB;
  const int tid = threadIdx.x;
  const int lane = tid & 63, w = tid >> 6;
  const int wr = (w >> 1) * 64, wc = (w & 1) * 64;
  __shared__ unsigned short As[128 * 64];
  __shared__ unsigned short Bs[128 * 64];
  f32x4 acc[4][4];
#pragma unroll
  for (int i = 0; i < 4; ++i)
#pragma unroll
    for (int j = 0; j < 4; ++j) acc[i][j] = (f32x4){0.f, 0.f, 0.f, 0.f};
  const int srow = tid >> 3, scol = (tid & 7) * 8;
  const int rl = lane & 15, kl = (lane >> 4) * 8;
  for (int k0 = 0; k0 < K; k0 += 64) {
    __syncthreads();
#pragma unroll
    for (int it = 0; it < 4; ++it) {
      gload16(Ab + (long)(m0 + it * 32 + srow) * lda + k0 + scol,
              As + w * 512 + it * 2048);
      gload16(Bb + (long)(n0 + it * 32 + srow) * ldb + k0 + scol,
              Bs + w * 512 + it * 2048);
    }
    __syncthreads();
#pragma unroll
    for (int kk = 0; kk < 64; kk += 32) {
      short8b af[4], bfr[4];
#pragma unroll
      for (int m = 0; m < 4; ++m)
        af[m] = *(const short8b*)&As[(wr + m * 16 + rl) * 64 + kk + kl];
#pragma unroll
      for (int nn = 0; nn < 4; ++nn)
        bfr[nn] = *(const short8b*)&Bs[(wc + nn * 16 + rl) * 64 + kk + kl];
#pragma unroll
      for (int m = 0; m < 4; ++m)
#pragma unroll
        for (int nn = 0; nn < 4; ++nn)
          acc[m][nn] = __builtin_amdgcn_mfma_f32_16x16x32_bf16(
              af[m], bfr[nn], acc[m][nn], 0, 0, 0);
    }
  }
  const int rrow = (lane >> 4) * 4;
  float bv[4];
#pragma unroll
  for (int nn = 0; nn < 4; ++nn)
    bv[nn] = bias ? bias[n0 + wc + nn * 16 + rl] : 0.f;
  if (CMODE == 2) {
#pragma unroll
    for (int m = 0; m < 4; ++m)
#pragma unroll
      for (int nn = 0; nn < 4; ++nn) {
        const int row = m0 + wr + m * 16 + rrow;
        const int col = n0 + wc + nn * 16 + rl;
        us4 o;
#pragma unroll
        for (int r = 0; r < 4; ++r) {
          float v = alpha * acc[m][nn][r] + bv[nn];
          if (ACT == 1) v = LEAKY(v);
          o[r] = f2b(v);
        }
        const long off =
            (long)(row >> 10) * 524288 + (long)col * 1024 + (row & 1023);
        *(us4*)&((unsigned short*)Cv)[off] = o;
      }
  } else {
#pragma unroll
    for (int m = 0; m < 4; ++m)
#pragma unroll
      for (int nn = 0; nn < 4; ++nn)
#pragma unroll
        for (int r = 0; r < 4; ++r) {
          float v = alpha * acc[m][nn][r] + bv[nn];
          if (ACT == 1) v = LEAKY(v);
          long off = (long)blockIdx.z * sC +
                     (long)(m0 + wr + m * 16 + rrow + r) * ldc + n0 + wc +
                     nn * 16 + rl;
          if (CMODE == 1)
            ((unsigned short*)Cv)[off] = f2b(v);
          else
            ((float*)Cv)[off] = v;
        }
  }
}

// ---------------------------------------------------------------------------
// BatchNorm over flattened (16384, 512), bf16 in/out
// ---------------------------------------------------------------------------
__global__ __launch_bounds__(256) void bn_stats_b(const unsigned short* __restrict__ X,
                                                  float* __restrict__ ST) {
  const int tid = threadIdx.x;
  const unsigned short* p = X + (long)blockIdx.x * 128 * 512;
  float s0 = 0.f, q0 = 0.f, s1 = 0.f, q1 = 0.f;
  for (int r = 0; r < 128; ++r) {
    const float a = b2f(p[r * 512 + tid]);
    const float b = b2f(p[r * 512 + tid + 256]);
    s0 += a; q0 += a * a; s1 += b; q1 += b * b;
  }
  atomicAdd(&ST[tid], s0);
  atomicAdd(&ST[512 + tid], q0);
  atomicAdd(&ST[tid + 256], s1);
  atomicAdd(&ST[512 + tid + 256], q1);
}

__global__ __launch_bounds__(256) void bn_apply_b(
    const unsigned short* __restrict__ X, unsigned short* __restrict__ Y,
    const float* __restrict__ ST, const float* __restrict__ g,
    const float* __restrict__ be) {
  const long p = ((long)blockIdx.x * 256 + threadIdx.x) * 4;
  const int c = (int)(p & 511);
  us4 x = *(const us4*)&X[p];
  us4 y;
#pragma unroll
  for (int j = 0; j < 4; ++j) {
    const int col = c + j;
    const float mu = ST[col] * (1.f / 16384.f);
    const float var = ST[512 + col] * (1.f / 16384.f) - mu * mu;
    float v = (b2f(x[j]) - mu) * rsqrtf(var + 1e-5f) * g[col] + be[col];
    y[j] = f2b(LEAKY(v));
  }
  *(us4*)&Y[p] = y;
}

// ---------------------------------------------------------------------------
// bf16 MFMA flash attention. Q,K: (n,1024,512) bf16; Vt: (n,512,1024) bf16.
// Grid (qb=16, h=8, n=4), 256 threads (4 waves, 16 q-rows each).
// Swapped QK^T (lane owns q = w*16 + (lane&15)); P via per-wave LDS rows;
// all LDS tiles XOR-swizzled (linear dest + pre-swizzled global src).
// ---------------------------------------------------------------------------
__global__ __launch_bounds__(256) void attn_mfma(
    const unsigned short* __restrict__ Q, const unsigned short* __restrict__ K,
    const unsigned short* __restrict__ Vt, unsigned short* __restrict__ O) {
  const int qb = blockIdx.x, h = blockIdx.y, n = blockIdx.z;
  const int tid = threadIdx.x;
  const int lane = tid & 63, w = tid >> 6;
  const int rl = lane & 15, lg = lane >> 4;
  __shared__ unsigned short Qs[4096];
  __shared__ unsigned short Ks[4096];
  __shared__ unsigned short Vs[4096];
  __shared__ unsigned short Ps[4096];
  stage64(Q + ((long)n * 1024 + qb * 64) * 512 + h * 64, 512, Qs, lane, w);
  float m_r = -1e30f, l_r = 0.f;
  f32x4 po[4];
#pragma unroll
  for (int i = 0; i < 4; ++i) po[i] = (f32x4){0.f, 0.f, 0.f, 0.f};
  const unsigned short* Kg0 = K + ((long)n * 1024) * 512 + h * 64;
  const unsigned short* Vg0 = Vt + (long)n * 524288 + (long)(h * 64) * 1024;
  for (int kt = 0; kt < 16; ++kt) {
    __syncthreads();
    stage64(Kg0 + (long)(kt * 64) * 512, 512, Ks, lane, w);
    stage64(Vg0 + kt * 64, 1024, Vs, lane, w);
    __syncthreads();
    // S^T[key][q] = sum_d K[key][d] Q[q][d] ; wave w covers q = w*16..+15
    f32x4 sa[4];
#pragma unroll
    for (int i = 0; i < 4; ++i) sa[i] = (f32x4){0.f, 0.f, 0.f, 0.f};
#pragma unroll
    for (int kk = 0; kk < 2; ++kk) {
      const short8b qf = ldsw(Qs, w * 16 + rl, 4 * kk + lg);
#pragma unroll
      for (int mt = 0; mt < 4; ++mt) {
        const short8b kf = ldsw(Ks, mt * 16 + rl, 4 * kk + lg);
        sa[mt] = __builtin_amdgcn_mfma_f32_16x16x32_bf16(kf, qf, sa[mt], 0, 0, 0);
      }
    }
    // online softmax: lane's q = w*16+rl; lane holds keys 16*mt + 4*lg + r
    float pr[4][4];
    float mx = -1e30f;
#pragma unroll
    for (int mt = 0; mt < 4; ++mt)
#pragma unroll
      for (int r = 0; r < 4; ++r) {
        pr[mt][r] = sa[mt][r] * 0.125f;
        mx = fmaxf(mx, pr[mt][r]);
      }
    mx = fmaxf(mx, __shfl_xor(mx, 16, 64));
    mx = fmaxf(mx, __shfl_xor(mx, 32, 64));
    const float mn = fmaxf(m_r, mx);
    const float f = __expf(m_r - mn);
    m_r = mn;
    float ps = 0.f;
    const int q = w * 16 + rl;
#pragma unroll
    for (int mt = 0; mt < 4; ++mt) {
      us4 o;
#pragma unroll
      for (int r = 0; r < 4; ++r) {
        const float p = __expf(pr[mt][r] - mn);
        ps += p;
        o[r] = f2b(p);
      }
      const int c16 = (4 * mt + lg) >> 1;
      *(us4*)&Ps[q * 64 + ((c16 ^ (q & 7)) << 3) + ((lg & 1) << 2)] = o;
    }
    ps += __shfl_xor(ps, 16, 64);
    ps += __shfl_xor(ps, 32, 64);
    l_r = l_r * f + ps;
#pragma unroll
    for (int r = 0; r < 4; ++r) {
      const float fr = __shfl(f, lg * 4 + r, 64);
#pragma unroll
      for (int nt = 0; nt < 4; ++nt) po[nt][r] *= fr;
    }
    // O[q][d] += P[q][key] V[key][d]
#pragma unroll
    for (int kk = 0; kk < 2; ++kk) {
      const short8b pf = ldsw(Ps, w * 16 + rl, 4 * kk + lg);
#pragma unroll
      for (int nt = 0; nt < 4; ++nt) {
        const short8b vf = ldsw(Vs, nt * 16 + rl, 4 * kk + lg);
        po[nt] = __builtin_amdgcn_mfma_f32_16x16x32_bf16(pf, vf, po[nt], 0, 0, 0);
      }
    }
  }
  float invr[4];
#pragma unroll
  for (int r = 0; r < 4; ++r) invr[r] = 1.f / __shfl(l_r, lg * 4 + r, 64);
  const long ob = ((long)n * 1024 + qb * 64 + w * 16) * 512 + h * 64;
#pragma unroll
  for (int nt = 0; nt < 4; ++nt)
#pragma unroll
    for (int r = 0; r < 4; ++r)
      O[ob + (long)(lg * 4 + r) * 512 + nt * 16 + rl] = f2b(po[nt][r] * invr[r]);
}

// ---------------------------------------------------------------------------
// Row softmax over 2048-wide rows of d_out
// ---------------------------------------------------------------------------
__global__ __launch_bounds__(256) void softmax_rows(float* __restrict__ D) {
  float* p = D + (long)blockIdx.x * 2048;
  const int tid = threadIdx.x;
  const int wv = tid >> 6, ln = tid & 63;
  float v[8];
  float mx = -1e30f;
#pragma unroll
  for (int k = 0; k < 8; ++k) {
    v[k] = p[tid + k * 256];
    mx = fmaxf(mx, v[k]);
  }
#pragma unroll
  for (int mask = 1; mask < 64; mask <<= 1) mx = fmaxf(mx, __shfl_xor(mx, mask, 64));
  __shared__ float red[8];
  if (ln == 0) red[wv] = mx;
  __syncthreads();
  mx = fmaxf(fmaxf(red[0], red[1]), fmaxf(red[2], red[3]));
  float s = 0.f;
#pragma unroll
  for (int k = 0; k < 8; ++k) {
    v[k] = __expf(v[k] - mx);
    s += v[k];
  }
#pragma unroll
  for (int mask = 1; mask < 64; mask <<= 1) s += __shfl_xor(s, mask, 64);
  if (ln == 0) red[4 + wv] = s;
  __syncthreads();
  s = red[4] + red[5] + red[6] + red[7];
  const float inv = 1.f / s;
#pragma unroll
  for (int k = 0; k < 8; ++k) p[tid + k * 256] = v[k] * inv;
}

__global__ __launch_bounds__(256) void colsum_kernel(const float* __restrict__ D,
                                                     float* __restrict__ CS) {
  const int j = blockIdx.x * 256 + threadIdx.x;
  const int n = blockIdx.z;
  const long base = ((long)n * 2048 + blockIdx.y * 256) * 2048 + j;
  float s = 0.f;
  for (int i = 0; i < 256; ++i) s += D[base + (long)i * 2048];
  atomicAdd(&CS[n * 2048 + j], s);
}

__global__ __launch_bounds__(256) void scale_kernel(float* __restrict__ D,
                                                    const float* __restrict__ CS) {
  const long p = ((long)blockIdx.x * 256 + threadIdx.x) * 4;
  const int n = (int)(p >> 22);
  const int j = (int)(p & 2047);
  float4 v = *(float4*)&D[p];
  const float* c = &CS[n * 2048 + j];
  v.x *= (c[0] > 0.f ? 1.f / c[0] : 0.f);
  v.y *= (c[1] > 0.f ? 1.f / c[1] : 0.f);
  v.z *= (c[2] > 0.f ? 1.f / c[2] : 0.f);
  v.w *= (c[3] > 0.f ? 1.f / c[3] : 0.f);
  *(float4*)&D[p] = v;
}

// ---------------------------------------------------------------------------
extern "C" void kernel_launch(void* const* d_in, const int* in_sizes, int n_in,
                              void* d_out, int out_size, void* d_ws,
                              size_t ws_size, hipStream_t stream) {
  const float* x1 = (const float*)d_in[0];
  const float* x2 = (const float*)d_in[1];
  const float* enc1 = (const float*)d_in[2];
  const float* enc2 = (const float*)d_in[3];
  const float* mlp_b1 = (const float*)d_in[5];
  const float* mlp_b2 = (const float*)d_in[7];
  const float* mlp_g = (const float*)d_in[8];
  const float* mlp_be = (const float*)d_in[9];
  const float* nlp_b1 = (const float*)d_in[11];
  const float* nlp_b2 = (const float*)d_in[13];
  const float* nlp_g = (const float*)d_in[14];
  const float* nlp_be = (const float*)d_in[15];
  float* out = (float*)d_out;

  unsigned short* W = (unsigned short*)d_ws;
  const long M1 = 1L << 20;
  unsigned short* Pb1 = W;
  unsigned short* Pb2 = W + M1;
  unsigned short* Pt1 = W + 2 * M1;
  unsigned short* Pt2 = W + 3 * M1;
  unsigned short* E1B = W + 4 * M1;
  unsigned short* E2B = W + 8 * M1;
  unsigned short* E1T = W + 12 * M1;
  unsigned short* WT = W + 16 * M1;   // 12 x 262144
  unsigned short* BA = W + 20 * M1;   // 8M us scratch
  unsigned short* BB = W + 28 * M1;   // 8M us scratch
  unsigned short* H1T = W + 36 * M1;  // 8M us
  unsigned short* H2T = W + 44 * M1;  // 8M us
  unsigned short* E1 = W + 52 * M1;   // 2M us
  unsigned short* E2 = W + 54 * M1;   // 2M us
  float* ST = (float*)(W + 56 * M1);
  float* CS = ST + 1024;
  unsigned short* QB = BA;            // (4,1024,512) bf16
  unsigned short* KB = BA + 2 * M1;
  unsigned short* VtB = BA + 4 * M1;  // (4,512,1024) bf16
  unsigned short* AO = BA + 6 * M1;
  unsigned short* A1P = E2B;          // (4,1024,512)
  unsigned short* A2P = E2B + 2 * M1;

  const dim3 T(256);
  const long sP = 262144;
  const long sNE = 2097152;
  const long sE = 524288;
  const long sD = 4194304;

  // --- prep + operand conversion ---
  prep_pool<<<dim3(1024, 4), T, 0, stream>>>(x1, Pb1);
  prep_pool<<<dim3(1024, 4), T, 0, stream>>>(x2, Pb2);
  transpose_b2b<<<dim3(4, 16, 4), T, 0, stream>>>(Pb1, Pt1, 1024, 256, sP, sP);
  transpose_b2b<<<dim3(4, 16, 4), T, 0, stream>>>(Pb2, Pt2, 1024, 256, sP, sP);
  convert_f2b<<<4096, T, 0, stream>>>(enc1, E1B, 1048576);
  convert_f2b<<<4096, T, 0, stream>>>(enc2, E2B, 1048576);
  transpose_f2b<<<dim3(16, 64), T, 0, stream>>>(enc1, E1T, 4096, 1024);
  WPtrs wp;
  wp.p[0] = (const float*)d_in[4];
  wp.p[1] = (const float*)d_in[6];
  wp.p[2] = (const float*)d_in[10];
  wp.p[3] = (const float*)d_in[12];
  wp.p[4] = (const float*)d_in[16];
  wp.p[5] = (const float*)d_in[18];
  wp.p[6] = (const float*)d_in[20];
  wp.p[7] = (const float*)d_in[22];
  wp.p[8] = (const float*)d_in[24];
  wp.p[9] = (const float*)d_in[26];
  wp.p[10] = (const float*)d_in[28];
  wp.p[11] = (const float*)d_in[30];
  wtrans<<<dim3(8, 8, 12), T, 0, stream>>>(wp, WT);

  // --- branch 1: node_enc -> MLP -> h1t ---
  gemm_mfma<0, 1><<<dim3(2, 32, 4), T, 0, stream>>>(
      E1B, Pt1, BA, nullptr, 1024, 1024, 1024, 512, 0, sP, sNE, 1.f);
  gemm_mfma<0, 1><<<dim3(2, 32, 4), T, 0, stream>>>(
      E2B, Pt1, BA + 256, nullptr, 1024, 1024, 1024, 512, 0, sP, sNE, 1.f);
  gemm_mfma<1, 1><<<dim3(4, 128, 1), T, 0, stream>>>(
      BA, WT + 0 * 262144, BB, mlp_b1, 512, 512, 512, 512, 0, 0, 0, 1.f);
  gemm_mfma<0, 1><<<dim3(4, 128, 1), T, 0, stream>>>(
      BB, WT + 1 * 262144, BA, mlp_b2, 512, 512, 512, 512, 0, 0, 0, 1.f);
  hipMemsetAsync(ST, 0, 1024 * sizeof(float), stream);
  bn_stats_b<<<128, T, 0, stream>>>(BA, ST);
  bn_apply_b<<<8192, T, 0, stream>>>(BA, BB, ST, mlp_g, mlp_be);
  transpose_b2b<<<dim3(8, 64, 4), T, 0, stream>>>(BB, H1T, 4096, 512, sNE, sNE);

  // --- branch 2 ---
  gemm_mfma<0, 1><<<dim3(2, 32, 4), T, 0, stream>>>(
      E1B, Pt2, BA, nullptr, 1024, 1024, 1024, 512, 0, sP, sNE, 1.f);
  gemm_mfma<0, 1><<<dim3(2, 32, 4), T, 0, stream>>>(
      E2B, Pt2, BA + 256, nullptr, 1024, 1024, 1024, 512, 0, sP, sNE, 1.f);
  gemm_mfma<1, 1><<<dim3(4, 128, 1), T, 0, stream>>>(
      BA, WT + 2 * 262144, BB, nlp_b1, 512, 512, 512, 512, 0, 0, 0, 1.f);
  gemm_mfma<0, 1><<<dim3(4, 128, 1), T, 0, stream>>>(
      BB, WT + 3 * 262144, BA, nlp_b2, 512, 512, 512, 512, 0, 0, 0, 1.f);
  hipMemsetAsync(ST, 0, 1024 * sizeof(float), stream);
  bn_stats_b<<<128, T, 0, stream>>>(BA, ST);
  bn_apply_b<<<8192, T, 0, stream>>>(BA, BB, ST, nlp_g, nlp_be);
  transpose_b2b<<<dim3(8, 64, 4), T, 0, stream>>>(BB, H2T, 4096, 512, sNE, sNE);

  // --- edge decode ---
  gemm_mfma<0, 1><<<dim3(4, 8, 4), T, 0, stream>>>(
      E1T, H1T, E1, nullptr, 4096, 4096, 4096, 512, 0, sNE, sE, 1.f / 1024.f);
  gemm_mfma<0, 1><<<dim3(4, 8, 4), T, 0, stream>>>(
      E1T, H2T, E2, nullptr, 4096, 4096, 4096, 512, 0, sNE, sE, 1.f / 1024.f);

  // --- attention 1: q=e2, k=v=e1 ---
  gemm_mfma<0, 1><<<dim3(4, 32, 1), T, 0, stream>>>(
      E2, WT + 4 * 262144, QB, (const float*)d_in[17], 512, 512, 512, 512, 0, 0, 0, 1.f);
  gemm_mfma<0, 1><<<dim3(4, 32, 1), T, 0, stream>>>(
      E1, WT + 5 * 262144, KB, (const float*)d_in[19], 512, 512, 512, 512, 0, 0, 0, 1.f);
  gemm_mfma<0, 2><<<dim3(4, 32, 1), T, 0, stream>>>(
      E1, WT + 6 * 262144, VtB, (const float*)d_in[21], 512, 512, 512, 512, 0, 0, 0, 1.f);
  attn_mfma<<<dim3(16, 8, 4), T, 0, stream>>>(QB, KB, VtB, AO);
  gemm_mfma<0, 1><<<dim3(4, 32, 1), T, 0, stream>>>(
      AO, WT + 7 * 262144, A1P, (const float*)d_in[23], 512, 512, 512, 512, 0, 0, 0, 1.f);

  // --- attention 2: q=e1, k=v=e2 ---
  gemm_mfma<0, 1><<<dim3(4, 32, 1), T, 0, stream>>>(
      E1, WT + 8 * 262144, QB, (const float*)d_in[25], 512, 512, 512, 512, 0, 0, 0, 1.f);
  gemm_mfma<0, 1><<<dim3(4, 32, 1), T, 0, stream>>>(
      E2, WT + 9 * 262144, KB, (const float*)d_in[27], 512, 512, 512, 512, 0, 0, 0, 1.f);
  gemm_mfma<0, 2><<<dim3(4, 32, 1), T, 0, stream>>>(
      E2, WT + 10 * 262144, VtB, (const float*)d_in[29], 512, 512, 512, 512, 0, 0, 0, 1.f);
  attn_mfma<<<dim3(16, 8, 4), T, 0, stream>>>(QB, KB, VtB, AO);
  gemm_mfma<0, 1><<<dim3(4, 32, 1), T, 0, stream>>>(
      AO, WT + 11 * 262144, A2P, (const float*)d_in[31], 512, 512, 512, 512, 0, 0, 0, 1.f);

  // --- logits quadrants into d_out ---
  gemm_mfma<0, 0><<<dim3(8, 8, 4), T, 0, stream>>>(
      A1P, A2P, out, nullptr, 512, 512, 512, 2048, sE, sE, sD, 1.f);
  gemm_mfma<0, 0><<<dim3(8, 8, 4), T, 0, stream>>>(
      A1P, A1P, out + 1024, nullptr, 512, 512, 512, 2048, sE, sE, sD, 1.f);
  gemm_mfma<0, 0><<<dim3(8, 8, 4), T, 0, stream>>>(
      A2P, A2P, out + 1024L * 2048, nullptr, 512, 512, 512, 2048, sE, sE, sD, 1.f);
  gemm_mfma<0, 0><<<dim3(8, 8, 4), T, 0, stream>>>(
      A2P, A1P, out + 1024L * 2048 + 1024, nullptr, 512, 512, 512, 2048, sE, sE, sD, 1.f);

  // --- softmax + column normalization ---
  softmax_rows<<<8192, T, 0, stream>>>(out);
  hipMemsetAsync(CS, 0, 8192 * sizeof(float), stream);
  colsum_kernel<<<dim3(8, 8, 4), T, 0, stream>>>(out, CS);
  scale_kernel<<<16384, T, 0, stream>>>(out, CS);
}

// Round 4
// 520.347 us; speedup vs baseline: 4.7586x; 1.3895x over previous
//
#include <hip/hip_runtime.h>
#include <hip/hip_bf16.h>

#define LEAKY(v) ((v) >= 0.f ? (v) : 0.01f * (v))

typedef __attribute__((ext_vector_type(8))) short short8b;
typedef __attribute__((ext_vector_type(4))) float f32x4;
typedef __attribute__((ext_vector_type(4))) unsigned short us4;

__device__ __forceinline__ unsigned short f2b(float f) {
  unsigned int u = __builtin_bit_cast(unsigned int, f);
  return (unsigned short)((u + 0x7FFFu + ((u >> 16) & 1u)) >> 16);
}
__device__ __forceinline__ float b2f(unsigned short s) {
  return __builtin_bit_cast(float, (unsigned int)s << 16);
}

__device__ __forceinline__ void gload16(const unsigned short* g, unsigned short* l) {
  __builtin_amdgcn_global_load_lds(
      (const __attribute__((address_space(1))) unsigned int*)(g),
      (__attribute__((address_space(3))) unsigned int*)(l), 16, 0, 0);
}

// Stage a 64x64 bf16 tile (rows of 128B) global->LDS, XOR-swizzled source.
__device__ __forceinline__ void stage64(const unsigned short* g, int ldg,
                                        unsigned short* lds, int lane, int w) {
  const int r8 = lane >> 3;
  const int ce = ((lane & 7) ^ r8) << 3;
  const int r0 = w * 8 + r8;
  gload16(g + (long)r0 * ldg + ce, lds + w * 512);
  gload16(g + (long)(r0 + 32) * ldg + ce, lds + 2048 + w * 512);
}

// Swizzled 16B read: row, c4 = 16B-column index 0..7
__device__ __forceinline__ short8b ldsw(const unsigned short* base, int row, int c4) {
  return *(const short8b*)&base[row * 64 + (((c4 ^ (row & 7)) << 3))];
}

// ---------------------------------------------------------------------------
// prep + exact AdaptiveAvgPool1d -> bf16
// ---------------------------------------------------------------------------
__global__ __launch_bounds__(256) void prep_pool(const float* __restrict__ X,
                                                 unsigned short* __restrict__ P) {
  const int i = blockIdx.x, n = blockIdx.y;
  const int t = i >> 4;
  const int vvb = (i & 15) * 64;
  __shared__ float tile[64][65];
  const int tid = threadIdx.x;
  const long base = (((long)n * 64) * 64 + t) * 1024 + vvb;
#pragma unroll
  for (int it = 0; it < 16; ++it) {
    int idx = tid + it * 256;
    int c = idx >> 6, w = idx & 63;
    tile[c][w] = X[base + (long)c * 64 * 1024 + w];
  }
  __syncthreads();
  const int k = tid;
  const int w = k >> 2, cb = (k & 3) * 16;
  float s = 0.f;
#pragma unroll
  for (int m = 0; m < 16; ++m) s += tile[cb + m][w];
  P[((long)n * 1024 + i) * 256 + k] = f2b(s * (1.f / 16.f));
}

// ---------------------------------------------------------------------------
// fp32 (R x C) -> bf16 (C x R) transpose
// ---------------------------------------------------------------------------
__global__ __launch_bounds__(256) void transpose_f2b(
    const float* __restrict__ in, unsigned short* __restrict__ out, int R, int C) {
  __shared__ float t[64][65];
  const int c0 = blockIdx.x * 64, r0 = blockIdx.y * 64;
  const int tid = threadIdx.x;
#pragma unroll
  for (int it = 0; it < 4; ++it) {
    int idx = tid + it * 256;
    int r = idx >> 4, c4 = (idx & 15) * 4;
    float4 v = *(const float4*)&in[(long)(r0 + r) * C + c0 + c4];
    t[c4 + 0][r] = v.x; t[c4 + 1][r] = v.y;
    t[c4 + 2][r] = v.z; t[c4 + 3][r] = v.w;
  }
  __syncthreads();
#pragma unroll
  for (int it = 0; it < 4; ++it) {
    int idx = tid + it * 256;
    int c = idx >> 4, r4 = (idx & 15) * 4;
    us4 o;
    o[0] = f2b(t[c][r4 + 0]); o[1] = f2b(t[c][r4 + 1]);
    o[2] = f2b(t[c][r4 + 2]); o[3] = f2b(t[c][r4 + 3]);
    *(us4*)&out[(long)(c0 + c) * R + r0 + r4] = o;
  }
}

// fused 12x 512x512 weight transpose+convert
struct WPtrs { const float* p[12]; };
__global__ __launch_bounds__(256) void wtrans(WPtrs wp, unsigned short* __restrict__ out) {
  const float* in = wp.p[blockIdx.z];
  unsigned short* ob = out + (long)blockIdx.z * 262144;
  __shared__ float t[64][65];
  const int c0 = blockIdx.x * 64, r0 = blockIdx.y * 64;
  const int tid = threadIdx.x;
#pragma unroll
  for (int it = 0; it < 4; ++it) {
    int idx = tid + it * 256;
    int r = idx >> 4, c4 = (idx & 15) * 4;
    float4 v = *(const float4*)&in[(long)(r0 + r) * 512 + c0 + c4];
    t[c4 + 0][r] = v.x; t[c4 + 1][r] = v.y;
    t[c4 + 2][r] = v.z; t[c4 + 3][r] = v.w;
  }
  __syncthreads();
#pragma unroll
  for (int it = 0; it < 4; ++it) {
    int idx = tid + it * 256;
    int c = idx >> 4, r4 = (idx & 15) * 4;
    us4 o;
    o[0] = f2b(t[c][r4 + 0]); o[1] = f2b(t[c][r4 + 1]);
    o[2] = f2b(t[c][r4 + 2]); o[3] = f2b(t[c][r4 + 3]);
    *(us4*)&ob[(long)(c0 + c) * 512 + r0 + r4] = o;
  }
}

// bf16 (R x C) -> bf16 (C x R) transpose, batched over z
__global__ __launch_bounds__(256) void transpose_b2b(
    const unsigned short* __restrict__ in, unsigned short* __restrict__ out,
    int R, int C, long sIn, long sOut) {
  const unsigned short* ib = in + (long)blockIdx.z * sIn;
  unsigned short* ob = out + (long)blockIdx.z * sOut;
  __shared__ unsigned short t[64][65];
  const int c0 = blockIdx.x * 64, r0 = blockIdx.y * 64;
  const int tid = threadIdx.x;
#pragma unroll
  for (int it = 0; it < 2; ++it) {
    int idx = tid + it * 256;
    int r = idx >> 3, c8 = (idx & 7) * 8;
    short8b v = *(const short8b*)&ib[(long)(r0 + r) * C + c0 + c8];
#pragma unroll
    for (int j = 0; j < 8; ++j) t[c8 + j][r] = (unsigned short)v[j];
  }
  __syncthreads();
#pragma unroll
  for (int it = 0; it < 4; ++it) {
    int idx = tid + it * 256;
    int c = idx >> 4, r4 = (idx & 15) * 4;
    us4 o;
    o[0] = t[c][r4 + 0]; o[1] = t[c][r4 + 1];
    o[2] = t[c][r4 + 2]; o[3] = t[c][r4 + 3];
    *(us4*)&ob[(long)(c0 + c) * R + r0 + r4] = o;
  }
}

// straight fp32 -> bf16 convert (n4 = count/4)
__global__ __launch_bounds__(256) void convert_f2b(const float* __restrict__ in,
                                                   unsigned short* __restrict__ out,
                                                   long n4) {
  long i = (long)blockIdx.x * 256 + threadIdx.x;
  if (i < n4) {
    float4 v = ((const float4*)in)[i];
    us4 o;
    o[0] = f2b(v.x); o[1] = f2b(v.y); o[2] = f2b(v.z); o[3] = f2b(v.w);
    ((us4*)out)[i] = o;
  }
}

// add two fp32 partials, scale, convert to bf16. count = gridDim*1024 elems
__global__ __launch_bounds__(256) void addcvt(const float* __restrict__ P0,
                                              const float* __restrict__ P1,
                                              unsigned short* __restrict__ out,
                                              float alpha) {
  const long i = ((long)blockIdx.x * 256 + threadIdx.x) * 4;
  const float4 a = *(const float4*)&P0[i];
  const float4 b = *(const float4*)&P1[i];
  us4 o;
  o[0] = f2b((a.x + b.x) * alpha);
  o[1] = f2b((a.y + b.y) * alpha);
  o[2] = f2b((a.z + b.z) * alpha);
  o[3] = f2b((a.w + b.w) * alpha);
  *(us4*)&out[i] = o;
}

// ---------------------------------------------------------------------------
// bf16 MFMA GEMM, 128x128 tile, BK=64, 4 waves; XOR-swizzled LDS.
// A: M x K row-major. B: N x K row-major (B^T layout).
// Per-z A pointer select: bit bz of amask ? A2 : A. Per-z bias bp.p[bz&3].
// KSPLIT=2: bz=(zb<<1)|s, K = chunk size, cols offset s*K, C += s*sC2 (fp32).
// CMODE: 0 fp32 out, 1 bf16 out, 2 bf16 out in attn-V^T layout.
// ---------------------------------------------------------------------------
struct BPtrs { const float* p[4]; };

template <int ACT, int CMODE, int KSPLIT>
__global__ __launch_bounds__(256) void gemm_mfma(
    const unsigned short* __restrict__ A, const unsigned short* __restrict__ A2,
    unsigned amask, const unsigned short* __restrict__ B,
    void* __restrict__ Cv, BPtrs bp, int K, int lda, int ldb, int ldc,
    long sA, long sB, long sC, long sC2, float alpha) {
  const int bz = blockIdx.z;
  const int s = (KSPLIT > 1) ? (bz & 1) : 0;
  const int zb = (KSPLIT > 1) ? (bz >> 1) : bz;
  const int m0 = blockIdx.y * 128, n0 = blockIdx.x * 128;
  const unsigned short* Ab =
      (((amask >> bz) & 1) ? A2 : A) + (long)zb * sA + (long)s * K;
  const unsigned short* Bb = B + (long)zb * sB + (long)s * K;
  const float* bias = bp.p[bz & 3];
  const int tid = threadIdx.x;
  const int lane = tid & 63, w = tid >> 6;
  const int wr = (w >> 1) * 64, wc = (w & 1) * 64;
  __shared__ unsigned short As[128 * 64];
  __shared__ unsigned short Bs[128 * 64];
  f32x4 acc[4][4];
#pragma unroll
  for (int i = 0; i < 4; ++i)
#pragma unroll
    for (int j = 0; j < 4; ++j) acc[i][j] = (f32x4){0.f, 0.f, 0.f, 0.f};
  const int srow = tid >> 3;
  const int scol = (((tid & 7) ^ ((tid >> 3) & 7)) << 3);  // swizzled source col
  const int rl = lane & 15, lg = lane >> 4, rx = rl & 7;
  for (int k0 = 0; k0 < K; k0 += 64) {
    __syncthreads();
#pragma unroll
    for (int it = 0; it < 4; ++it) {
      gload16(Ab + (long)(m0 + it * 32 + srow) * lda + k0 + scol,
              As + w * 512 + it * 2048);
      gload16(Bb + (long)(n0 + it * 32 + srow) * ldb + k0 + scol,
              Bs + w * 512 + it * 2048);
    }
    __syncthreads();
#pragma unroll
    for (int kk = 0; kk < 2; ++kk) {
      short8b af[4], bfr[4];
#pragma unroll
      for (int m = 0; m < 4; ++m)
        af[m] = *(const short8b*)&As[(wr + m * 16 + rl) * 64 +
                                     ((((kk * 4 + lg) ^ rx)) << 3)];
#pragma unroll
      for (int nn = 0; nn < 4; ++nn)
        bfr[nn] = *(const short8b*)&Bs[(wc + nn * 16 + rl) * 64 +
                                       ((((kk * 4 + lg) ^ rx)) << 3)];
#pragma unroll
      for (int m = 0; m < 4; ++m)
#pragma unroll
        for (int nn = 0; nn < 4; ++nn)
          acc[m][nn] = __builtin_amdgcn_mfma_f32_16x16x32_bf16(
              af[m], bfr[nn], acc[m][nn], 0, 0, 0);
    }
  }
  const int rrow = lg * 4;
  float bv[4];
#pragma unroll
  for (int nn = 0; nn < 4; ++nn)
    bv[nn] = bias ? bias[n0 + wc + nn * 16 + rl] : 0.f;
  if (CMODE == 2) {
#pragma unroll
    for (int m = 0; m < 4; ++m)
#pragma unroll
      for (int nn = 0; nn < 4; ++nn) {
        const int row = m0 + wr + m * 16 + rrow;
        const int col = n0 + wc + nn * 16 + rl;
        us4 o;
#pragma unroll
        for (int r = 0; r < 4; ++r) {
          float v = alpha * acc[m][nn][r] + bv[nn];
          if (ACT == 1) v = LEAKY(v);
          o[r] = f2b(v);
        }
        const long off = (long)zb * sC + (long)(row >> 10) * 524288 +
                         (long)col * 1024 + (row & 1023);
        *(us4*)&((unsigned short*)Cv)[off] = o;
      }
  } else {
#pragma unroll
    for (int m = 0; m < 4; ++m)
#pragma unroll
      for (int nn = 0; nn < 4; ++nn)
#pragma unroll
        for (int r = 0; r < 4; ++r) {
          float v = alpha * acc[m][nn][r] + bv[nn];
          if (ACT == 1) v = LEAKY(v);
          long off = (long)zb * sC + (long)s * sC2 +
                     (long)(m0 + wr + m * 16 + rrow + r) * ldc + n0 + wc +
                     nn * 16 + rl;
          if (CMODE == 1)
            ((unsigned short*)Cv)[off] = f2b(v);
          else
            ((float*)Cv)[off] = v;
        }
  }
}

// ---------------------------------------------------------------------------
// BatchNorm over flattened (16384, 512), bf16 in/out
// ---------------------------------------------------------------------------
__global__ __launch_bounds__(256) void bn_stats_b(const unsigned short* __restrict__ X,
                                                  float* __restrict__ ST) {
  const int tid = threadIdx.x;
  const unsigned short* p = X + (long)blockIdx.x * 128 * 512;
  float s0 = 0.f, q0 = 0.f, s1 = 0.f, q1 = 0.f;
  for (int r = 0; r < 128; ++r) {
    const float a = b2f(p[r * 512 + tid]);
    const float b = b2f(p[r * 512 + tid + 256]);
    s0 += a; q0 += a * a; s1 += b; q1 += b * b;
  }
  atomicAdd(&ST[tid], s0);
  atomicAdd(&ST[512 + tid], q0);
  atomicAdd(&ST[tid + 256], s1);
  atomicAdd(&ST[512 + tid + 256], q1);
}

__global__ __launch_bounds__(256) void bn_apply_b(
    const unsigned short* __restrict__ X, unsigned short* __restrict__ Y,
    const float* __restrict__ ST, const float* __restrict__ g,
    const float* __restrict__ be) {
  const long p = ((long)blockIdx.x * 256 + threadIdx.x) * 4;
  const int c = (int)(p & 511);
  us4 x = *(const us4*)&X[p];
  us4 y;
#pragma unroll
  for (int j = 0; j < 4; ++j) {
    const int col = c + j;
    const float mu = ST[col] * (1.f / 16384.f);
    const float var = ST[512 + col] * (1.f / 16384.f) - mu * mu;
    float v = (b2f(x[j]) - mu) * rsqrtf(var + 1e-5f) * g[col] + be[col];
    y[j] = f2b(LEAKY(v));
  }
  *(us4*)&Y[p] = y;
}

// ---------------------------------------------------------------------------
// bf16 MFMA flash attention, both attentions in one dispatch (z = 8:
// sel = z>>2 picks att1/att2 buffer sets, n = z&3).
// ---------------------------------------------------------------------------
__global__ __launch_bounds__(256) void attn_mfma(
    const unsigned short* __restrict__ Q, const unsigned short* __restrict__ K,
    const unsigned short* __restrict__ Vt, unsigned short* __restrict__ O) {
  const int qb = blockIdx.x, h = blockIdx.y;
  const int n = blockIdx.z & 3, sel = blockIdx.z >> 2;
  Q += (long)sel * 4194304;
  K += (long)sel * 4194304;
  Vt += (long)sel * 2097152;
  O += (long)sel * 2097152;
  const int tid = threadIdx.x;
  const int lane = tid & 63, w = tid >> 6;
  const int rl = lane & 15, lg = lane >> 4;
  __shared__ unsigned short Qs[4096];
  __shared__ unsigned short Ks[4096];
  __shared__ unsigned short Vs[4096];
  __shared__ unsigned short Ps[4096];
  stage64(Q + ((long)n * 1024 + qb * 64) * 512 + h * 64, 512, Qs, lane, w);
  float m_r = -1e30f, l_r = 0.f;
  f32x4 po[4];
#pragma unroll
  for (int i = 0; i < 4; ++i) po[i] = (f32x4){0.f, 0.f, 0.f, 0.f};
  const unsigned short* Kg0 = K + ((long)n * 1024) * 512 + h * 64;
  const unsigned short* Vg0 = Vt + (long)n * 524288 + (long)(h * 64) * 1024;
  for (int kt = 0; kt < 16; ++kt) {
    __syncthreads();
    stage64(Kg0 + (long)(kt * 64) * 512, 512, Ks, lane, w);
    stage64(Vg0 + kt * 64, 1024, Vs, lane, w);
    __syncthreads();
    f32x4 sa[4];
#pragma unroll
    for (int i = 0; i < 4; ++i) sa[i] = (f32x4){0.f, 0.f, 0.f, 0.f};
#pragma unroll
    for (int kk = 0; kk < 2; ++kk) {
      const short8b qf = ldsw(Qs, w * 16 + rl, 4 * kk + lg);
#pragma unroll
      for (int mt = 0; mt < 4; ++mt) {
        const short8b kf = ldsw(Ks, mt * 16 + rl, 4 * kk + lg);
        sa[mt] = __builtin_amdgcn_mfma_f32_16x16x32_bf16(kf, qf, sa[mt], 0, 0, 0);
      }
    }
    float pr[4][4];
    float mx = -1e30f;
#pragma unroll
    for (int mt = 0; mt < 4; ++mt)
#pragma unroll
      for (int r = 0; r < 4; ++r) {
        pr[mt][r] = sa[mt][r] * 0.125f;
        mx = fmaxf(mx, pr[mt][r]);
      }
    mx = fmaxf(mx, __shfl_xor(mx, 16, 64));
    mx = fmaxf(mx, __shfl_xor(mx, 32, 64));
    const float mn = fmaxf(m_r, mx);
    const float f = __expf(m_r - mn);
    m_r = mn;
    float ps = 0.f;
    const int q = w * 16 + rl;
#pragma unroll
    for (int mt = 0; mt < 4; ++mt) {
      us4 o;
#pragma unroll
      for (int r = 0; r < 4; ++r) {
        const float p = __expf(pr[mt][r] - mn);
        ps += p;
        o[r] = f2b(p);
      }
      const int c16 = (4 * mt + lg) >> 1;
      *(us4*)&Ps[q * 64 + ((c16 ^ (q & 7)) << 3) + ((lg & 1) << 2)] = o;
    }
    ps += __shfl_xor(ps, 16, 64);
    ps += __shfl_xor(ps, 32, 64);
    l_r = l_r * f + ps;
#pragma unroll
    for (int r = 0; r < 4; ++r) {
      const float fr = __shfl(f, lg * 4 + r, 64);
#pragma unroll
      for (int nt = 0; nt < 4; ++nt) po[nt][r] *= fr;
    }
#pragma unroll
    for (int kk = 0; kk < 2; ++kk) {
      const short8b pf = ldsw(Ps, w * 16 + rl, 4 * kk + lg);
#pragma unroll
      for (int nt = 0; nt < 4; ++nt) {
        const short8b vf = ldsw(Vs, nt * 16 + rl, 4 * kk + lg);
        po[nt] = __builtin_amdgcn_mfma_f32_16x16x32_bf16(pf, vf, po[nt], 0, 0, 0);
      }
    }
  }
  float invr[4];
#pragma unroll
  for (int r = 0; r < 4; ++r) invr[r] = 1.f / __shfl(l_r, lg * 4 + r, 64);
  const long ob = ((long)n * 1024 + qb * 64 + w * 16) * 512 + h * 64;
#pragma unroll
  for (int nt = 0; nt < 4; ++nt)
#pragma unroll
    for (int r = 0; r < 4; ++r)
      O[ob + (long)(lg * 4 + r) * 512 + nt * 16 + rl] = f2b(po[nt][r] * invr[r]);
}

// ---------------------------------------------------------------------------
// Row softmax over 2048-wide rows of d_out
// ---------------------------------------------------------------------------
__global__ __launch_bounds__(256) void softmax_rows(float* __restrict__ D) {
  float* p = D + (long)blockIdx.x * 2048;
  const int tid = threadIdx.x;
  const int wv = tid >> 6, ln = tid & 63;
  float v[8];
  float mx = -1e30f;
#pragma unroll
  for (int k = 0; k < 8; ++k) {
    v[k] = p[tid + k * 256];
    mx = fmaxf(mx, v[k]);
  }
#pragma unroll
  for (int mask = 1; mask < 64; mask <<= 1) mx = fmaxf(mx, __shfl_xor(mx, mask, 64));
  __shared__ float red[8];
  if (ln == 0) red[wv] = mx;
  __syncthreads();
  mx = fmaxf(fmaxf(red[0], red[1]), fmaxf(red[2], red[3]));
  float s = 0.f;
#pragma unroll
  for (int k = 0; k < 8; ++k) {
    v[k] = __expf(v[k] - mx);
    s += v[k];
  }
#pragma unroll
  for (int mask = 1; mask < 64; mask <<= 1) s += __shfl_xor(s, mask, 64);
  if (ln == 0) red[4 + wv] = s;
  __syncthreads();
  s = red[4] + red[5] + red[6] + red[7];
  const float inv = 1.f / s;
#pragma unroll
  for (int k = 0; k < 8; ++k) p[tid + k * 256] = v[k] * inv;
}

__global__ __launch_bounds__(256) void colsum_kernel(const float* __restrict__ D,
                                                     float* __restrict__ CS) {
  const int j = blockIdx.x * 256 + threadIdx.x;
  const int n = blockIdx.z;
  const long base = ((long)n * 2048 + blockIdx.y * 256) * 2048 + j;
  float s = 0.f;
  for (int i = 0; i < 256; ++i) s += D[base + (long)i * 2048];
  atomicAdd(&CS[n * 2048 + j], s);
}

__global__ __launch_bounds__(256) void scale_kernel(float* __restrict__ D,
                                                    const float* __restrict__ CS) {
  const long p = ((long)blockIdx.x * 256 + threadIdx.x) * 4;
  const int n = (int)(p >> 22);
  const int j = (int)(p & 2047);
  float4 v = *(float4*)&D[p];
  const float* c = &CS[n * 2048 + j];
  v.x *= (c[0] > 0.f ? 1.f / c[0] : 0.f);
  v.y *= (c[1] > 0.f ? 1.f / c[1] : 0.f);
  v.z *= (c[2] > 0.f ? 1.f / c[2] : 0.f);
  v.w *= (c[3] > 0.f ? 1.f / c[3] : 0.f);
  *(float4*)&D[p] = v;
}

// ---------------------------------------------------------------------------
extern "C" void kernel_launch(void* const* d_in, const int* in_sizes, int n_in,
                              void* d_out, int out_size, void* d_ws,
                              size_t ws_size, hipStream_t stream) {
  const float* x1 = (const float*)d_in[0];
  const float* x2 = (const float*)d_in[1];
  const float* enc1 = (const float*)d_in[2];
  const float* enc2 = (const float*)d_in[3];
  const float* mlp_b1 = (const float*)d_in[5];
  const float* mlp_b2 = (const float*)d_in[7];
  const float* mlp_g = (const float*)d_in[8];
  const float* mlp_be = (const float*)d_in[9];
  const float* nlp_b1 = (const float*)d_in[11];
  const float* nlp_b2 = (const float*)d_in[13];
  const float* nlp_g = (const float*)d_in[14];
  const float* nlp_be = (const float*)d_in[15];
  float* out = (float*)d_out;

  unsigned short* W = (unsigned short*)d_ws;
  const long M1 = 1L << 20;
  const long S = 262144;
  unsigned short* Pb1 = W;
  unsigned short* Pb2 = W + M1;
  unsigned short* Pt1 = W + 2 * M1;
  unsigned short* Pt2 = W + 3 * M1;
  unsigned short* E1B = W + 4 * M1;
  unsigned short* E2B = W + 8 * M1;
  unsigned short* E1T = W + 12 * M1;
  unsigned short* WT = W + 16 * M1;   // 12 x 262144
  unsigned short* BA = W + 20 * M1;   // 8M us scratch
  unsigned short* BB = W + 28 * M1;   // 8M us scratch
  unsigned short* H1T = W + 36 * M1;  // 8M us
  unsigned short* H2T = W + 44 * M1;  // 8M us (contiguous after H1T)
  unsigned short* E1 = W + 52 * M1;   // 2M us
  unsigned short* E2 = W + 54 * M1;   // 2M us (contiguous after E1)
  float* ST = (float*)(W + 56 * M1);
  float* CS = ST + 1024;
  // edge-decode split-K partials (over BA+BB, dead at that point)
  float* P0f = (float*)BA;            // 4M floats
  float* P1f = (float*)BB;            // 4M floats
  // attention buffers (after addcvt, BA/BB free again)
  unsigned short* QB1 = BA;
  unsigned short* KB1 = BA + 2 * M1;
  unsigned short* QB2 = BA + 4 * M1;
  unsigned short* KB2 = BA + 6 * M1;
  unsigned short* Vt1 = BB;
  unsigned short* Vt2 = BB + 2 * M1;
  unsigned short* AO1 = BB + 4 * M1;
  unsigned short* AO2 = BB + 6 * M1;
  unsigned short* A1P = E2B;          // (4,1024,512)
  unsigned short* A2P = E2B + 2 * M1;

  const dim3 T(256);
  const long sP = 262144;
  const long sNE = 2097152;
  const long sE = 524288;
  const long sD = 4194304;
  BPtrs nb = {{nullptr, nullptr, nullptr, nullptr}};

  // --- prep + operand conversion ---
  prep_pool<<<dim3(1024, 4), T, 0, stream>>>(x1, Pb1);
  prep_pool<<<dim3(1024, 4), T, 0, stream>>>(x2, Pb2);
  transpose_b2b<<<dim3(4, 16, 4), T, 0, stream>>>(Pb1, Pt1, 1024, 256, sP, sP);
  transpose_b2b<<<dim3(4, 16, 4), T, 0, stream>>>(Pb2, Pt2, 1024, 256, sP, sP);
  convert_f2b<<<4096, T, 0, stream>>>(enc1, E1B, 1048576);
  convert_f2b<<<4096, T, 0, stream>>>(enc2, E2B, 1048576);
  transpose_f2b<<<dim3(16, 64), T, 0, stream>>>(enc1, E1T, 4096, 1024);
  WPtrs wp;
  wp.p[0] = (const float*)d_in[4];   // mlp_w1
  wp.p[1] = (const float*)d_in[6];   // mlp_w2
  wp.p[2] = (const float*)d_in[10];  // nlp_w1
  wp.p[3] = (const float*)d_in[12];  // nlp_w2
  wp.p[4] = (const float*)d_in[16];  // a1_wq
  wp.p[5] = (const float*)d_in[18];  // a1_wk
  wp.p[6] = (const float*)d_in[24];  // a2_wq
  wp.p[7] = (const float*)d_in[26];  // a2_wk
  wp.p[8] = (const float*)d_in[20];  // a1_wv
  wp.p[9] = (const float*)d_in[28];  // a2_wv
  wp.p[10] = (const float*)d_in[22]; // a1_fc
  wp.p[11] = (const float*)d_in[30]; // a2_fc
  wtrans<<<dim3(8, 8, 12), T, 0, stream>>>(wp, WT);

  // --- branch 1: node_enc -> MLP -> h1t ---
  gemm_mfma<0, 1, 1><<<dim3(2, 32, 4), T, 0, stream>>>(
      E1B, E1B, 0, Pt1, BA, nb, 1024, 1024, 1024, 512, 0, sP, sNE, 0, 1.f);
  gemm_mfma<0, 1, 1><<<dim3(2, 32, 4), T, 0, stream>>>(
      E2B, E2B, 0, Pt1, BA + 256, nb, 1024, 1024, 1024, 512, 0, sP, sNE, 0, 1.f);
  BPtrs bm1 = {{mlp_b1, nullptr, nullptr, nullptr}};
  BPtrs bm2 = {{mlp_b2, nullptr, nullptr, nullptr}};
  gemm_mfma<1, 1, 1><<<dim3(4, 128, 1), T, 0, stream>>>(
      BA, BA, 0, WT + 0 * S, BB, bm1, 512, 512, 512, 512, 0, 0, 0, 0, 1.f);
  gemm_mfma<0, 1, 1><<<dim3(4, 128, 1), T, 0, stream>>>(
      BB, BB, 0, WT + 1 * S, BA, bm2, 512, 512, 512, 512, 0, 0, 0, 0, 1.f);
  hipMemsetAsync(ST, 0, 1024 * sizeof(float), stream);
  bn_stats_b<<<128, T, 0, stream>>>(BA, ST);
  bn_apply_b<<<8192, T, 0, stream>>>(BA, BB, ST, mlp_g, mlp_be);
  transpose_b2b<<<dim3(8, 64, 4), T, 0, stream>>>(BB, H1T, 4096, 512, sNE, sNE);

  // --- branch 2 ---
  gemm_mfma<0, 1, 1><<<dim3(2, 32, 4), T, 0, stream>>>(
      E1B, E1B, 0, Pt2, BA, nb, 1024, 1024, 1024, 512, 0, sP, sNE, 0, 1.f);
  gemm_mfma<0, 1, 1><<<dim3(2, 32, 4), T, 0, stream>>>(
      E2B, E2B, 0, Pt2, BA + 256, nb, 1024, 1024, 1024, 512, 0, sP, sNE, 0, 1.f);
  BPtrs bn1 = {{nlp_b1, nullptr, nullptr, nullptr}};
  BPtrs bn2 = {{nlp_b2, nullptr, nullptr, nullptr}};
  gemm_mfma<1, 1, 1><<<dim3(4, 128, 1), T, 0, stream>>>(
      BA, BA, 0, WT + 2 * S, BB, bn1, 512, 512, 512, 512, 0, 0, 0, 0, 1.f);
  gemm_mfma<0, 1, 1><<<dim3(4, 128, 1), T, 0, stream>>>(
      BB, BB, 0, WT + 3 * S, BA, bn2, 512, 512, 512, 512, 0, 0, 0, 0, 1.f);
  hipMemsetAsync(ST, 0, 1024 * sizeof(float), stream);
  bn_stats_b<<<128, T, 0, stream>>>(BA, ST);
  bn_apply_b<<<8192, T, 0, stream>>>(BA, BB, ST, nlp_g, nlp_be);
  transpose_b2b<<<dim3(8, 64, 4), T, 0, stream>>>(BB, H2T, 4096, 512, sNE, sNE);

  // --- edge decode: merged (h1,h2 -> z=8) + split-K=2 into fp32 partials ---
  gemm_mfma<0, 0, 2><<<dim3(4, 8, 16), T, 0, stream>>>(
      E1T, E1T, 0, H1T, P0f, nb, 2048, 4096, 4096, 512, 0, sNE, 524288,
      4194304, 1.f);
  addcvt<<<4096, T, 0, stream>>>(P0f, P1f, E1, 1.f / 1024.f);  // fills E1+E2

  // --- projections: Q1,K1,Q2,K2 (z=4); V1,V2 (z=2) ---
  BPtrs bqk = {{(const float*)d_in[17], (const float*)d_in[19],
                (const float*)d_in[25], (const float*)d_in[27]}};
  gemm_mfma<0, 1, 1><<<dim3(4, 32, 4), T, 0, stream>>>(
      E1, E2, 0b1001u, WT + 4 * S, QB1, bqk, 512, 512, 512, 512, 0, S,
      2097152, 0, 1.f);
  BPtrs bvv = {{(const float*)d_in[21], (const float*)d_in[29], nullptr,
                nullptr}};
  gemm_mfma<0, 2, 1><<<dim3(4, 32, 2), T, 0, stream>>>(
      E1, E2, 0b10u, WT + 8 * S, Vt1, bvv, 512, 512, 512, 512, 0, S, 2097152,
      0, 1.f);

  // --- both attentions in one dispatch ---
  attn_mfma<<<dim3(16, 8, 8), T, 0, stream>>>(QB1, KB1, Vt1, AO1);

  // --- fc for both attentions (z=2) ---
  BPtrs bfc = {{(const float*)d_in[23], (const float*)d_in[31], nullptr,
                nullptr}};
  gemm_mfma<0, 1, 1><<<dim3(4, 32, 2), T, 0, stream>>>(
      AO1, AO2, 0b10u, WT + 10 * S, A1P, bfc, 512, 512, 512, 512, 0, S,
      2097152, 0, 1.f);

  // --- logits quadrants into d_out ---
  gemm_mfma<0, 0, 1><<<dim3(8, 8, 4), T, 0, stream>>>(
      A1P, A1P, 0, A2P, out, nb, 512, 512, 512, 2048, sE, sE, sD, 0, 1.f);
  gemm_mfma<0, 0, 1><<<dim3(8, 8, 4), T, 0, stream>>>(
      A1P, A1P, 0, A1P, out + 1024, nb, 512, 512, 512, 2048, sE, sE, sD, 0, 1.f);
  gemm_mfma<0, 0, 1><<<dim3(8, 8, 4), T, 0, stream>>>(
      A2P, A2P, 0, A2P, out + 1024L * 2048, nb, 512, 512, 512, 2048, sE, sE,
      sD, 0, 1.f);
  gemm_mfma<0, 0, 1><<<dim3(8, 8, 4), T, 0, stream>>>(
      A2P, A2P, 0, A1P, out + 1024L * 2048 + 1024, nb, 512, 512, 512, 2048,
      sE, sE, sD, 0, 1.f);

  // --- softmax + column normalization ---
  softmax_rows<<<8192, T, 0, stream>>>(out);
  hipMemsetAsync(CS, 0, 8192 * sizeof(float), stream);
  colsum_kernel<<<dim3(8, 8, 4), T, 0, stream>>>(out, CS);
  scale_kernel<<<16384, T, 0, stream>>>(out, CS);
}

// Round 5
// 413.027 us; speedup vs baseline: 5.9950x; 1.2598x over previous
//
#include <hip/hip_runtime.h>
#include <hip/hip_bf16.h>

#define LEAKY(v) ((v) >= 0.f ? (v) : 0.01f * (v))

typedef __attribute__((ext_vector_type(8))) short short8b;
typedef __attribute__((ext_vector_type(4))) float f32x4;
typedef __attribute__((ext_vector_type(4))) unsigned short us4;

__device__ __forceinline__ unsigned short f2b(float f) {
  unsigned int u = __builtin_bit_cast(unsigned int, f);
  return (unsigned short)((u + 0x7FFFu + ((u >> 16) & 1u)) >> 16);
}
__device__ __forceinline__ float b2f(unsigned short s) {
  return __builtin_bit_cast(float, (unsigned int)s << 16);
}

__device__ __forceinline__ void gload16(const unsigned short* g, unsigned short* l) {
  __builtin_amdgcn_global_load_lds(
      (const __attribute__((address_space(1))) unsigned int*)(g),
      (__attribute__((address_space(3))) unsigned int*)(l), 16, 0, 0);
}

// Stage a 64x64 bf16 tile (rows of 128B) global->LDS, XOR-swizzled source.
__device__ __forceinline__ void stage64(const unsigned short* g, int ldg,
                                        unsigned short* lds, int lane, int w) {
  const int r8 = lane >> 3;
  const int ce = ((lane & 7) ^ r8) << 3;
  const int r0 = w * 8 + r8;
  gload16(g + (long)r0 * ldg + ce, lds + w * 512);
  gload16(g + (long)(r0 + 32) * ldg + ce, lds + 2048 + w * 512);
}

// Swizzled 16B read: row, c4 = 16B-column index 0..7
__device__ __forceinline__ short8b ldsw(const unsigned short* base, int row, int c4) {
  return *(const short8b*)&base[row * 64 + (((c4 ^ (row & 7)) << 3))];
}

// ---------------------------------------------------------------------------
// prep + exact AdaptiveAvgPool1d -> bf16 (both inputs, z selects)
// ---------------------------------------------------------------------------
__global__ __launch_bounds__(256) void prep_pool(const float* __restrict__ X1,
                                                 const float* __restrict__ X2,
                                                 unsigned short* __restrict__ P) {
  const float* X = blockIdx.z ? X2 : X1;
  unsigned short* Pb = P + (long)blockIdx.z * (1L << 20);
  const int i = blockIdx.x, n = blockIdx.y;
  const int t = i >> 4;
  const int vvb = (i & 15) * 64;
  __shared__ float tile[64][65];
  const int tid = threadIdx.x;
  const long base = (((long)n * 64) * 64 + t) * 1024 + vvb;
#pragma unroll
  for (int it = 0; it < 16; ++it) {
    int idx = tid + it * 256;
    int c = idx >> 6, w = idx & 63;
    tile[c][w] = X[base + (long)c * 64 * 1024 + w];
  }
  __syncthreads();
  const int k = tid;
  const int w = k >> 2, cb = (k & 3) * 16;
  float s = 0.f;
#pragma unroll
  for (int m = 0; m < 16; ++m) s += tile[cb + m][w];
  Pb[((long)n * 1024 + i) * 256 + k] = f2b(s * (1.f / 16.f));
}

// ---------------------------------------------------------------------------
// fp32 (R x C) -> bf16 (C x R) transpose
// ---------------------------------------------------------------------------
__global__ __launch_bounds__(256) void transpose_f2b(
    const float* __restrict__ in, unsigned short* __restrict__ out, int R, int C) {
  __shared__ float t[64][65];
  const int c0 = blockIdx.x * 64, r0 = blockIdx.y * 64;
  const int tid = threadIdx.x;
#pragma unroll
  for (int it = 0; it < 4; ++it) {
    int idx = tid + it * 256;
    int r = idx >> 4, c4 = (idx & 15) * 4;
    float4 v = *(const float4*)&in[(long)(r0 + r) * C + c0 + c4];
    t[c4 + 0][r] = v.x; t[c4 + 1][r] = v.y;
    t[c4 + 2][r] = v.z; t[c4 + 3][r] = v.w;
  }
  __syncthreads();
#pragma unroll
  for (int it = 0; it < 4; ++it) {
    int idx = tid + it * 256;
    int c = idx >> 4, r4 = (idx & 15) * 4;
    us4 o;
    o[0] = f2b(t[c][r4 + 0]); o[1] = f2b(t[c][r4 + 1]);
    o[2] = f2b(t[c][r4 + 2]); o[3] = f2b(t[c][r4 + 3]);
    *(us4*)&out[(long)(c0 + c) * R + r0 + r4] = o;
  }
}

// fused 12x 512x512 weight transpose+convert
struct WPtrs { const float* p[12]; };
__global__ __launch_bounds__(256) void wtrans(WPtrs wp, unsigned short* __restrict__ out) {
  const float* in = wp.p[blockIdx.z];
  unsigned short* ob = out + (long)blockIdx.z * 262144;
  __shared__ float t[64][65];
  const int c0 = blockIdx.x * 64, r0 = blockIdx.y * 64;
  const int tid = threadIdx.x;
#pragma unroll
  for (int it = 0; it < 4; ++it) {
    int idx = tid + it * 256;
    int r = idx >> 4, c4 = (idx & 15) * 4;
    float4 v = *(const float4*)&in[(long)(r0 + r) * 512 + c0 + c4];
    t[c4 + 0][r] = v.x; t[c4 + 1][r] = v.y;
    t[c4 + 2][r] = v.z; t[c4 + 3][r] = v.w;
  }
  __syncthreads();
#pragma unroll
  for (int it = 0; it < 4; ++it) {
    int idx = tid + it * 256;
    int c = idx >> 4, r4 = (idx & 15) * 4;
    us4 o;
    o[0] = f2b(t[c][r4 + 0]); o[1] = f2b(t[c][r4 + 1]);
    o[2] = f2b(t[c][r4 + 2]); o[3] = f2b(t[c][r4 + 3]);
    *(us4*)&ob[(long)(c0 + c) * 512 + r0 + r4] = o;
  }
}

// bf16 (R x C) -> bf16 (C x R) transpose, batched over z
__global__ __launch_bounds__(256) void transpose_b2b(
    const unsigned short* __restrict__ in, unsigned short* __restrict__ out,
    int R, int C, long sIn, long sOut) {
  const unsigned short* ib = in + (long)blockIdx.z * sIn;
  unsigned short* ob = out + (long)blockIdx.z * sOut;
  __shared__ unsigned short t[64][65];
  const int c0 = blockIdx.x * 64, r0 = blockIdx.y * 64;
  const int tid = threadIdx.x;
#pragma unroll
  for (int it = 0; it < 2; ++it) {
    int idx = tid + it * 256;
    int r = idx >> 3, c8 = (idx & 7) * 8;
    short8b v = *(const short8b*)&ib[(long)(r0 + r) * C + c0 + c8];
#pragma unroll
    for (int j = 0; j < 8; ++j) t[c8 + j][r] = (unsigned short)v[j];
  }
  __syncthreads();
#pragma unroll
  for (int it = 0; it < 4; ++it) {
    int idx = tid + it * 256;
    int c = idx >> 4, r4 = (idx & 15) * 4;
    us4 o;
    o[0] = t[c][r4 + 0]; o[1] = t[c][r4 + 1];
    o[2] = t[c][r4 + 2]; o[3] = t[c][r4 + 3];
    *(us4*)&ob[(long)(c0 + c) * R + r0 + r4] = o;
  }
}

// fp32 -> bf16 convert, two inputs (z selects), each n4=1048576 quads
__global__ __launch_bounds__(256) void convert2_f2b(const float* __restrict__ i1,
                                                    const float* __restrict__ i2,
                                                    unsigned short* __restrict__ out) {
  const float* in = blockIdx.z ? i2 : i1;
  unsigned short* o = out + (long)blockIdx.z * (4L << 20);
  long i = (long)blockIdx.x * 256 + threadIdx.x;
  float4 v = ((const float4*)in)[i];
  us4 q;
  q[0] = f2b(v.x); q[1] = f2b(v.y); q[2] = f2b(v.z); q[3] = f2b(v.w);
  ((us4*)o)[i] = q;
}

// add two fp32 partials, scale, convert to bf16
__global__ __launch_bounds__(256) void addcvt(const float* __restrict__ P0,
                                              const float* __restrict__ P1,
                                              unsigned short* __restrict__ out,
                                              float alpha) {
  const long i = ((long)blockIdx.x * 256 + threadIdx.x) * 4;
  const float4 a = *(const float4*)&P0[i];
  const float4 b = *(const float4*)&P1[i];
  us4 o;
  o[0] = f2b((a.x + b.x) * alpha);
  o[1] = f2b((a.y + b.y) * alpha);
  o[2] = f2b((a.z + b.z) * alpha);
  o[3] = f2b((a.w + b.w) * alpha);
  *(us4*)&out[i] = o;
}

// ---------------------------------------------------------------------------
// bf16 MFMA GEMM, 128x128 tile, BK=64, 4 waves; XOR-swizzled LDS.
// Per-z descriptor: A, B (both row-major, B in N x K "B^T" layout),
// C offset (elements), bias. KSPLIT: s = bz % KSPLIT shifts A/B cols by s*K
// and C by s*sC2 (fp32 partials).
// CMODE: 0 fp32; 1 bf16; 2 bf16 attn-V^T layout; 3 bf16 transposed (C^T).
// ---------------------------------------------------------------------------
struct GDesc { const unsigned short* A; const unsigned short* B; long coff; const float* bias; };
struct GDescs { GDesc d[16]; };

template <int ACT, int CMODE, int KSPLIT>
__global__ __launch_bounds__(256) void gemm_z(
    GDescs ga, void* __restrict__ Cv, int K, int lda, int ldb, int ldc,
    long sC2, float alpha) {
  const int bz = blockIdx.z;
  const int s = (KSPLIT > 1) ? (bz % KSPLIT) : 0;
  const int zb = (KSPLIT > 1) ? (bz / KSPLIT) : bz;
  const GDesc g = ga.d[zb];
  const unsigned short* Ab = g.A + (long)s * K;
  const unsigned short* Bb = g.B + (long)s * K;
  const int m0 = blockIdx.y * 128, n0 = blockIdx.x * 128;
  const int tid = threadIdx.x;
  const int lane = tid & 63, w = tid >> 6;
  const int wr = (w >> 1) * 64, wc = (w & 1) * 64;
  __shared__ unsigned short As[128 * 64];
  __shared__ unsigned short Bs[128 * 64];
  f32x4 acc[4][4];
#pragma unroll
  for (int i = 0; i < 4; ++i)
#pragma unroll
    for (int j = 0; j < 4; ++j) acc[i][j] = (f32x4){0.f, 0.f, 0.f, 0.f};
  const int srow = tid >> 3;
  const int scol = (((tid & 7) ^ ((tid >> 3) & 7)) << 3);
  const int rl = lane & 15, lg = lane >> 4, rx = rl & 7;
  for (int k0 = 0; k0 < K; k0 += 64) {
    __syncthreads();
#pragma unroll
    for (int it = 0; it < 4; ++it) {
      gload16(Ab + (long)(m0 + it * 32 + srow) * lda + k0 + scol,
              As + w * 512 + it * 2048);
      gload16(Bb + (long)(n0 + it * 32 + srow) * ldb + k0 + scol,
              Bs + w * 512 + it * 2048);
    }
    __syncthreads();
#pragma unroll
    for (int kk = 0; kk < 2; ++kk) {
      short8b af[4], bfr[4];
#pragma unroll
      for (int m = 0; m < 4; ++m)
        af[m] = *(const short8b*)&As[(wr + m * 16 + rl) * 64 +
                                     ((((kk * 4 + lg) ^ rx)) << 3)];
#pragma unroll
      for (int nn = 0; nn < 4; ++nn)
        bfr[nn] = *(const short8b*)&Bs[(wc + nn * 16 + rl) * 64 +
                                       ((((kk * 4 + lg) ^ rx)) << 3)];
#pragma unroll
      for (int m = 0; m < 4; ++m)
#pragma unroll
        for (int nn = 0; nn < 4; ++nn)
          acc[m][nn] = __builtin_amdgcn_mfma_f32_16x16x32_bf16(
              af[m], bfr[nn], acc[m][nn], 0, 0, 0);
    }
  }
  const int rrow = lg * 4;
  float bv[4];
#pragma unroll
  for (int nn = 0; nn < 4; ++nn)
    bv[nn] = g.bias ? g.bias[n0 + wc + nn * 16 + rl] : 0.f;
  if (CMODE == 2) {
#pragma unroll
    for (int m = 0; m < 4; ++m)
#pragma unroll
      for (int nn = 0; nn < 4; ++nn) {
        const int row = m0 + wr + m * 16 + rrow;
        const int col = n0 + wc + nn * 16 + rl;
        us4 o;
#pragma unroll
        for (int r = 0; r < 4; ++r) {
          float v = alpha * acc[m][nn][r] + bv[nn];
          if (ACT == 1) v = LEAKY(v);
          o[r] = f2b(v);
        }
        const long off = g.coff + (long)(row >> 10) * 524288 +
                         (long)col * 1024 + (row & 1023);
        *(us4*)&((unsigned short*)Cv)[off] = o;
      }
  } else if (CMODE == 3) {
#pragma unroll
    for (int m = 0; m < 4; ++m)
#pragma unroll
      for (int nn = 0; nn < 4; ++nn) {
        const int row = m0 + wr + m * 16 + rrow;
        const int col = n0 + wc + nn * 16 + rl;
        us4 o;
#pragma unroll
        for (int r = 0; r < 4; ++r) {
          float v = alpha * acc[m][nn][r] + bv[nn];
          if (ACT == 1) v = LEAKY(v);
          o[r] = f2b(v);
        }
        *(us4*)&((unsigned short*)Cv)[g.coff + (long)col * ldc + row] = o;
      }
  } else {
#pragma unroll
    for (int m = 0; m < 4; ++m)
#pragma unroll
      for (int nn = 0; nn < 4; ++nn)
#pragma unroll
        for (int r = 0; r < 4; ++r) {
          float v = alpha * acc[m][nn][r] + bv[nn];
          if (ACT == 1) v = LEAKY(v);
          long off = g.coff + (long)s * sC2 +
                     (long)(m0 + wr + m * 16 + rrow + r) * ldc + n0 + wc +
                     nn * 16 + rl;
          if (CMODE == 1)
            ((unsigned short*)Cv)[off] = f2b(v);
          else
            ((float*)Cv)[off] = v;
        }
  }
}

// ---------------------------------------------------------------------------
// BatchNorm on transposed layout h^T (512 features x 16384 samples), bf16.
// Stats: one block per feature row (no atomics). Apply: elementwise in-place.
// ---------------------------------------------------------------------------
__global__ __launch_bounds__(256) void bn_stats_t(const unsigned short* __restrict__ X,
                                                  float* __restrict__ ST) {
  const int f = blockIdx.x;
  const unsigned short* p = X + (long)f * 16384;
  const int tid = threadIdx.x;
  float s = 0.f, q = 0.f;
#pragma unroll
  for (int k = 0; k < 16; ++k) {
    us4 v = *(const us4*)&p[(k * 256 + tid) * 4];
#pragma unroll
    for (int j = 0; j < 4; ++j) {
      const float x = b2f(v[j]);
      s += x; q += x * x;
    }
  }
#pragma unroll
  for (int mask = 1; mask < 64; mask <<= 1) {
    s += __shfl_xor(s, mask, 64);
    q += __shfl_xor(q, mask, 64);
  }
  __shared__ float rs[8];
  const int wv = tid >> 6;
  if ((tid & 63) == 0) { rs[wv] = s; rs[4 + wv] = q; }
  __syncthreads();
  if (tid == 0) {
    s = rs[0] + rs[1] + rs[2] + rs[3];
    q = rs[4] + rs[5] + rs[6] + rs[7];
    const float mu = s * (1.f / 16384.f);
    ST[f] = mu;
    ST[512 + f] = q * (1.f / 16384.f) - mu * mu;
  }
}

__global__ __launch_bounds__(256) void bn_apply_t(
    unsigned short* __restrict__ X, const float* __restrict__ ST,
    const float* __restrict__ g, const float* __restrict__ be) {
  const long i = ((long)blockIdx.x * 256 + threadIdx.x) * 4;
  const int f = (int)(i >> 14);
  const float rs = rsqrtf(ST[512 + f] + 1e-5f) * g[f];
  const float bb = be[f] - ST[f] * rs;
  us4 v = *(const us4*)&X[i];
  us4 o;
#pragma unroll
  for (int j = 0; j < 4; ++j) {
    const float y = b2f(v[j]) * rs + bb;
    o[j] = f2b(LEAKY(y));
  }
  *(us4*)&X[i] = o;
}

// ---------------------------------------------------------------------------
// bf16 MFMA flash attention, both attentions in one dispatch (z = 8).
// ---------------------------------------------------------------------------
__global__ __launch_bounds__(256) void attn_mfma(
    const unsigned short* __restrict__ Q, const unsigned short* __restrict__ K,
    const unsigned short* __restrict__ Vt, unsigned short* __restrict__ O) {
  const int qb = blockIdx.x, h = blockIdx.y;
  const int n = blockIdx.z & 3, sel = blockIdx.z >> 2;
  Q += (long)sel * 4194304;
  K += (long)sel * 4194304;
  Vt += (long)sel * 2097152;
  O += (long)sel * 2097152;
  const int tid = threadIdx.x;
  const int lane = tid & 63, w = tid >> 6;
  const int rl = lane & 15, lg = lane >> 4;
  __shared__ unsigned short Qs[4096];
  __shared__ unsigned short Ks[4096];
  __shared__ unsigned short Vs[4096];
  __shared__ unsigned short Ps[4096];
  stage64(Q + ((long)n * 1024 + qb * 64) * 512 + h * 64, 512, Qs, lane, w);
  float m_r = -1e30f, l_r = 0.f;
  f32x4 po[4];
#pragma unroll
  for (int i = 0; i < 4; ++i) po[i] = (f32x4){0.f, 0.f, 0.f, 0.f};
  const unsigned short* Kg0 = K + ((long)n * 1024) * 512 + h * 64;
  const unsigned short* Vg0 = Vt + (long)n * 524288 + (long)(h * 64) * 1024;
  for (int kt = 0; kt < 16; ++kt) {
    __syncthreads();
    stage64(Kg0 + (long)(kt * 64) * 512, 512, Ks, lane, w);
    stage64(Vg0 + kt * 64, 1024, Vs, lane, w);
    __syncthreads();
    f32x4 sa[4];
#pragma unroll
    for (int i = 0; i < 4; ++i) sa[i] = (f32x4){0.f, 0.f, 0.f, 0.f};
#pragma unroll
    for (int kk = 0; kk < 2; ++kk) {
      const short8b qf = ldsw(Qs, w * 16 + rl, 4 * kk + lg);
#pragma unroll
      for (int mt = 0; mt < 4; ++mt) {
        const short8b kf = ldsw(Ks, mt * 16 + rl, 4 * kk + lg);
        sa[mt] = __builtin_amdgcn_mfma_f32_16x16x32_bf16(kf, qf, sa[mt], 0, 0, 0);
      }
    }
    float pr[4][4];
    float mx = -1e30f;
#pragma unroll
    for (int mt = 0; mt < 4; ++mt)
#pragma unroll
      for (int r = 0; r < 4; ++r) {
        pr[mt][r] = sa[mt][r] * 0.125f;
        mx = fmaxf(mx, pr[mt][r]);
      }
    mx = fmaxf(mx, __shfl_xor(mx, 16, 64));
    mx = fmaxf(mx, __shfl_xor(mx, 32, 64));
    const float mn = fmaxf(m_r, mx);
    const float f = __expf(m_r - mn);
    m_r = mn;
    float ps = 0.f;
    const int q = w * 16 + rl;
#pragma unroll
    for (int mt = 0; mt < 4; ++mt) {
      us4 o;
#pragma unroll
      for (int r = 0; r < 4; ++r) {
        const float p = __expf(pr[mt][r] - mn);
        ps += p;
        o[r] = f2b(p);
      }
      const int c16 = (4 * mt + lg) >> 1;
      *(us4*)&Ps[q * 64 + ((c16 ^ (q & 7)) << 3) + ((lg & 1) << 2)] = o;
    }
    ps += __shfl_xor(ps, 16, 64);
    ps += __shfl_xor(ps, 32, 64);
    l_r = l_r * f + ps;
#pragma unroll
    for (int r = 0; r < 4; ++r) {
      const float fr = __shfl(f, lg * 4 + r, 64);
#pragma unroll
      for (int nt = 0; nt < 4; ++nt) po[nt][r] *= fr;
    }
#pragma unroll
    for (int kk = 0; kk < 2; ++kk) {
      const short8b pf = ldsw(Ps, w * 16 + rl, 4 * kk + lg);
#pragma unroll
      for (int nt = 0; nt < 4; ++nt) {
        const short8b vf = ldsw(Vs, nt * 16 + rl, 4 * kk + lg);
        po[nt] = __builtin_amdgcn_mfma_f32_16x16x32_bf16(pf, vf, po[nt], 0, 0, 0);
      }
    }
  }
  float invr[4];
#pragma unroll
  for (int r = 0; r < 4; ++r) invr[r] = 1.f / __shfl(l_r, lg * 4 + r, 64);
  const long ob = ((long)n * 1024 + qb * 64 + w * 16) * 512 + h * 64;
#pragma unroll
  for (int nt = 0; nt < 4; ++nt)
#pragma unroll
    for (int r = 0; r < 4; ++r)
      O[ob + (long)(lg * 4 + r) * 512 + nt * 16 + rl] = f2b(po[nt][r] * invr[r]);
}

// ---------------------------------------------------------------------------
// Softmax pass 1: per-row max & 1/sum (stored to RS), column sums of the
// softmaxed matrix accumulated via LDS + one atomicAdd per column per block.
// Does NOT write the softmax matrix. 8 rows per block.
// ---------------------------------------------------------------------------
__global__ __launch_bounds__(256) void softmax_cs(const float* __restrict__ D,
                                                  float* __restrict__ RS,
                                                  float* __restrict__ CS) {
  __shared__ float colacc[2048];
  __shared__ float red[8];
  const int tid = threadIdx.x;
  const int wv = tid >> 6, ln = tid & 63;
#pragma unroll
  for (int k = 0; k < 8; ++k) colacc[tid + k * 256] = 0.f;
  __syncthreads();
  const int r0 = blockIdx.x * 8;
  const int n = r0 >> 11;
  for (int rr = 0; rr < 8; ++rr) {
    const float* p = D + (long)(r0 + rr) * 2048;
    float v[8];
    float mx = -1e30f;
#pragma unroll
    for (int k = 0; k < 8; ++k) {
      v[k] = p[tid + k * 256];
      mx = fmaxf(mx, v[k]);
    }
#pragma unroll
    for (int mask = 1; mask < 64; mask <<= 1) mx = fmaxf(mx, __shfl_xor(mx, mask, 64));
    if (ln == 0) red[wv] = mx;
    __syncthreads();
    mx = fmaxf(fmaxf(red[0], red[1]), fmaxf(red[2], red[3]));
    float sum = 0.f;
#pragma unroll
    for (int k = 0; k < 8; ++k) {
      v[k] = __expf(v[k] - mx);
      sum += v[k];
    }
#pragma unroll
    for (int mask = 1; mask < 64; mask <<= 1) sum += __shfl_xor(sum, mask, 64);
    if (ln == 0) red[4 + wv] = sum;
    __syncthreads();
    sum = red[4] + red[5] + red[6] + red[7];
    const float inv = 1.f / sum;
    if (tid == 0) {
      RS[(r0 + rr) * 2] = mx;
      RS[(r0 + rr) * 2 + 1] = inv;
    }
#pragma unroll
    for (int k = 0; k < 8; ++k) colacc[tid + k * 256] += v[k] * inv;
    __syncthreads();
  }
#pragma unroll
  for (int k = 0; k < 8; ++k)
    atomicAdd(&CS[n * 2048 + tid + k * 256], colacc[tid + k * 256]);
}

// Pass 2: recompute softmax from logits + row stats, apply column normalize.
__global__ __launch_bounds__(256) void final_scale(float* __restrict__ D,
                                                   const float* __restrict__ RS,
                                                   const float* __restrict__ CS) {
  const long i = ((long)blockIdx.x * 256 + threadIdx.x) * 4;
  const long row = i >> 11;
  const int n = (int)(row >> 11);
  const int j = (int)(i & 2047);
  const float mx = RS[row * 2];
  const float inv = RS[row * 2 + 1];
  float4 v = *(float4*)&D[i];
  const float* c = &CS[n * 2048 + j];
  v.x = __expf(v.x - mx) * inv * (c[0] > 0.f ? 1.f / c[0] : 0.f);
  v.y = __expf(v.y - mx) * inv * (c[1] > 0.f ? 1.f / c[1] : 0.f);
  v.z = __expf(v.z - mx) * inv * (c[2] > 0.f ? 1.f / c[2] : 0.f);
  v.w = __expf(v.w - mx) * inv * (c[3] > 0.f ? 1.f / c[3] : 0.f);
  *(float4*)&D[i] = v;
}

// ---------------------------------------------------------------------------
extern "C" void kernel_launch(void* const* d_in, const int* in_sizes, int n_in,
                              void* d_out, int out_size, void* d_ws,
                              size_t ws_size, hipStream_t stream) {
  const float* x1 = (const float*)d_in[0];
  const float* x2 = (const float*)d_in[1];
  const float* enc1 = (const float*)d_in[2];
  const float* enc2 = (const float*)d_in[3];
  const float* mlp_b1 = (const float*)d_in[5];
  const float* mlp_b2 = (const float*)d_in[7];
  const float* mlp_g = (const float*)d_in[8];
  const float* mlp_be = (const float*)d_in[9];
  const float* nlp_b1 = (const float*)d_in[11];
  const float* nlp_b2 = (const float*)d_in[13];
  const float* nlp_g = (const float*)d_in[14];
  const float* nlp_be = (const float*)d_in[15];
  float* out = (float*)d_out;

  unsigned short* W = (unsigned short*)d_ws;
  const long M1 = 1L << 20;
  const long S = 262144;
  unsigned short* Pb1 = W;            // 0..2 M1: pooled (both inputs)
  unsigned short* Pt1 = W + 2 * M1;   // 2..4: pooled transposed
  unsigned short* E1B = W + 4 * M1;   // 4..8
  unsigned short* E2B = W + 8 * M1;   // 8..12
  unsigned short* E1T = W + 12 * M1;  // 12..16
  unsigned short* WT = W + 16 * M1;   // 16..20 (12 x 262144)
  unsigned short* BA = W + 20 * M1;   // 20..28
  unsigned short* BB = W + 28 * M1;   // 28..36
  unsigned short* H1T = W + 36 * M1;  // 36..44: h1^T (512,16384)
  unsigned short* H2T = W + 44 * M1;  // 44..52: h2^T
  unsigned short* E1 = W + 52 * M1;   // 52..54: e1 bf16 (4,1024,512)
  float* ST = (float*)(W + 56 * M1);
  float* CS = ST + 1024;
  float* RS = CS + 8192;
  float* P0f = (float*)BA;
  float* P1f = (float*)BB;
  unsigned short* A1P = E2B;          // a1 (4,1024,512)
  unsigned short* A2P = E2B + 2 * M1; // a2

  const dim3 T(256);
  const long sP = 262144;
  const long sNE = 2097152;
  const long sE = 524288;
  const long sD = 4194304;

  // --- prep + operand conversion ---
  prep_pool<<<dim3(1024, 4, 2), T, 0, stream>>>(x1, x2, Pb1);
  transpose_b2b<<<dim3(4, 16, 8), T, 0, stream>>>(Pb1, Pt1, 1024, 256, sP, sP);
  convert2_f2b<<<dim3(4096, 1, 2), T, 0, stream>>>(enc1, enc2, E1B);
  transpose_f2b<<<dim3(16, 64), T, 0, stream>>>(enc1, E1T, 4096, 1024);
  WPtrs wp;
  wp.p[0] = (const float*)d_in[4];   // mlp_w1
  wp.p[1] = (const float*)d_in[6];   // mlp_w2
  wp.p[2] = (const float*)d_in[10];  // nlp_w1
  wp.p[3] = (const float*)d_in[12];  // nlp_w2
  wp.p[4] = (const float*)d_in[16];  // a1_wq
  wp.p[5] = (const float*)d_in[18];  // a1_wk
  wp.p[6] = (const float*)d_in[24];  // a2_wq
  wp.p[7] = (const float*)d_in[26];  // a2_wk
  wp.p[8] = (const float*)d_in[20];  // a1_wv
  wp.p[9] = (const float*)d_in[28];  // a2_wv
  wp.p[10] = (const float*)d_in[22]; // a1_fc
  wp.p[11] = (const float*)d_in[30]; // a2_fc
  wtrans<<<dim3(8, 8, 12), T, 0, stream>>>(wp, WT);

  // --- branch 1: node_enc (z=8) -> lin1 -> lin2^T -> BN ---
  {
    GDescs g{};
    for (int pr = 0; pr < 2; ++pr)
      for (int n = 0; n < 4; ++n)
        g.d[pr * 4 + n] = {pr ? E2B : E1B, Pt1 + n * sP,
                           (long)n * sNE + pr * 256, nullptr};
    gemm_z<0, 1, 1><<<dim3(2, 32, 8), T, 0, stream>>>(g, BA, 1024, 1024, 1024,
                                                      512, 0, 1.f);
  }
  {
    GDescs g{};
    g.d[0] = {BA, WT + 0 * S, 0, mlp_b1};
    gemm_z<1, 1, 1><<<dim3(4, 128, 1), T, 0, stream>>>(g, BB, 512, 512, 512,
                                                       512, 0, 1.f);
  }
  {
    GDescs g{};
    g.d[0] = {BB, WT + 1 * S, 0, mlp_b2};
    gemm_z<0, 3, 1><<<dim3(4, 128, 1), T, 0, stream>>>(g, H1T, 512, 512, 512,
                                                       16384, 0, 1.f);
  }
  bn_stats_t<<<512, T, 0, stream>>>(H1T, ST);
  bn_apply_t<<<8192, T, 0, stream>>>(H1T, ST, mlp_g, mlp_be);

  // --- branch 2 ---
  {
    GDescs g{};
    for (int pr = 0; pr < 2; ++pr)
      for (int n = 0; n < 4; ++n)
        g.d[pr * 4 + n] = {pr ? E2B : E1B, Pt1 + M1 + n * sP,
                           (long)n * sNE + pr * 256, nullptr};
    gemm_z<0, 1, 1><<<dim3(2, 32, 8), T, 0, stream>>>(g, BA, 1024, 1024, 1024,
                                                      512, 0, 1.f);
  }
  {
    GDescs g{};
    g.d[0] = {BA, WT + 2 * S, 0, nlp_b1};
    gemm_z<1, 1, 1><<<dim3(4, 128, 1), T, 0, stream>>>(g, BB, 512, 512, 512,
                                                       512, 0, 1.f);
  }
  {
    GDescs g{};
    g.d[0] = {BB, WT + 3 * S, 0, nlp_b2};
    gemm_z<0, 3, 1><<<dim3(4, 128, 1), T, 0, stream>>>(g, H2T, 512, 512, 512,
                                                       16384, 0, 1.f);
  }
  bn_stats_t<<<512, T, 0, stream>>>(H2T, ST);
  bn_apply_t<<<8192, T, 0, stream>>>(H2T, ST, nlp_g, nlp_be);

  // --- edge decode: z = 8 descs x split-K 2, fp32 partials, then addcvt ---
  {
    GDescs g{};
    for (int d = 0; d < 8; ++d)
      g.d[d] = {E1T, (d >= 4 ? H2T : H1T) + (d & 3) * 4096, (long)d * 524288,
                nullptr};
    gemm_z<0, 0, 2><<<dim3(4, 8, 16), T, 0, stream>>>(g, P0f, 2048, 4096,
                                                      16384, 512, 4194304, 1.f);
  }
  addcvt<<<4096, T, 0, stream>>>(P0f, P1f, E1, 1.f / 1024.f);

  // --- projections: Q1,K1,Q2,K2 (z=4); V1,V2 (z=2, V^T layout) ---
  unsigned short* E2 = E1 + 2 * M1;
  {
    GDescs g{};
    g.d[0] = {E2, WT + 4 * S, 0, (const float*)d_in[17]};
    g.d[1] = {E1, WT + 5 * S, 2 * M1, (const float*)d_in[19]};
    g.d[2] = {E1, WT + 6 * S, 4 * M1, (const float*)d_in[25]};
    g.d[3] = {E2, WT + 7 * S, 6 * M1, (const float*)d_in[27]};
    gemm_z<0, 1, 1><<<dim3(4, 32, 4), T, 0, stream>>>(g, BA, 512, 512, 512,
                                                      512, 0, 1.f);
  }
  {
    GDescs g{};
    g.d[0] = {E1, WT + 8 * S, 0, (const float*)d_in[21]};
    g.d[1] = {E2, WT + 9 * S, 2 * M1, (const float*)d_in[29]};
    gemm_z<0, 2, 1><<<dim3(4, 32, 2), T, 0, stream>>>(g, BB, 512, 512, 512,
                                                      512, 0, 1.f);
  }

  // --- both attentions ---
  attn_mfma<<<dim3(16, 8, 8), T, 0, stream>>>(BA, BA + 2 * M1, BB, BB + 4 * M1);

  // --- fc for both attentions ---
  {
    GDescs g{};
    g.d[0] = {BB + 4 * M1, WT + 10 * S, 0, (const float*)d_in[23]};
    g.d[1] = {BB + 6 * M1, WT + 11 * S, 2 * M1, (const float*)d_in[31]};
    gemm_z<0, 1, 1><<<dim3(4, 32, 2), T, 0, stream>>>(g, A1P, 512, 512, 512,
                                                      512, 0, 1.f);
  }

  // --- logits: all 4 quadrants x 4 n in one dispatch (z=16) ---
  {
    GDescs g{};
    for (int q = 0; q < 4; ++q)
      for (int n = 0; n < 4; ++n) {
        const unsigned short* A = (q < 2 ? A1P : A2P) + n * sE;
        const unsigned short* B = ((q == 0 || q == 2) ? A2P : A1P) + n * sE;
        const long coff =
            (long)n * sD + (q & 1) * 1024 + (long)(q >> 1) * 2097152;
        g.d[q * 4 + n] = {A, B, coff, nullptr};
      }
    gemm_z<0, 0, 1><<<dim3(8, 8, 16), T, 0, stream>>>(g, out, 512, 512, 512,
                                                      2048, 0, 1.f);
  }

  // --- softmax + column normalization (2 passes, no middle write) ---
  hipMemsetAsync(CS, 0, 8192 * sizeof(float), stream);
  softmax_cs<<<1024, T, 0, stream>>>(out, RS, CS);
  final_scale<<<16384, T, 0, stream>>>(out, RS, CS);
}

// Round 7
// 392.409 us; speedup vs baseline: 6.3100x; 1.0525x over previous
//
#include <hip/hip_runtime.h>
#include <hip/hip_bf16.h>

#define LEAKY(v) ((v) >= 0.f ? (v) : 0.01f * (v))

typedef __attribute__((ext_vector_type(8))) short short8b;
typedef __attribute__((ext_vector_type(4))) float f32x4;
typedef __attribute__((ext_vector_type(4))) unsigned short us4;

__device__ __forceinline__ unsigned short f2b(float f) {
  unsigned int u = __builtin_bit_cast(unsigned int, f);
  return (unsigned short)((u + 0x7FFFu + ((u >> 16) & 1u)) >> 16);
}
__device__ __forceinline__ float b2f(unsigned short s) {
  return __builtin_bit_cast(float, (unsigned int)s << 16);
}

__device__ __forceinline__ void gload16(const unsigned short* g, unsigned short* l) {
  __builtin_amdgcn_global_load_lds(
      (const __attribute__((address_space(1))) unsigned int*)(g),
      (__attribute__((address_space(3))) unsigned int*)(l), 16, 0, 0);
}

// Stage a 64x64 bf16 tile (rows of 128B) global->LDS, XOR-swizzled source.
__device__ __forceinline__ void stage64(const unsigned short* g, int ldg,
                                        unsigned short* lds, int lane, int w) {
  const int r8 = lane >> 3;
  const int ce = ((lane & 7) ^ r8) << 3;
  const int r0 = w * 8 + r8;
  gload16(g + (long)r0 * ldg + ce, lds + w * 512);
  gload16(g + (long)(r0 + 32) * ldg + ce, lds + 2048 + w * 512);
}

// Swizzled 16B read: row, c4 = 16B-column index 0..7
__device__ __forceinline__ short8b ldsw(const unsigned short* base, int row, int c4) {
  return *(const short8b*)&base[row * 64 + (((c4 ^ (row & 7)) << 3))];
}

// ---------------------------------------------------------------------------
// prep + exact AdaptiveAvgPool1d, written DIRECTLY transposed.
// Pt[inp][n][k][i], k = vvv*4 + cbi, i = t*16 + vb:
//   value = mean_m X[n, cbi*16+m, t, vb*64+vvv]
// ---------------------------------------------------------------------------
__global__ __launch_bounds__(256) void prep_pool_t(const float* __restrict__ X1,
                                                   const float* __restrict__ X2,
                                                   unsigned short* __restrict__ Pt) {
  const int t = blockIdx.x;   // 0..63
  const int cbi = blockIdx.y; // 0..3
  const int n = blockIdx.z & 3, inp = blockIdx.z >> 2;
  const float* X = inp ? X2 : X1;
  const int tid = threadIdx.x;
  __shared__ unsigned short sacc[64][20];
  float acc[4] = {0.f, 0.f, 0.f, 0.f};
  const long base0 = (((long)n * 64 + cbi * 16) * 64 + t) * 1024 + tid * 4;
#pragma unroll
  for (int m = 0; m < 16; ++m) {
    const float4 v = *(const float4*)&X[base0 + (long)m * 65536];
    acc[0] += v.x; acc[1] += v.y; acc[2] += v.z; acc[3] += v.w;
  }
  const int q = tid & 15, vb = tid >> 4;
#pragma unroll
  for (int j = 0; j < 4; ++j)
    sacc[q * 4 + j][vb] = f2b(acc[j] * (1.f / 16.f));
  __syncthreads();
  const int vvv = tid >> 2, iq = tid & 3;
  const us4 o = *(const us4*)&sacc[vvv][iq * 4];
  *(us4*)&Pt[(long)inp * (1L << 20) + (long)n * 262144 +
             (long)(vvv * 4 + cbi) * 1024 + t * 16 + iq * 4] = o;
}

// ---------------------------------------------------------------------------
// fp32 (R x C) -> bf16 (C x R) transpose
// ---------------------------------------------------------------------------
__global__ __launch_bounds__(256) void transpose_f2b(
    const float* __restrict__ in, unsigned short* __restrict__ out, int R, int C) {
  __shared__ float t[64][65];
  const int c0 = blockIdx.x * 64, r0 = blockIdx.y * 64;
  const int tid = threadIdx.x;
#pragma unroll
  for (int it = 0; it < 4; ++it) {
    int idx = tid + it * 256;
    int r = idx >> 4, c4 = (idx & 15) * 4;
    float4 v = *(const float4*)&in[(long)(r0 + r) * C + c0 + c4];
    t[c4 + 0][r] = v.x; t[c4 + 1][r] = v.y;
    t[c4 + 2][r] = v.z; t[c4 + 3][r] = v.w;
  }
  __syncthreads();
#pragma unroll
  for (int it = 0; it < 4; ++it) {
    int idx = tid + it * 256;
    int c = idx >> 4, r4 = (idx & 15) * 4;
    us4 o;
    o[0] = f2b(t[c][r4 + 0]); o[1] = f2b(t[c][r4 + 1]);
    o[2] = f2b(t[c][r4 + 2]); o[3] = f2b(t[c][r4 + 3]);
    *(us4*)&out[(long)(c0 + c) * R + r0 + r4] = o;
  }
}

// fused 12x 512x512 weight transpose+convert
struct WPtrs { const float* p[12]; };
__global__ __launch_bounds__(256) void wtrans(WPtrs wp, unsigned short* __restrict__ out) {
  const float* in = wp.p[blockIdx.z];
  unsigned short* ob = out + (long)blockIdx.z * 262144;
  __shared__ float t[64][65];
  const int c0 = blockIdx.x * 64, r0 = blockIdx.y * 64;
  const int tid = threadIdx.x;
#pragma unroll
  for (int it = 0; it < 4; ++it) {
    int idx = tid + it * 256;
    int r = idx >> 4, c4 = (idx & 15) * 4;
    float4 v = *(const float4*)&in[(long)(r0 + r) * 512 + c0 + c4];
    t[c4 + 0][r] = v.x; t[c4 + 1][r] = v.y;
    t[c4 + 2][r] = v.z; t[c4 + 3][r] = v.w;
  }
  __syncthreads();
#pragma unroll
  for (int it = 0; it < 4; ++it) {
    int idx = tid + it * 256;
    int c = idx >> 4, r4 = (idx & 15) * 4;
    us4 o;
    o[0] = f2b(t[c][r4 + 0]); o[1] = f2b(t[c][r4 + 1]);
    o[2] = f2b(t[c][r4 + 2]); o[3] = f2b(t[c][r4 + 3]);
    *(us4*)&ob[(long)(c0 + c) * 512 + r0 + r4] = o;
  }
}

// fp32 -> bf16 convert, two inputs (z selects), each 1M quads
__global__ __launch_bounds__(256) void convert2_f2b(const float* __restrict__ i1,
                                                    const float* __restrict__ i2,
                                                    unsigned short* __restrict__ out) {
  const float* in = blockIdx.z ? i2 : i1;
  unsigned short* o = out + (long)blockIdx.z * (4L << 20);
  long i = (long)blockIdx.x * 256 + threadIdx.x;
  float4 v = ((const float4*)in)[i];
  us4 q;
  q[0] = f2b(v.x); q[1] = f2b(v.y); q[2] = f2b(v.z); q[3] = f2b(v.w);
  ((us4*)o)[i] = q;
}

// add two fp32 partials, scale, convert to bf16
__global__ __launch_bounds__(256) void addcvt(const float* __restrict__ P0,
                                              const float* __restrict__ P1,
                                              unsigned short* __restrict__ out,
                                              float alpha) {
  const long i = ((long)blockIdx.x * 256 + threadIdx.x) * 4;
  const float4 a = *(const float4*)&P0[i];
  const float4 b = *(const float4*)&P1[i];
  us4 o;
  o[0] = f2b((a.x + b.x) * alpha);
  o[1] = f2b((a.y + b.y) * alpha);
  o[2] = f2b((a.z + b.z) * alpha);
  o[3] = f2b((a.w + b.w) * alpha);
  *(us4*)&out[i] = o;
}

// ---------------------------------------------------------------------------
// bf16 MFMA GEMM, 128x128 tile, BK=64, 4 waves; XOR-swizzled LDS.
// Per-z descriptor: A, B (row-major; B in N x K "B^T" layout), C offset, bias.
// KSPLIT=2: s = bz%2 shifts A/B cols by s*K and C by s*sC2 (fp32 partials).
// CMODE: 0 fp32; 1 bf16; 2 bf16 attn-V^T layout; 3 bf16 transposed (C^T).
// ---------------------------------------------------------------------------
struct GDesc { const unsigned short* A; const unsigned short* B; long coff; const float* bias; };
struct GDescs { GDesc d[16]; };

template <int ACT, int CMODE, int KSPLIT>
__global__ __launch_bounds__(256) void gemm_z(
    GDescs ga, void* __restrict__ Cv, int K, int lda, int ldb, int ldc,
    long sC2, float alpha) {
  const int bz = blockIdx.z;
  const int s = (KSPLIT > 1) ? (bz % KSPLIT) : 0;
  const int zb = (KSPLIT > 1) ? (bz / KSPLIT) : bz;
  const GDesc g = ga.d[zb];
  const unsigned short* Ab = g.A + (long)s * K;
  const unsigned short* Bb = g.B + (long)s * K;
  const int m0 = blockIdx.y * 128, n0 = blockIdx.x * 128;
  const int tid = threadIdx.x;
  const int lane = tid & 63, w = tid >> 6;
  const int wr = (w >> 1) * 64, wc = (w & 1) * 64;
  __shared__ unsigned short As[128 * 64];
  __shared__ unsigned short Bs[128 * 64];
  f32x4 acc[4][4];
#pragma unroll
  for (int i = 0; i < 4; ++i)
#pragma unroll
    for (int j = 0; j < 4; ++j) acc[i][j] = (f32x4){0.f, 0.f, 0.f, 0.f};
  const int srow = tid >> 3;
  const int scol = (((tid & 7) ^ ((tid >> 3) & 7)) << 3);
  const int rl = lane & 15, lg = lane >> 4, rx = rl & 7;
  for (int k0 = 0; k0 < K; k0 += 64) {
    __syncthreads();
#pragma unroll
    for (int it = 0; it < 4; ++it) {
      gload16(Ab + (long)(m0 + it * 32 + srow) * lda + k0 + scol,
              As + w * 512 + it * 2048);
      gload16(Bb + (long)(n0 + it * 32 + srow) * ldb + k0 + scol,
              Bs + w * 512 + it * 2048);
    }
    __syncthreads();
#pragma unroll
    for (int kk = 0; kk < 2; ++kk) {
      short8b af[4], bfr[4];
#pragma unroll
      for (int m = 0; m < 4; ++m)
        af[m] = *(const short8b*)&As[(wr + m * 16 + rl) * 64 +
                                     ((((kk * 4 + lg) ^ rx)) << 3)];
#pragma unroll
      for (int nn = 0; nn < 4; ++nn)
        bfr[nn] = *(const short8b*)&Bs[(wc + nn * 16 + rl) * 64 +
                                       ((((kk * 4 + lg) ^ rx)) << 3)];
#pragma unroll
      for (int m = 0; m < 4; ++m)
#pragma unroll
        for (int nn = 0; nn < 4; ++nn)
          acc[m][nn] = __builtin_amdgcn_mfma_f32_16x16x32_bf16(
              af[m], bfr[nn], acc[m][nn], 0, 0, 0);
    }
  }
  const int rrow = lg * 4;
  float bv[4];
#pragma unroll
  for (int nn = 0; nn < 4; ++nn)
    bv[nn] = g.bias ? g.bias[n0 + wc + nn * 16 + rl] : 0.f;
  if (CMODE == 2) {
#pragma unroll
    for (int m = 0; m < 4; ++m)
#pragma unroll
      for (int nn = 0; nn < 4; ++nn) {
        const int row = m0 + wr + m * 16 + rrow;
        const int col = n0 + wc + nn * 16 + rl;
        us4 o;
#pragma unroll
        for (int r = 0; r < 4; ++r) {
          float v = alpha * acc[m][nn][r] + bv[nn];
          if (ACT == 1) v = LEAKY(v);
          o[r] = f2b(v);
        }
        const long off = g.coff + (long)(row >> 10) * 524288 +
                         (long)col * 1024 + (row & 1023);
        *(us4*)&((unsigned short*)Cv)[off] = o;
      }
  } else if (CMODE == 3) {
#pragma unroll
    for (int m = 0; m < 4; ++m)
#pragma unroll
      for (int nn = 0; nn < 4; ++nn) {
        const int row = m0 + wr + m * 16 + rrow;
        const int col = n0 + wc + nn * 16 + rl;
        us4 o;
#pragma unroll
        for (int r = 0; r < 4; ++r) {
          float v = alpha * acc[m][nn][r] + bv[nn];
          if (ACT == 1) v = LEAKY(v);
          o[r] = f2b(v);
        }
        *(us4*)&((unsigned short*)Cv)[g.coff + (long)col * ldc + row] = o;
      }
  } else {
#pragma unroll
    for (int m = 0; m < 4; ++m)
#pragma unroll
      for (int nn = 0; nn < 4; ++nn)
#pragma unroll
        for (int r = 0; r < 4; ++r) {
          float v = alpha * acc[m][nn][r] + bv[nn];
          if (ACT == 1) v = LEAKY(v);
          long off = g.coff + (long)s * sC2 +
                     (long)(m0 + wr + m * 16 + rrow + r) * ldc + n0 + wc +
                     nn * 16 + rl;
          if (CMODE == 1)
            ((unsigned short*)Cv)[off] = f2b(v);
          else
            ((float*)Cv)[off] = v;
        }
  }
}

// ---------------------------------------------------------------------------
// BatchNorm on transposed layout h^T (512 features x 16384 samples), bf16.
// z selects branch (X offset z*8M, ST offset z*1024, per-z gamma/beta).
// ---------------------------------------------------------------------------
__global__ __launch_bounds__(256) void bn_stats_t(const unsigned short* __restrict__ X,
                                                  float* __restrict__ ST) {
  const int f = blockIdx.x;
  const int z = blockIdx.z;
  const unsigned short* p = X + (long)z * (8L << 20) + (long)f * 16384;
  float* st = ST + z * 1024;
  const int tid = threadIdx.x;
  float s = 0.f, q = 0.f;
#pragma unroll
  for (int k = 0; k < 16; ++k) {
    us4 v = *(const us4*)&p[(k * 256 + tid) * 4];
#pragma unroll
    for (int j = 0; j < 4; ++j) {
      const float x = b2f(v[j]);
      s += x; q += x * x;
    }
  }
#pragma unroll
  for (int mask = 1; mask < 64; mask <<= 1) {
    s += __shfl_xor(s, mask, 64);
    q += __shfl_xor(q, mask, 64);
  }
  __shared__ float rs[8];
  const int wv = tid >> 6;
  if ((tid & 63) == 0) { rs[wv] = s; rs[4 + wv] = q; }
  __syncthreads();
  if (tid == 0) {
    s = rs[0] + rs[1] + rs[2] + rs[3];
    q = rs[4] + rs[5] + rs[6] + rs[7];
    const float mu = s * (1.f / 16384.f);
    st[f] = mu;
    st[512 + f] = q * (1.f / 16384.f) - mu * mu;
  }
}

__global__ __launch_bounds__(256) void bn_apply_t(
    unsigned short* __restrict__ X, const float* __restrict__ ST,
    const float* __restrict__ g1, const float* __restrict__ be1,
    const float* __restrict__ g2, const float* __restrict__ be2) {
  const int z = blockIdx.z;
  unsigned short* Xb = X + (long)z * (8L << 20);
  const float* st = ST + z * 1024;
  const float* g = z ? g2 : g1;
  const float* be = z ? be2 : be1;
  const long i = ((long)blockIdx.x * 256 + threadIdx.x) * 4;
  const int f = (int)(i >> 14);
  const float rs = rsqrtf(st[512 + f] + 1e-5f) * g[f];
  const float bb = be[f] - st[f] * rs;
  us4 v = *(const us4*)&Xb[i];
  us4 o;
#pragma unroll
  for (int j = 0; j < 4; ++j) {
    const float y = b2f(v[j]) * rs + bb;
    o[j] = f2b(LEAKY(y));
  }
  *(us4*)&Xb[i] = o;
}

// ---------------------------------------------------------------------------
// bf16 MFMA flash attention, both attentions in one dispatch (z = 8).
// ---------------------------------------------------------------------------
__global__ __launch_bounds__(256) void attn_mfma(
    const unsigned short* __restrict__ Q, const unsigned short* __restrict__ K,
    const unsigned short* __restrict__ Vt, unsigned short* __restrict__ O) {
  const int qb = blockIdx.x, h = blockIdx.y;
  const int n = blockIdx.z & 3, sel = blockIdx.z >> 2;
  Q += (long)sel * 4194304;
  K += (long)sel * 4194304;
  Vt += (long)sel * 2097152;
  O += (long)sel * 2097152;
  const int tid = threadIdx.x;
  const int lane = tid & 63, w = tid >> 6;
  const int rl = lane & 15, lg = lane >> 4;
  __shared__ unsigned short Qs[4096];
  __shared__ unsigned short Ks[4096];
  __shared__ unsigned short Vs[4096];
  __shared__ unsigned short Ps[4096];
  stage64(Q + ((long)n * 1024 + qb * 64) * 512 + h * 64, 512, Qs, lane, w);
  float m_r = -1e30f, l_r = 0.f;
  f32x4 po[4];
#pragma unroll
  for (int i = 0; i < 4; ++i) po[i] = (f32x4){0.f, 0.f, 0.f, 0.f};
  const unsigned short* Kg0 = K + ((long)n * 1024) * 512 + h * 64;
  const unsigned short* Vg0 = Vt + (long)n * 524288 + (long)(h * 64) * 1024;
  for (int kt = 0; kt < 16; ++kt) {
    __syncthreads();
    stage64(Kg0 + (long)(kt * 64) * 512, 512, Ks, lane, w);
    stage64(Vg0 + kt * 64, 1024, Vs, lane, w);
    __syncthreads();
    f32x4 sa[4];
#pragma unroll
    for (int i = 0; i < 4; ++i) sa[i] = (f32x4){0.f, 0.f, 0.f, 0.f};
#pragma unroll
    for (int kk = 0; kk < 2; ++kk) {
      const short8b qf = ldsw(Qs, w * 16 + rl, 4 * kk + lg);
#pragma unroll
      for (int mt = 0; mt < 4; ++mt) {
        const short8b kf = ldsw(Ks, mt * 16 + rl, 4 * kk + lg);
        sa[mt] = __builtin_amdgcn_mfma_f32_16x16x32_bf16(kf, qf, sa[mt], 0, 0, 0);
      }
    }
    float pr[4][4];
    float mx = -1e30f;
#pragma unroll
    for (int mt = 0; mt < 4; ++mt)
#pragma unroll
      for (int r = 0; r < 4; ++r) {
        pr[mt][r] = sa[mt][r] * 0.125f;
        mx = fmaxf(mx, pr[mt][r]);
      }
    mx = fmaxf(mx, __shfl_xor(mx, 16, 64));
    mx = fmaxf(mx, __shfl_xor(mx, 32, 64));
    const float mn = fmaxf(m_r, mx);
    const float f = __expf(m_r - mn);
    m_r = mn;
    float ps = 0.f;
    const int q = w * 16 + rl;
#pragma unroll
    for (int mt = 0; mt < 4; ++mt) {
      us4 o;
#pragma unroll
      for (int r = 0; r < 4; ++r) {
        const float p = __expf(pr[mt][r] - mn);
        ps += p;
        o[r] = f2b(p);
      }
      const int c16 = (4 * mt + lg) >> 1;
      *(us4*)&Ps[q * 64 + ((c16 ^ (q & 7)) << 3) + ((lg & 1) << 2)] = o;
    }
    ps += __shfl_xor(ps, 16, 64);
    ps += __shfl_xor(ps, 32, 64);
    l_r = l_r * f + ps;
#pragma unroll
    for (int r = 0; r < 4; ++r) {
      const float fr = __shfl(f, lg * 4 + r, 64);
#pragma unroll
      for (int nt = 0; nt < 4; ++nt) po[nt][r] *= fr;
    }
#pragma unroll
    for (int kk = 0; kk < 2; ++kk) {
      const short8b pf = ldsw(Ps, w * 16 + rl, 4 * kk + lg);
#pragma unroll
      for (int nt = 0; nt < 4; ++nt) {
        const short8b vf = ldsw(Vs, nt * 16 + rl, 4 * kk + lg);
        po[nt] = __builtin_amdgcn_mfma_f32_16x16x32_bf16(pf, vf, po[nt], 0, 0, 0);
      }
    }
  }
  float invr[4];
#pragma unroll
  for (int r = 0; r < 4; ++r) invr[r] = 1.f / __shfl(l_r, lg * 4 + r, 64);
  const long ob = ((long)n * 1024 + qb * 64 + w * 16) * 512 + h * 64;
#pragma unroll
  for (int nt = 0; nt < 4; ++nt)
#pragma unroll
    for (int r = 0; r < 4; ++r)
      O[ob + (long)(lg * 4 + r) * 512 + nt * 16 + rl] = f2b(po[nt][r] * invr[r]);
}

// ---------------------------------------------------------------------------
// Softmax pass 1: per-row max & 1/sum, plus column sums of softmax(A).
// ---------------------------------------------------------------------------
__global__ __launch_bounds__(256) void softmax_cs(const float* __restrict__ D,
                                                  float* __restrict__ RS,
                                                  float* __restrict__ CS) {
  __shared__ float colacc[2048];
  __shared__ float red[8];
  const int tid = threadIdx.x;
  const int wv = tid >> 6, ln = tid & 63;
#pragma unroll
  for (int k = 0; k < 8; ++k) colacc[tid + k * 256] = 0.f;
  __syncthreads();
  const int r0 = blockIdx.x * 8;
  const int n = r0 >> 11;
  for (int rr = 0; rr < 8; ++rr) {
    const float* p = D + (long)(r0 + rr) * 2048;
    float v[8];
    float mx = -1e30f;
#pragma unroll
    for (int k = 0; k < 8; ++k) {
      v[k] = p[tid + k * 256];
      mx = fmaxf(mx, v[k]);
    }
#pragma unroll
    for (int mask = 1; mask < 64; mask <<= 1) mx = fmaxf(mx, __shfl_xor(mx, mask, 64));
    if (ln == 0) red[wv] = mx;
    __syncthreads();
    mx = fmaxf(fmaxf(red[0], red[1]), fmaxf(red[2], red[3]));
    float sum = 0.f;
#pragma unroll
    for (int k = 0; k < 8; ++k) {
      v[k] = __expf(v[k] - mx);
      sum += v[k];
    }
#pragma unroll
    for (int mask = 1; mask < 64; mask <<= 1) sum += __shfl_xor(sum, mask, 64);
    if (ln == 0) red[4 + wv] = sum;
    __syncthreads();
    sum = red[4] + red[5] + red[6] + red[7];
    const float inv = 1.f / sum;
    if (tid == 0) {
      RS[(r0 + rr) * 2] = mx;
      RS[(r0 + rr) * 2 + 1] = inv;
    }
#pragma unroll
    for (int k = 0; k < 8; ++k) colacc[tid + k * 256] += v[k] * inv;
    __syncthreads();
  }
#pragma unroll
  for (int k = 0; k < 8; ++k)
    atomicAdd(&CS[n * 2048 + tid + k * 256], colacc[tid + k * 256]);
}

// Pass 2: recompute softmax from logits + row stats, apply column normalize.
__global__ __launch_bounds__(256) void final_scale(float* __restrict__ D,
                                                   const float* __restrict__ RS,
                                                   const float* __restrict__ CS) {
  const long i = ((long)blockIdx.x * 256 + threadIdx.x) * 4;
  const long row = i >> 11;
  const int n = (int)(row >> 11);
  const int j = (int)(i & 2047);
  const float mx = RS[row * 2];
  const float inv = RS[row * 2 + 1];
  float4 v = *(float4*)&D[i];
  const float* c = &CS[n * 2048 + j];
  v.x = __expf(v.x - mx) * inv * (c[0] > 0.f ? 1.f / c[0] : 0.f);
  v.y = __expf(v.y - mx) * inv * (c[1] > 0.f ? 1.f / c[1] : 0.f);
  v.z = __expf(v.z - mx) * inv * (c[2] > 0.f ? 1.f / c[2] : 0.f);
  v.w = __expf(v.w - mx) * inv * (c[3] > 0.f ? 1.f / c[3] : 0.f);
  *(float4*)&D[i] = v;
}

// ---------------------------------------------------------------------------
extern "C" void kernel_launch(void* const* d_in, const int* in_sizes, int n_in,
                              void* d_out, int out_size, void* d_ws,
                              size_t ws_size, hipStream_t stream) {
  const float* x1 = (const float*)d_in[0];
  const float* x2 = (const float*)d_in[1];
  const float* enc1 = (const float*)d_in[2];
  const float* enc2 = (const float*)d_in[3];
  const float* mlp_b1 = (const float*)d_in[5];
  const float* mlp_b2 = (const float*)d_in[7];
  const float* mlp_g = (const float*)d_in[8];
  const float* mlp_be = (const float*)d_in[9];
  const float* nlp_b1 = (const float*)d_in[11];
  const float* nlp_b2 = (const float*)d_in[13];
  const float* nlp_g = (const float*)d_in[14];
  const float* nlp_be = (const float*)d_in[15];
  float* out = (float*)d_out;

  unsigned short* W = (unsigned short*)d_ws;
  const long M1 = 1L << 20;
  const long S = 262144;
  // Rolling layout (us units). Lifetimes audited disjoint-in-time:
  //  0.. 2M : Pt (pooled^T, both inputs)        [dead after node_enc]
  //  4..12M : ENC (enc1,enc2 bf16)              [dead after node_enc]
  //           -> E1/E2 (4..8M) after addcvt     [dead after projections]
  //           -> A1P/A2P (8..12M) after fc
  // 12..16M : E1T (enc1^T)                      [dead after edge decode]
  // 16..19M : WT (12 transposed weights)        [dead after fc]
  // 20..36M : NE (node-enc out, 2 branches)     [dead after lin1]
  //           -> H1T/H2T (lin2 out, BN in-place) [dead after edge decode]
  // 36..52M : MID (lin1 out, 2 x 8M)            [dead after lin2]
  //           -> P0f fp32 edge partials         [dead after addcvt]
  //           -> QKQK (36..44M), V^T (44..48M), AO (48..52M)
  unsigned short* Pt = W;
  unsigned short* ENC = W + 4 * M1;
  unsigned short* E1T = W + 12 * M1;
  unsigned short* WT = W + 16 * M1;
  unsigned short* NE = W + 20 * M1;
  unsigned short* H1T = W + 20 * M1;
  unsigned short* MID = W + 36 * M1;
  float* P0f = (float*)(W + 36 * M1);
  unsigned short* E1 = W + 4 * M1;
  unsigned short* E2 = W + 6 * M1;
  unsigned short* QKV = W + 36 * M1;
  unsigned short* VT = W + 44 * M1;
  unsigned short* AO = W + 48 * M1;
  unsigned short* A1P = W + 8 * M1;
  unsigned short* A2P = W + 10 * M1;
  float* ST = (float*)(W + 56 * M1);
  float* CS = ST + 2048;
  float* RS = CS + 8192;

  const dim3 T(256);
  const long sP = 262144;   // per-n Pt stride
  const long sNE = 2097152; // per-n node-enc stride
  const long sE = 524288;   // per-n edge stride
  const long sD = 4194304;

  // --- prep (direct transposed pooled) + operand conversion ---
  prep_pool_t<<<dim3(64, 4, 8), T, 0, stream>>>(x1, x2, Pt);
  convert2_f2b<<<dim3(4096, 1, 2), T, 0, stream>>>(enc1, enc2, ENC);
  transpose_f2b<<<dim3(16, 64), T, 0, stream>>>(enc1, E1T, 4096, 1024);
  WPtrs wp;
  wp.p[0] = (const float*)d_in[4];   // mlp_w1
  wp.p[1] = (const float*)d_in[6];   // mlp_w2
  wp.p[2] = (const float*)d_in[10];  // nlp_w1
  wp.p[3] = (const float*)d_in[12];  // nlp_w2
  wp.p[4] = (const float*)d_in[16];  // a1_wq
  wp.p[5] = (const float*)d_in[18];  // a1_wk
  wp.p[6] = (const float*)d_in[24];  // a2_wq
  wp.p[7] = (const float*)d_in[26];  // a2_wk
  wp.p[8] = (const float*)d_in[20];  // a1_wv
  wp.p[9] = (const float*)d_in[28];  // a2_wv
  wp.p[10] = (const float*)d_in[22]; // a1_fc
  wp.p[11] = (const float*)d_in[30]; // a2_fc
  wtrans<<<dim3(8, 8, 12), T, 0, stream>>>(wp, WT);

  // --- node_enc for BOTH branches: z=16 (inp x pr x n) -> NE ---
  {
    GDescs g{};
    for (int inp = 0; inp < 2; ++inp)
      for (int pr = 0; pr < 2; ++pr)
        for (int nn = 0; nn < 4; ++nn)
          g.d[inp * 8 + pr * 4 + nn] = {
              ENC + (long)pr * (4 * M1), Pt + (long)inp * M1 + nn * sP,
              (long)inp * (8 * M1) + (long)nn * sNE + pr * 256, nullptr};
    gemm_z<0, 1, 1><<<dim3(2, 32, 16), T, 0, stream>>>(g, NE, 1024, 1024,
                                                       1024, 512, 0, 1.f);
  }
  // --- lin1 both branches (z=2) -> MID (each branch = 8M us!) ---
  {
    GDescs g{};
    g.d[0] = {NE, WT + 0 * S, 0, mlp_b1};
    g.d[1] = {NE + 8 * M1, WT + 2 * S, 8 * M1, nlp_b1};
    gemm_z<1, 1, 1><<<dim3(4, 128, 2), T, 0, stream>>>(g, MID, 512, 512, 512,
                                                       512, 0, 1.f);
  }
  // --- lin2^T both branches (z=2) -> H1T/H2T (over NE, dead) ---
  {
    GDescs g{};
    g.d[0] = {MID, WT + 1 * S, 0, mlp_b2};
    g.d[1] = {MID + 8 * M1, WT + 3 * S, 8 * M1, nlp_b2};
    gemm_z<0, 3, 1><<<dim3(4, 128, 2), T, 0, stream>>>(g, H1T, 512, 512, 512,
                                                       16384, 0, 1.f);
  }
  bn_stats_t<<<dim3(512, 1, 2), T, 0, stream>>>(H1T, ST);
  bn_apply_t<<<dim3(8192, 1, 2), T, 0, stream>>>(H1T, ST, mlp_g, mlp_be,
                                                 nlp_g, nlp_be);

  // --- edge decode: z = 8 descs x split-K 2, fp32 partials in MID region ---
  {
    GDescs g{};
    for (int d = 0; d < 8; ++d)
      g.d[d] = {E1T, H1T + (long)(d >> 2) * (8 * M1) + (d & 3) * 4096,
                (long)d * 524288, nullptr};
    gemm_z<0, 0, 2><<<dim3(4, 8, 16), T, 0, stream>>>(g, P0f, 2048, 4096,
                                                      16384, 512, 4194304, 1.f);
  }
  addcvt<<<4096, T, 0, stream>>>(P0f, P0f + 4194304, E1, 1.f / 1024.f);

  // --- projections: Q1,K1,Q2,K2 (z=4) -> QKV; V1,V2 (z=2, V^T) -> VT ---
  {
    GDescs g{};
    g.d[0] = {E2, WT + 4 * S, 0, (const float*)d_in[17]};
    g.d[1] = {E1, WT + 5 * S, 2 * M1, (const float*)d_in[19]};
    g.d[2] = {E1, WT + 6 * S, 4 * M1, (const float*)d_in[25]};
    g.d[3] = {E2, WT + 7 * S, 6 * M1, (const float*)d_in[27]};
    gemm_z<0, 1, 1><<<dim3(4, 32, 4), T, 0, stream>>>(g, QKV, 512, 512, 512,
                                                      512, 0, 1.f);
  }
  {
    GDescs g{};
    g.d[0] = {E1, WT + 8 * S, 0, (const float*)d_in[21]};
    g.d[1] = {E2, WT + 9 * S, 2 * M1, (const float*)d_in[29]};
    gemm_z<0, 2, 1><<<dim3(4, 32, 2), T, 0, stream>>>(g, VT, 512, 512, 512,
                                                      512, 0, 1.f);
  }

  // --- both attentions ---
  attn_mfma<<<dim3(16, 8, 8), T, 0, stream>>>(QKV, QKV + 2 * M1, VT, AO);

  // --- fc for both attentions -> A1P/A2P ---
  {
    GDescs g{};
    g.d[0] = {AO, WT + 10 * S, 0, (const float*)d_in[23]};
    g.d[1] = {AO + 2 * M1, WT + 11 * S, 2 * M1, (const float*)d_in[31]};
    gemm_z<0, 1, 1><<<dim3(4, 32, 2), T, 0, stream>>>(g, A1P, 512, 512, 512,
                                                      512, 0, 1.f);
  }

  // --- logits: all 4 quadrants x 4 n in one dispatch (z=16) ---
  {
    GDescs g{};
    for (int q = 0; q < 4; ++q)
      for (int n = 0; n < 4; ++n) {
        const unsigned short* A = (q < 2 ? A1P : A2P) + n * sE;
        const unsigned short* B = ((q == 0 || q == 2) ? A2P : A1P) + n * sE;
        const long coff =
            (long)n * sD + (q & 1) * 1024 + (long)(q >> 1) * 2097152;
        g.d[q * 4 + n] = {A, B, coff, nullptr};
      }
    gemm_z<0, 0, 1><<<dim3(8, 8, 16), T, 0, stream>>>(g, out, 512, 512, 512,
                                                      2048, 0, 1.f);
  }

  // --- softmax + column normalization (2 passes, no middle write) ---
  hipMemsetAsync(CS, 0, 8192 * sizeof(float), stream);
  softmax_cs<<<1024, T, 0, stream>>>(out, RS, CS);
  final_scale<<<16384, T, 0, stream>>>(out, RS, CS);
}

// Round 8
// 390.584 us; speedup vs baseline: 6.3395x; 1.0047x over previous
//
#include <hip/hip_runtime.h>
#include <hip/hip_bf16.h>

#define LEAKY(v) ((v) >= 0.f ? (v) : 0.01f * (v))

typedef __attribute__((ext_vector_type(8))) short short8b;
typedef __attribute__((ext_vector_type(4))) float f32x4;
typedef __attribute__((ext_vector_type(4))) unsigned short us4;

__device__ __forceinline__ unsigned short f2b(float f) {
  unsigned int u = __builtin_bit_cast(unsigned int, f);
  return (unsigned short)((u + 0x7FFFu + ((u >> 16) & 1u)) >> 16);
}
__device__ __forceinline__ float b2f(unsigned short s) {
  return __builtin_bit_cast(float, (unsigned int)s << 16);
}

__device__ __forceinline__ void gload16(const unsigned short* g, unsigned short* l) {
  __builtin_amdgcn_global_load_lds(
      (const __attribute__((address_space(1))) unsigned int*)(g),
      (__attribute__((address_space(3))) unsigned int*)(l), 16, 0, 0);
}

// Stage a 64x64 bf16 tile (rows of 128B) global->LDS, XOR-swizzled source.
__device__ __forceinline__ void stage64(const unsigned short* g, int ldg,
                                        unsigned short* lds, int lane, int w) {
  const int r8 = lane >> 3;
  const int ce = ((lane & 7) ^ r8) << 3;
  const int r0 = w * 8 + r8;
  gload16(g + (long)r0 * ldg + ce, lds + w * 512);
  gload16(g + (long)(r0 + 32) * ldg + ce, lds + 2048 + w * 512);
}

// Swizzled 16B read: row, c4 = 16B-column index 0..7
__device__ __forceinline__ short8b ldsw(const unsigned short* base, int row, int c4) {
  return *(const short8b*)&base[row * 64 + (((c4 ^ (row & 7)) << 3))];
}

// ---------------------------------------------------------------------------
// prep stage A: depth-4 channel partial sums, fully coalesced read + write.
// S[((z*16 + y)*64 + t)*1024 + v] = sum_{m<4} X[n, y*4+m, t, v]
//   (y = cbi*4+sub encodes a 4-channel sub-window; z = inp*4+n)
// ---------------------------------------------------------------------------
__global__ __launch_bounds__(256) void prep_partial(const float* __restrict__ X1,
                                                    const float* __restrict__ X2,
                                                    float* __restrict__ S) {
  const int t = blockIdx.x;   // 0..63
  const int y = blockIdx.y;   // 0..15
  const int z = blockIdx.z;   // 0..7
  const float* X = (z >> 2) ? X2 : X1;
  const int n = z & 3;
  const int tid = threadIdx.x;
  const long base = (((long)n * 64 + y * 4) * 64 + t) * 1024 + tid * 4;
  const float4 a = *(const float4*)&X[base];
  const float4 b = *(const float4*)&X[base + 65536];
  const float4 c = *(const float4*)&X[base + 2 * 65536];
  const float4 d = *(const float4*)&X[base + 3 * 65536];
  float4 o;
  o.x = (a.x + b.x) + (c.x + d.x);
  o.y = (a.y + b.y) + (c.y + d.y);
  o.z = (a.z + b.z) + (c.z + d.z);
  o.w = (a.w + b.w) + (c.w + d.w);
  *(float4*)&S[(((long)z * 16 + y) * 64 + t) * 1024 + tid * 4] = o;
}

// ---------------------------------------------------------------------------
// prep stage B: combine 4 sub-window partials, write pooled^T bf16.
// Pt[inp][n][k][i], k = vvv*4 + cbi, i = t*16 + vb
// ---------------------------------------------------------------------------
__global__ __launch_bounds__(256) void prep_finish(const float* __restrict__ S,
                                                   unsigned short* __restrict__ Pt) {
  const int t = blockIdx.x;   // 0..63
  const int cbi = blockIdx.y; // 0..3
  const int z = blockIdx.z;   // inp*4+n
  const int n = z & 3, inp = z >> 2;
  const int tid = threadIdx.x;
  __shared__ unsigned short sacc[64][20];
  const long sb = (((long)z * 16 + cbi * 4) * 64 + t) * 1024 + tid * 4;
  const float4 a = *(const float4*)&S[sb];
  const float4 b = *(const float4*)&S[sb + 65536];
  const float4 c = *(const float4*)&S[sb + 2 * 65536];
  const float4 d = *(const float4*)&S[sb + 3 * 65536];
  float acc[4];
  acc[0] = (a.x + b.x) + (c.x + d.x);
  acc[1] = (a.y + b.y) + (c.y + d.y);
  acc[2] = (a.z + b.z) + (c.z + d.z);
  acc[3] = (a.w + b.w) + (c.w + d.w);
  const int q = tid & 15, vb = tid >> 4;
#pragma unroll
  for (int j = 0; j < 4; ++j)
    sacc[q * 4 + j][vb] = f2b(acc[j] * (1.f / 16.f));
  __syncthreads();
  const int vvv = tid >> 2, iq = tid & 3;
  const us4 o = *(const us4*)&sacc[vvv][iq * 4];
  *(us4*)&Pt[(long)inp * (1L << 20) + (long)n * 262144 +
             (long)(vvv * 4 + cbi) * 1024 + t * 16 + iq * 4] = o;
}

// ---------------------------------------------------------------------------
// fp32 (R x C) -> bf16 (C x R) transpose
// ---------------------------------------------------------------------------
__global__ __launch_bounds__(256) void transpose_f2b(
    const float* __restrict__ in, unsigned short* __restrict__ out, int R, int C) {
  __shared__ float t[64][65];
  const int c0 = blockIdx.x * 64, r0 = blockIdx.y * 64;
  const int tid = threadIdx.x;
#pragma unroll
  for (int it = 0; it < 4; ++it) {
    int idx = tid + it * 256;
    int r = idx >> 4, c4 = (idx & 15) * 4;
    float4 v = *(const float4*)&in[(long)(r0 + r) * C + c0 + c4];
    t[c4 + 0][r] = v.x; t[c4 + 1][r] = v.y;
    t[c4 + 2][r] = v.z; t[c4 + 3][r] = v.w;
  }
  __syncthreads();
#pragma unroll
  for (int it = 0; it < 4; ++it) {
    int idx = tid + it * 256;
    int c = idx >> 4, r4 = (idx & 15) * 4;
    us4 o;
    o[0] = f2b(t[c][r4 + 0]); o[1] = f2b(t[c][r4 + 1]);
    o[2] = f2b(t[c][r4 + 2]); o[3] = f2b(t[c][r4 + 3]);
    *(us4*)&out[(long)(c0 + c) * R + r0 + r4] = o;
  }
}

// fused 12x 512x512 weight transpose+convert
struct WPtrs { const float* p[12]; };
__global__ __launch_bounds__(256) void wtrans(WPtrs wp, unsigned short* __restrict__ out) {
  const float* in = wp.p[blockIdx.z];
  unsigned short* ob = out + (long)blockIdx.z * 262144;
  __shared__ float t[64][65];
  const int c0 = blockIdx.x * 64, r0 = blockIdx.y * 64;
  const int tid = threadIdx.x;
#pragma unroll
  for (int it = 0; it < 4; ++it) {
    int idx = tid + it * 256;
    int r = idx >> 4, c4 = (idx & 15) * 4;
    float4 v = *(const float4*)&in[(long)(r0 + r) * 512 + c0 + c4];
    t[c4 + 0][r] = v.x; t[c4 + 1][r] = v.y;
    t[c4 + 2][r] = v.z; t[c4 + 3][r] = v.w;
  }
  __syncthreads();
#pragma unroll
  for (int it = 0; it < 4; ++it) {
    int idx = tid + it * 256;
    int c = idx >> 4, r4 = (idx & 15) * 4;
    us4 o;
    o[0] = f2b(t[c][r4 + 0]); o[1] = f2b(t[c][r4 + 1]);
    o[2] = f2b(t[c][r4 + 2]); o[3] = f2b(t[c][r4 + 3]);
    *(us4*)&ob[(long)(c0 + c) * 512 + r0 + r4] = o;
  }
}

// fp32 -> bf16 convert, two inputs (z selects), each 1M quads
__global__ __launch_bounds__(256) void convert2_f2b(const float* __restrict__ i1,
                                                    const float* __restrict__ i2,
                                                    unsigned short* __restrict__ out) {
  const float* in = blockIdx.z ? i2 : i1;
  unsigned short* o = out + (long)blockIdx.z * (4L << 20);
  long i = (long)blockIdx.x * 256 + threadIdx.x;
  float4 v = ((const float4*)in)[i];
  us4 q;
  q[0] = f2b(v.x); q[1] = f2b(v.y); q[2] = f2b(v.z); q[3] = f2b(v.w);
  ((us4*)o)[i] = q;
}

// add two fp32 partials, scale, convert to bf16
__global__ __launch_bounds__(256) void addcvt(const float* __restrict__ P0,
                                              const float* __restrict__ P1,
                                              unsigned short* __restrict__ out,
                                              float alpha) {
  const long i = ((long)blockIdx.x * 256 + threadIdx.x) * 4;
  const float4 a = *(const float4*)&P0[i];
  const float4 b = *(const float4*)&P1[i];
  us4 o;
  o[0] = f2b((a.x + b.x) * alpha);
  o[1] = f2b((a.y + b.y) * alpha);
  o[2] = f2b((a.z + b.z) * alpha);
  o[3] = f2b((a.w + b.w) * alpha);
  *(us4*)&out[i] = o;
}

// ---------------------------------------------------------------------------
// bf16 MFMA GEMM, 128x128 tile, BK=64, 4 waves; XOR-swizzled LDS.
// Per-z descriptor: A, B (row-major; B in N x K "B^T" layout), C offset, bias,
// mode (used by CMODE==4). KSPLIT=2: s = bz%2 shifts A/B cols by s*K, C by
// s*sC2 (fp32 partials).
// CMODE: 0 fp32; 1 bf16; 2 bf16 attn-V^T layout; 3 bf16 transposed (C^T);
//        4 per-desc (mode==2 -> V^T layout, else bf16 row-major).
// ---------------------------------------------------------------------------
struct GDesc { const unsigned short* A; const unsigned short* B; long coff;
               const float* bias; int mode; };
struct GDescs { GDesc d[16]; };

template <int ACT, int CMODE, int KSPLIT>
__global__ __launch_bounds__(256) void gemm_z(
    GDescs ga, void* __restrict__ Cv, int K, int lda, int ldb, int ldc,
    long sC2, float alpha) {
  const int bz = blockIdx.z;
  const int s = (KSPLIT > 1) ? (bz % KSPLIT) : 0;
  const int zb = (KSPLIT > 1) ? (bz / KSPLIT) : bz;
  const GDesc g = ga.d[zb];
  const unsigned short* Ab = g.A + (long)s * K;
  const unsigned short* Bb = g.B + (long)s * K;
  const int m0 = blockIdx.y * 128, n0 = blockIdx.x * 128;
  const int tid = threadIdx.x;
  const int lane = tid & 63, w = tid >> 6;
  const int wr = (w >> 1) * 64, wc = (w & 1) * 64;
  __shared__ unsigned short As[128 * 64];
  __shared__ unsigned short Bs[128 * 64];
  f32x4 acc[4][4];
#pragma unroll
  for (int i = 0; i < 4; ++i)
#pragma unroll
    for (int j = 0; j < 4; ++j) acc[i][j] = (f32x4){0.f, 0.f, 0.f, 0.f};
  const int srow = tid >> 3;
  const int scol = (((tid & 7) ^ ((tid >> 3) & 7)) << 3);
  const int rl = lane & 15, lg = lane >> 4, rx = rl & 7;
  for (int k0 = 0; k0 < K; k0 += 64) {
    __syncthreads();
#pragma unroll
    for (int it = 0; it < 4; ++it) {
      gload16(Ab + (long)(m0 + it * 32 + srow) * lda + k0 + scol,
              As + w * 512 + it * 2048);
      gload16(Bb + (long)(n0 + it * 32 + srow) * ldb + k0 + scol,
              Bs + w * 512 + it * 2048);
    }
    __syncthreads();
#pragma unroll
    for (int kk = 0; kk < 2; ++kk) {
      short8b af[4], bfr[4];
#pragma unroll
      for (int m = 0; m < 4; ++m)
        af[m] = *(const short8b*)&As[(wr + m * 16 + rl) * 64 +
                                     ((((kk * 4 + lg) ^ rx)) << 3)];
#pragma unroll
      for (int nn = 0; nn < 4; ++nn)
        bfr[nn] = *(const short8b*)&Bs[(wc + nn * 16 + rl) * 64 +
                                       ((((kk * 4 + lg) ^ rx)) << 3)];
#pragma unroll
      for (int m = 0; m < 4; ++m)
#pragma unroll
        for (int nn = 0; nn < 4; ++nn)
          acc[m][nn] = __builtin_amdgcn_mfma_f32_16x16x32_bf16(
              af[m], bfr[nn], acc[m][nn], 0, 0, 0);
    }
  }
  const int rrow = lg * 4;
  float bv[4];
#pragma unroll
  for (int nn = 0; nn < 4; ++nn)
    bv[nn] = g.bias ? g.bias[n0 + wc + nn * 16 + rl] : 0.f;
  const bool vt_layout = (CMODE == 2) || (CMODE == 4 && g.mode == 2);
  if (CMODE == 2 || CMODE == 4) {
    if (vt_layout) {
#pragma unroll
      for (int m = 0; m < 4; ++m)
#pragma unroll
        for (int nn = 0; nn < 4; ++nn) {
          const int row = m0 + wr + m * 16 + rrow;
          const int col = n0 + wc + nn * 16 + rl;
          us4 o;
#pragma unroll
          for (int r = 0; r < 4; ++r) {
            float v = alpha * acc[m][nn][r] + bv[nn];
            if (ACT == 1) v = LEAKY(v);
            o[r] = f2b(v);
          }
          const long off = g.coff + (long)(row >> 10) * 524288 +
                           (long)col * 1024 + (row & 1023);
          *(us4*)&((unsigned short*)Cv)[off] = o;
        }
    } else {
#pragma unroll
      for (int m = 0; m < 4; ++m)
#pragma unroll
        for (int nn = 0; nn < 4; ++nn)
#pragma unroll
          for (int r = 0; r < 4; ++r) {
            float v = alpha * acc[m][nn][r] + bv[nn];
            if (ACT == 1) v = LEAKY(v);
            const long off = g.coff +
                             (long)(m0 + wr + m * 16 + rrow + r) * ldc + n0 +
                             wc + nn * 16 + rl;
            ((unsigned short*)Cv)[off] = f2b(v);
          }
    }
  } else if (CMODE == 3) {
#pragma unroll
    for (int m = 0; m < 4; ++m)
#pragma unroll
      for (int nn = 0; nn < 4; ++nn) {
        const int row = m0 + wr + m * 16 + rrow;
        const int col = n0 + wc + nn * 16 + rl;
        us4 o;
#pragma unroll
        for (int r = 0; r < 4; ++r) {
          float v = alpha * acc[m][nn][r] + bv[nn];
          if (ACT == 1) v = LEAKY(v);
          o[r] = f2b(v);
        }
        *(us4*)&((unsigned short*)Cv)[g.coff + (long)col * ldc + row] = o;
      }
  } else {
#pragma unroll
    for (int m = 0; m < 4; ++m)
#pragma unroll
      for (int nn = 0; nn < 4; ++nn)
#pragma unroll
        for (int r = 0; r < 4; ++r) {
          float v = alpha * acc[m][nn][r] + bv[nn];
          if (ACT == 1) v = LEAKY(v);
          long off = g.coff + (long)s * sC2 +
                     (long)(m0 + wr + m * 16 + rrow + r) * ldc + n0 + wc +
                     nn * 16 + rl;
          if (CMODE == 1)
            ((unsigned short*)Cv)[off] = f2b(v);
          else
            ((float*)Cv)[off] = v;
        }
  }
}

// ---------------------------------------------------------------------------
// BatchNorm on transposed layout h^T (512 features x 16384 samples), bf16.
// z selects branch (X offset z*8M, ST offset z*1024, per-z gamma/beta).
// ---------------------------------------------------------------------------
__global__ __launch_bounds__(256) void bn_stats_t(const unsigned short* __restrict__ X,
                                                  float* __restrict__ ST) {
  const int f = blockIdx.x;
  const int z = blockIdx.z;
  const unsigned short* p = X + (long)z * (8L << 20) + (long)f * 16384;
  float* st = ST + z * 1024;
  const int tid = threadIdx.x;
  float s = 0.f, q = 0.f;
#pragma unroll
  for (int k = 0; k < 16; ++k) {
    us4 v = *(const us4*)&p[(k * 256 + tid) * 4];
#pragma unroll
    for (int j = 0; j < 4; ++j) {
      const float x = b2f(v[j]);
      s += x; q += x * x;
    }
  }
#pragma unroll
  for (int mask = 1; mask < 64; mask <<= 1) {
    s += __shfl_xor(s, mask, 64);
    q += __shfl_xor(q, mask, 64);
  }
  __shared__ float rs[8];
  const int wv = tid >> 6;
  if ((tid & 63) == 0) { rs[wv] = s; rs[4 + wv] = q; }
  __syncthreads();
  if (tid == 0) {
    s = rs[0] + rs[1] + rs[2] + rs[3];
    q = rs[4] + rs[5] + rs[6] + rs[7];
    const float mu = s * (1.f / 16384.f);
    st[f] = mu;
    st[512 + f] = q * (1.f / 16384.f) - mu * mu;
  }
}

__global__ __launch_bounds__(256) void bn_apply_t(
    unsigned short* __restrict__ X, const float* __restrict__ ST,
    const float* __restrict__ g1, const float* __restrict__ be1,
    const float* __restrict__ g2, const float* __restrict__ be2) {
  const int z = blockIdx.z;
  unsigned short* Xb = X + (long)z * (8L << 20);
  const float* st = ST + z * 1024;
  const float* g = z ? g2 : g1;
  const float* be = z ? be2 : be1;
  const long i = ((long)blockIdx.x * 256 + threadIdx.x) * 4;
  const int f = (int)(i >> 14);
  const float rs = rsqrtf(st[512 + f] + 1e-5f) * g[f];
  const float bb = be[f] - st[f] * rs;
  us4 v = *(const us4*)&Xb[i];
  us4 o;
#pragma unroll
  for (int j = 0; j < 4; ++j) {
    const float y = b2f(v[j]) * rs + bb;
    o[j] = f2b(LEAKY(y));
  }
  *(us4*)&Xb[i] = o;
}

// ---------------------------------------------------------------------------
// bf16 MFMA flash attention, both attentions in one dispatch (z = 8).
// exp2-domain softmax + defer-max (T13): skip O-rescale while the running
// max grows by < 8 nats (11.54 bits); P bounded by e^8, f32 accum absorbs.
// ---------------------------------------------------------------------------
__global__ __launch_bounds__(256) void attn_mfma(
    const unsigned short* __restrict__ Q, const unsigned short* __restrict__ K,
    const unsigned short* __restrict__ Vt, unsigned short* __restrict__ O) {
  const int qb = blockIdx.x, h = blockIdx.y;
  const int n = blockIdx.z & 3, sel = blockIdx.z >> 2;
  Q += (long)sel * 4194304;
  K += (long)sel * 4194304;
  Vt += (long)sel * 2097152;
  O += (long)sel * 2097152;
  const int tid = threadIdx.x;
  const int lane = tid & 63, w = tid >> 6;
  const int rl = lane & 15, lg = lane >> 4;
  __shared__ unsigned short Qs[4096];
  __shared__ unsigned short Ks[4096];
  __shared__ unsigned short Vs[4096];
  __shared__ unsigned short Ps[4096];
  stage64(Q + ((long)n * 1024 + qb * 64) * 512 + h * 64, 512, Qs, lane, w);
  float m_r = -1e30f, l_r = 0.f;
  f32x4 po[4];
#pragma unroll
  for (int i = 0; i < 4; ++i) po[i] = (f32x4){0.f, 0.f, 0.f, 0.f};
  const unsigned short* Kg0 = K + ((long)n * 1024) * 512 + h * 64;
  const unsigned short* Vg0 = Vt + (long)n * 524288 + (long)(h * 64) * 1024;
  const float K2 = 0.18033688f;  // 0.125 * log2(e)
  for (int kt = 0; kt < 16; ++kt) {
    __syncthreads();
    stage64(Kg0 + (long)(kt * 64) * 512, 512, Ks, lane, w);
    stage64(Vg0 + kt * 64, 1024, Vs, lane, w);
    __syncthreads();
    f32x4 sa[4];
#pragma unroll
    for (int i = 0; i < 4; ++i) sa[i] = (f32x4){0.f, 0.f, 0.f, 0.f};
#pragma unroll
    for (int kk = 0; kk < 2; ++kk) {
      const short8b qf = ldsw(Qs, w * 16 + rl, 4 * kk + lg);
#pragma unroll
      for (int mt = 0; mt < 4; ++mt) {
        const short8b kf = ldsw(Ks, mt * 16 + rl, 4 * kk + lg);
        sa[mt] = __builtin_amdgcn_mfma_f32_16x16x32_bf16(kf, qf, sa[mt], 0, 0, 0);
      }
    }
    // base-2 domain logits
    float pr[4][4];
    float mx = -1e30f;
#pragma unroll
    for (int mt = 0; mt < 4; ++mt)
#pragma unroll
      for (int r = 0; r < 4; ++r) {
        pr[mt][r] = sa[mt][r] * K2;
        mx = fmaxf(mx, pr[mt][r]);
      }
    mx = fmaxf(mx, __shfl_xor(mx, 16, 64));
    mx = fmaxf(mx, __shfl_xor(mx, 32, 64));
    float fl = 1.f;
    const bool skip = __all(mx <= m_r + 11.541561f);
    if (!skip) {
      const float mn = fmaxf(m_r, mx);
      const float f = exp2f(m_r - mn);
      m_r = mn;
      fl = f;
#pragma unroll
      for (int r = 0; r < 4; ++r) {
        const float fr = __shfl(f, lg * 4 + r, 64);
#pragma unroll
        for (int nt = 0; nt < 4; ++nt) po[nt][r] *= fr;
      }
    }
    float ps = 0.f;
    const int q = w * 16 + rl;
#pragma unroll
    for (int mt = 0; mt < 4; ++mt) {
      us4 o;
#pragma unroll
      for (int r = 0; r < 4; ++r) {
        const float p = exp2f(pr[mt][r] - m_r);
        ps += p;
        o[r] = f2b(p);
      }
      const int c16 = (4 * mt + lg) >> 1;
      *(us4*)&Ps[q * 64 + ((c16 ^ (q & 7)) << 3) + ((lg & 1) << 2)] = o;
    }
    ps += __shfl_xor(ps, 16, 64);
    ps += __shfl_xor(ps, 32, 64);
    l_r = l_r * fl + ps;
#pragma unroll
    for (int kk = 0; kk < 2; ++kk) {
      const short8b pf = ldsw(Ps, w * 16 + rl, 4 * kk + lg);
#pragma unroll
      for (int nt = 0; nt < 4; ++nt) {
        const short8b vf = ldsw(Vs, nt * 16 + rl, 4 * kk + lg);
        po[nt] = __builtin_amdgcn_mfma_f32_16x16x32_bf16(pf, vf, po[nt], 0, 0, 0);
      }
    }
  }
  float invr[4];
#pragma unroll
  for (int r = 0; r < 4; ++r) invr[r] = 1.f / __shfl(l_r, lg * 4 + r, 64);
  const long ob = ((long)n * 1024 + qb * 64 + w * 16) * 512 + h * 64;
#pragma unroll
  for (int nt = 0; nt < 4; ++nt)
#pragma unroll
    for (int r = 0; r < 4; ++r)
      O[ob + (long)(lg * 4 + r) * 512 + nt * 16 + rl] = f2b(po[nt][r] * invr[r]);
}

// ---------------------------------------------------------------------------
// Softmax pass 1: per-row max & 1/sum, plus column sums of softmax(A).
// ---------------------------------------------------------------------------
__global__ __launch_bounds__(256) void softmax_cs(const float* __restrict__ D,
                                                  float* __restrict__ RS,
                                                  float* __restrict__ CS) {
  __shared__ float colacc[2048];
  __shared__ float red[8];
  const int tid = threadIdx.x;
  const int wv = tid >> 6, ln = tid & 63;
#pragma unroll
  for (int k = 0; k < 8; ++k) colacc[tid + k * 256] = 0.f;
  __syncthreads();
  const int r0 = blockIdx.x * 8;
  const int n = r0 >> 11;
  for (int rr = 0; rr < 8; ++rr) {
    const float* p = D + (long)(r0 + rr) * 2048;
    float v[8];
    float mx = -1e30f;
#pragma unroll
    for (int k = 0; k < 8; ++k) {
      v[k] = p[tid + k * 256];
      mx = fmaxf(mx, v[k]);
    }
#pragma unroll
    for (int mask = 1; mask < 64; mask <<= 1) mx = fmaxf(mx, __shfl_xor(mx, mask, 64));
    if (ln == 0) red[wv] = mx;
    __syncthreads();
    mx = fmaxf(fmaxf(red[0], red[1]), fmaxf(red[2], red[3]));
    float sum = 0.f;
#pragma unroll
    for (int k = 0; k < 8; ++k) {
      v[k] = __expf(v[k] - mx);
      sum += v[k];
    }
#pragma unroll
    for (int mask = 1; mask < 64; mask <<= 1) sum += __shfl_xor(sum, mask, 64);
    if (ln == 0) red[4 + wv] = sum;
    __syncthreads();
    sum = red[4] + red[5] + red[6] + red[7];
    const float inv = 1.f / sum;
    if (tid == 0) {
      RS[(r0 + rr) * 2] = mx;
      RS[(r0 + rr) * 2 + 1] = inv;
    }
#pragma unroll
    for (int k = 0; k < 8; ++k) colacc[tid + k * 256] += v[k] * inv;
    __syncthreads();
  }
#pragma unroll
  for (int k = 0; k < 8; ++k)
    atomicAdd(&CS[n * 2048 + tid + k * 256], colacc[tid + k * 256]);
}

// Pass 2: recompute softmax from logits + row stats, apply column normalize.
__global__ __launch_bounds__(256) void final_scale(float* __restrict__ D,
                                                   const float* __restrict__ RS,
                                                   const float* __restrict__ CS) {
  const long i = ((long)blockIdx.x * 256 + threadIdx.x) * 4;
  const long row = i >> 11;
  const int n = (int)(row >> 11);
  const int j = (int)(i & 2047);
  const float mx = RS[row * 2];
  const float inv = RS[row * 2 + 1];
  float4 v = *(float4*)&D[i];
  const float* c = &CS[n * 2048 + j];
  v.x = __expf(v.x - mx) * inv * (c[0] > 0.f ? 1.f / c[0] : 0.f);
  v.y = __expf(v.y - mx) * inv * (c[1] > 0.f ? 1.f / c[1] : 0.f);
  v.z = __expf(v.z - mx) * inv * (c[2] > 0.f ? 1.f / c[2] : 0.f);
  v.w = __expf(v.w - mx) * inv * (c[3] > 0.f ? 1.f / c[3] : 0.f);
  *(float4*)&D[i] = v;
}

// ---------------------------------------------------------------------------
extern "C" void kernel_launch(void* const* d_in, const int* in_sizes, int n_in,
                              void* d_out, int out_size, void* d_ws,
                              size_t ws_size, hipStream_t stream) {
  const float* x1 = (const float*)d_in[0];
  const float* x2 = (const float*)d_in[1];
  const float* enc1 = (const float*)d_in[2];
  const float* enc2 = (const float*)d_in[3];
  const float* mlp_b1 = (const float*)d_in[5];
  const float* mlp_b2 = (const float*)d_in[7];
  const float* mlp_g = (const float*)d_in[8];
  const float* mlp_be = (const float*)d_in[9];
  const float* nlp_b1 = (const float*)d_in[11];
  const float* nlp_b2 = (const float*)d_in[13];
  const float* nlp_g = (const float*)d_in[14];
  const float* nlp_be = (const float*)d_in[15];
  float* out = (float*)d_out;

  unsigned short* W = (unsigned short*)d_ws;
  const long M1 = 1L << 20;
  const long S = 262144;
  // Rolling layout (us units), lifetimes disjoint-in-time:
  //  0.. 2M : Pt                               [dead after node_enc]
  //  4..12M : ENC -> E1/E2 (4..8M) -> A1P/A2P (8..12M)
  // 12..16M : E1T                              [dead after edge decode]
  // 16..19M : WT                               [dead after fc]
  // 20..36M : NE -> H1T/H2T                    [dead after edge decode]
  // 36..52M : Sprep (prep partials, 32MB) -> MID (lin1) -> edge partials
  //           -> QKQK (36..44M), V^T (44..48M), AO (48..52M)
  unsigned short* Pt = W;
  unsigned short* ENC = W + 4 * M1;
  unsigned short* E1T = W + 12 * M1;
  unsigned short* WT = W + 16 * M1;
  unsigned short* NE = W + 20 * M1;
  unsigned short* H1T = W + 20 * M1;
  unsigned short* MID = W + 36 * M1;
  float* Sprep = (float*)(W + 36 * M1);
  float* P0f = (float*)(W + 36 * M1);
  unsigned short* E1 = W + 4 * M1;
  unsigned short* E2 = W + 6 * M1;
  unsigned short* QKV = W + 36 * M1;
  unsigned short* VT = W + 44 * M1;
  unsigned short* AO = W + 48 * M1;
  unsigned short* A1P = W + 8 * M1;
  unsigned short* A2P = W + 10 * M1;
  float* ST = (float*)(W + 56 * M1);
  float* CS = ST + 2048;
  float* RS = CS + 8192;

  const dim3 T(256);
  const long sP = 262144;   // per-n Pt stride
  const long sNE = 2097152; // per-n node-enc stride
  const long sE = 524288;   // per-n edge stride
  const long sD = 4194304;

  // --- prep (2-stage pooled^T) + operand conversion ---
  prep_partial<<<dim3(64, 16, 8), T, 0, stream>>>(x1, x2, Sprep);
  prep_finish<<<dim3(64, 4, 8), T, 0, stream>>>(Sprep, Pt);
  convert2_f2b<<<dim3(4096, 1, 2), T, 0, stream>>>(enc1, enc2, ENC);
  transpose_f2b<<<dim3(16, 64), T, 0, stream>>>(enc1, E1T, 4096, 1024);
  WPtrs wp;
  wp.p[0] = (const float*)d_in[4];   // mlp_w1
  wp.p[1] = (const float*)d_in[6];   // mlp_w2
  wp.p[2] = (const float*)d_in[10];  // nlp_w1
  wp.p[3] = (const float*)d_in[12];  // nlp_w2
  wp.p[4] = (const float*)d_in[16];  // a1_wq
  wp.p[5] = (const float*)d_in[18];  // a1_wk
  wp.p[6] = (const float*)d_in[24];  // a2_wq
  wp.p[7] = (const float*)d_in[26];  // a2_wk
  wp.p[8] = (const float*)d_in[20];  // a1_wv
  wp.p[9] = (const float*)d_in[28];  // a2_wv
  wp.p[10] = (const float*)d_in[22]; // a1_fc
  wp.p[11] = (const float*)d_in[30]; // a2_fc
  wtrans<<<dim3(8, 8, 12), T, 0, stream>>>(wp, WT);

  // --- node_enc for BOTH branches: z=16 (inp x pr x n) -> NE ---
  {
    GDescs g{};
    for (int inp = 0; inp < 2; ++inp)
      for (int pr = 0; pr < 2; ++pr)
        for (int nn = 0; nn < 4; ++nn)
          g.d[inp * 8 + pr * 4 + nn] = {
              ENC + (long)pr * (4 * M1), Pt + (long)inp * M1 + nn * sP,
              (long)inp * (8 * M1) + (long)nn * sNE + pr * 256, nullptr, 0};
    gemm_z<0, 1, 1><<<dim3(2, 32, 16), T, 0, stream>>>(g, NE, 1024, 1024,
                                                       1024, 512, 0, 1.f);
  }
  // --- lin1 both branches (z=2) -> MID ---
  {
    GDescs g{};
    g.d[0] = {NE, WT + 0 * S, 0, mlp_b1, 0};
    g.d[1] = {NE + 8 * M1, WT + 2 * S, 8 * M1, nlp_b1, 0};
    gemm_z<1, 1, 1><<<dim3(4, 128, 2), T, 0, stream>>>(g, MID, 512, 512, 512,
                                                       512, 0, 1.f);
  }
  // --- lin2^T both branches (z=2) -> H1T/H2T (over NE, dead) ---
  {
    GDescs g{};
    g.d[0] = {MID, WT + 1 * S, 0, mlp_b2, 0};
    g.d[1] = {MID + 8 * M1, WT + 3 * S, 8 * M1, nlp_b2, 0};
    gemm_z<0, 3, 1><<<dim3(4, 128, 2), T, 0, stream>>>(g, H1T, 512, 512, 512,
                                                       16384, 0, 1.f);
  }
  bn_stats_t<<<dim3(512, 1, 2), T, 0, stream>>>(H1T, ST);
  bn_apply_t<<<dim3(8192, 1, 2), T, 0, stream>>>(H1T, ST, mlp_g, mlp_be,
                                                 nlp_g, nlp_be);

  // --- edge decode: z = 8 descs x split-K 2, fp32 partials in MID region ---
  {
    GDescs g{};
    for (int d = 0; d < 8; ++d)
      g.d[d] = {E1T, H1T + (long)(d >> 2) * (8 * M1) + (d & 3) * 4096,
                (long)d * 524288, nullptr, 0};
    gemm_z<0, 0, 2><<<dim3(4, 8, 16), T, 0, stream>>>(g, P0f, 2048, 4096,
                                                      16384, 512, 4194304, 1.f);
  }
  addcvt<<<4096, T, 0, stream>>>(P0f, P0f + 4194304, E1, 1.f / 1024.f);

  // --- projections: Q1,K1,Q2,K2,V1,V2 in ONE dispatch (z=6, per-desc mode) ---
  {
    GDescs g{};
    g.d[0] = {E2, WT + 4 * S, 0, (const float*)d_in[17], 1};
    g.d[1] = {E1, WT + 5 * S, 2 * M1, (const float*)d_in[19], 1};
    g.d[2] = {E1, WT + 6 * S, 4 * M1, (const float*)d_in[25], 1};
    g.d[3] = {E2, WT + 7 * S, 6 * M1, (const float*)d_in[27], 1};
    g.d[4] = {E1, WT + 8 * S, 8 * M1, (const float*)d_in[21], 2};
    g.d[5] = {E2, WT + 9 * S, 10 * M1, (const float*)d_in[29], 2};
    gemm_z<0, 4, 1><<<dim3(4, 32, 6), T, 0, stream>>>(g, QKV, 512, 512, 512,
                                                      512, 0, 1.f);
  }

  // --- both attentions ---
  attn_mfma<<<dim3(16, 8, 8), T, 0, stream>>>(QKV, QKV + 2 * M1, VT, AO);

  // --- fc for both attentions -> A1P/A2P ---
  {
    GDescs g{};
    g.d[0] = {AO, WT + 10 * S, 0, (const float*)d_in[23], 0};
    g.d[1] = {AO + 2 * M1, WT + 11 * S, 2 * M1, (const float*)d_in[31], 0};
    gemm_z<0, 1, 1><<<dim3(4, 32, 2), T, 0, stream>>>(g, A1P, 512, 512, 512,
                                                      512, 0, 1.f);
  }

  // --- logits: all 4 quadrants x 4 n in one dispatch (z=16) ---
  {
    GDescs g{};
    for (int q = 0; q < 4; ++q)
      for (int n = 0; n < 4; ++n) {
        const unsigned short* A = (q < 2 ? A1P : A2P) + n * sE;
        const unsigned short* B = ((q == 0 || q == 2) ? A2P : A1P) + n * sE;
        const long coff =
            (long)n * sD + (q & 1) * 1024 + (long)(q >> 1) * 2097152;
        g.d[q * 4 + n] = {A, B, coff, nullptr, 0};
      }
    gemm_z<0, 0, 1><<<dim3(8, 8, 16), T, 0, stream>>>(g, out, 512, 512, 512,
                                                      2048, 0, 1.f);
  }

  // --- softmax + column normalization (2 passes, no middle write) ---
  hipMemsetAsync(CS, 0, 8192 * sizeof(float), stream);
  softmax_cs<<<1024, T, 0, stream>>>(out, RS, CS);
  final_scale<<<16384, T, 0, stream>>>(out, RS, CS);
}

// Round 9
// 379.544 us; speedup vs baseline: 6.5239x; 1.0291x over previous
//
#include <hip/hip_runtime.h>
#include <hip/hip_bf16.h>

#define LEAKY(v) ((v) >= 0.f ? (v) : 0.01f * (v))

typedef __attribute__((ext_vector_type(8))) short short8b;
typedef __attribute__((ext_vector_type(4))) float f32x4;
typedef __attribute__((ext_vector_type(4))) unsigned short us4;

__device__ __forceinline__ unsigned short f2b(float f) {
  unsigned int u = __builtin_bit_cast(unsigned int, f);
  return (unsigned short)((u + 0x7FFFu + ((u >> 16) & 1u)) >> 16);
}
__device__ __forceinline__ float b2f(unsigned short s) {
  return __builtin_bit_cast(float, (unsigned int)s << 16);
}

__device__ __forceinline__ void gload16(const unsigned short* g, unsigned short* l) {
  __builtin_amdgcn_global_load_lds(
      (const __attribute__((address_space(1))) unsigned int*)(g),
      (__attribute__((address_space(3))) unsigned int*)(l), 16, 0, 0);
}

// Stage a 64x64 bf16 tile (rows of 128B) global->LDS, XOR-swizzled source.
__device__ __forceinline__ void stage64(const unsigned short* g, int ldg,
                                        unsigned short* lds, int lane, int w) {
  const int r8 = lane >> 3;
  const int ce = ((lane & 7) ^ r8) << 3;
  const int r0 = w * 8 + r8;
  gload16(g + (long)r0 * ldg + ce, lds + w * 512);
  gload16(g + (long)(r0 + 32) * ldg + ce, lds + 2048 + w * 512);
}

// Swizzled 16B read: row, c4 = 16B-column index 0..7
__device__ __forceinline__ short8b ldsw(const unsigned short* base, int row, int c4) {
  return *(const short8b*)&base[row * 64 + (((c4 ^ (row & 7)) << 3))];
}

// ---------------------------------------------------------------------------
// prep stage A: depth-4 channel partial sums, fully coalesced read + write.
// ---------------------------------------------------------------------------
__global__ __launch_bounds__(256) void prep_partial(const float* __restrict__ X1,
                                                    const float* __restrict__ X2,
                                                    float* __restrict__ S) {
  const int t = blockIdx.x;   // 0..63
  const int y = blockIdx.y;   // 0..15
  const int z = blockIdx.z;   // 0..7
  const float* X = (z >> 2) ? X2 : X1;
  const int n = z & 3;
  const int tid = threadIdx.x;
  const long base = (((long)n * 64 + y * 4) * 64 + t) * 1024 + tid * 4;
  const float4 a = *(const float4*)&X[base];
  const float4 b = *(const float4*)&X[base + 65536];
  const float4 c = *(const float4*)&X[base + 2 * 65536];
  const float4 d = *(const float4*)&X[base + 3 * 65536];
  float4 o;
  o.x = (a.x + b.x) + (c.x + d.x);
  o.y = (a.y + b.y) + (c.y + d.y);
  o.z = (a.z + b.z) + (c.z + d.z);
  o.w = (a.w + b.w) + (c.w + d.w);
  *(float4*)&S[(((long)z * 16 + y) * 64 + t) * 1024 + tid * 4] = o;
}

// ---------------------------------------------------------------------------
// prep stage B: combine 4 sub-window partials, write pooled^T bf16.
// ---------------------------------------------------------------------------
__global__ __launch_bounds__(256) void prep_finish(const float* __restrict__ S,
                                                   unsigned short* __restrict__ Pt) {
  const int t = blockIdx.x;   // 0..63
  const int cbi = blockIdx.y; // 0..3
  const int z = blockIdx.z;   // inp*4+n
  const int n = z & 3, inp = z >> 2;
  const int tid = threadIdx.x;
  __shared__ unsigned short sacc[64][20];
  const long sb = (((long)z * 16 + cbi * 4) * 64 + t) * 1024 + tid * 4;
  const float4 a = *(const float4*)&S[sb];
  const float4 b = *(const float4*)&S[sb + 65536];
  const float4 c = *(const float4*)&S[sb + 2 * 65536];
  const float4 d = *(const float4*)&S[sb + 3 * 65536];
  float acc[4];
  acc[0] = (a.x + b.x) + (c.x + d.x);
  acc[1] = (a.y + b.y) + (c.y + d.y);
  acc[2] = (a.z + b.z) + (c.z + d.z);
  acc[3] = (a.w + b.w) + (c.w + d.w);
  const int q = tid & 15, vb = tid >> 4;
#pragma unroll
  for (int j = 0; j < 4; ++j)
    sacc[q * 4 + j][vb] = f2b(acc[j] * (1.f / 16.f));
  __syncthreads();
  const int vvv = tid >> 2, iq = tid & 3;
  const us4 o = *(const us4*)&sacc[vvv][iq * 4];
  *(us4*)&Pt[(long)inp * (1L << 20) + (long)n * 262144 +
             (long)(vvv * 4 + cbi) * 1024 + t * 16 + iq * 4] = o;
}

// ---------------------------------------------------------------------------
// fp32 (R x C) -> bf16 (C x R) transpose
// ---------------------------------------------------------------------------
__global__ __launch_bounds__(256) void transpose_f2b(
    const float* __restrict__ in, unsigned short* __restrict__ out, int R, int C) {
  __shared__ float t[64][65];
  const int c0 = blockIdx.x * 64, r0 = blockIdx.y * 64;
  const int tid = threadIdx.x;
#pragma unroll
  for (int it = 0; it < 4; ++it) {
    int idx = tid + it * 256;
    int r = idx >> 4, c4 = (idx & 15) * 4;
    float4 v = *(const float4*)&in[(long)(r0 + r) * C + c0 + c4];
    t[c4 + 0][r] = v.x; t[c4 + 1][r] = v.y;
    t[c4 + 2][r] = v.z; t[c4 + 3][r] = v.w;
  }
  __syncthreads();
#pragma unroll
  for (int it = 0; it < 4; ++it) {
    int idx = tid + it * 256;
    int c = idx >> 4, r4 = (idx & 15) * 4;
    us4 o;
    o[0] = f2b(t[c][r4 + 0]); o[1] = f2b(t[c][r4 + 1]);
    o[2] = f2b(t[c][r4 + 2]); o[3] = f2b(t[c][r4 + 3]);
    *(us4*)&out[(long)(c0 + c) * R + r0 + r4] = o;
  }
}

// fused 12x 512x512 weight transpose+convert, per-slot scale
struct WPtrs { const float* p[12]; float sc[12]; };
__global__ __launch_bounds__(256) void wtrans(WPtrs wp, unsigned short* __restrict__ out) {
  const float* in = wp.p[blockIdx.z];
  const float s = wp.sc[blockIdx.z];
  unsigned short* ob = out + (long)blockIdx.z * 262144;
  __shared__ float t[64][65];
  const int c0 = blockIdx.x * 64, r0 = blockIdx.y * 64;
  const int tid = threadIdx.x;
#pragma unroll
  for (int it = 0; it < 4; ++it) {
    int idx = tid + it * 256;
    int r = idx >> 4, c4 = (idx & 15) * 4;
    float4 v = *(const float4*)&in[(long)(r0 + r) * 512 + c0 + c4];
    t[c4 + 0][r] = v.x; t[c4 + 1][r] = v.y;
    t[c4 + 2][r] = v.z; t[c4 + 3][r] = v.w;
  }
  __syncthreads();
#pragma unroll
  for (int it = 0; it < 4; ++it) {
    int idx = tid + it * 256;
    int c = idx >> 4, r4 = (idx & 15) * 4;
    us4 o;
    o[0] = f2b(t[c][r4 + 0] * s); o[1] = f2b(t[c][r4 + 1] * s);
    o[2] = f2b(t[c][r4 + 2] * s); o[3] = f2b(t[c][r4 + 3] * s);
    *(us4*)&ob[(long)(c0 + c) * 512 + r0 + r4] = o;
  }
}

// fp32 -> bf16 convert, two inputs (z selects), each 1M quads
__global__ __launch_bounds__(256) void convert2_f2b(const float* __restrict__ i1,
                                                    const float* __restrict__ i2,
                                                    unsigned short* __restrict__ out) {
  const float* in = blockIdx.z ? i2 : i1;
  unsigned short* o = out + (long)blockIdx.z * (4L << 20);
  long i = (long)blockIdx.x * 256 + threadIdx.x;
  float4 v = ((const float4*)in)[i];
  us4 q;
  q[0] = f2b(v.x); q[1] = f2b(v.y); q[2] = f2b(v.z); q[3] = f2b(v.w);
  ((us4*)o)[i] = q;
}

// add two fp32 partials, scale, convert to bf16
__global__ __launch_bounds__(256) void addcvt(const float* __restrict__ P0,
                                              const float* __restrict__ P1,
                                              unsigned short* __restrict__ out,
                                              float alpha) {
  const long i = ((long)blockIdx.x * 256 + threadIdx.x) * 4;
  const float4 a = *(const float4*)&P0[i];
  const float4 b = *(const float4*)&P1[i];
  us4 o;
  o[0] = f2b((a.x + b.x) * alpha);
  o[1] = f2b((a.y + b.y) * alpha);
  o[2] = f2b((a.z + b.z) * alpha);
  o[3] = f2b((a.w + b.w) * alpha);
  *(us4*)&out[i] = o;
}

// ---------------------------------------------------------------------------
// bf16 MFMA GEMM, 128x128 tile, BK=64, 4 waves; XOR-swizzled LDS.
// Per-z descriptor: A, B, C offset, bias (scaled by bscale), mode.
// CMODE: 0 fp32; 1 bf16; 2 V^T layout; 3 C^T; 4 per-desc (mode==2 -> V^T).
// ---------------------------------------------------------------------------
struct GDesc { const unsigned short* A; const unsigned short* B; long coff;
               const float* bias; int mode; float bscale; };
struct GDescs { GDesc d[16]; };

template <int ACT, int CMODE, int KSPLIT>
__global__ __launch_bounds__(256) void gemm_z(
    GDescs ga, void* __restrict__ Cv, int K, int lda, int ldb, int ldc,
    long sC2, float alpha) {
  const int bz = blockIdx.z;
  const int s = (KSPLIT > 1) ? (bz % KSPLIT) : 0;
  const int zb = (KSPLIT > 1) ? (bz / KSPLIT) : bz;
  const GDesc g = ga.d[zb];
  const unsigned short* Ab = g.A + (long)s * K;
  const unsigned short* Bb = g.B + (long)s * K;
  const int m0 = blockIdx.y * 128, n0 = blockIdx.x * 128;
  const int tid = threadIdx.x;
  const int lane = tid & 63, w = tid >> 6;
  const int wr = (w >> 1) * 64, wc = (w & 1) * 64;
  __shared__ unsigned short As[128 * 64];
  __shared__ unsigned short Bs[128 * 64];
  f32x4 acc[4][4];
#pragma unroll
  for (int i = 0; i < 4; ++i)
#pragma unroll
    for (int j = 0; j < 4; ++j) acc[i][j] = (f32x4){0.f, 0.f, 0.f, 0.f};
  const int srow = tid >> 3;
  const int scol = (((tid & 7) ^ ((tid >> 3) & 7)) << 3);
  const int rl = lane & 15, lg = lane >> 4, rx = rl & 7;
  for (int k0 = 0; k0 < K; k0 += 64) {
    __syncthreads();
#pragma unroll
    for (int it = 0; it < 4; ++it) {
      gload16(Ab + (long)(m0 + it * 32 + srow) * lda + k0 + scol,
              As + w * 512 + it * 2048);
      gload16(Bb + (long)(n0 + it * 32 + srow) * ldb + k0 + scol,
              Bs + w * 512 + it * 2048);
    }
    __syncthreads();
#pragma unroll
    for (int kk = 0; kk < 2; ++kk) {
      short8b af[4], bfr[4];
#pragma unroll
      for (int m = 0; m < 4; ++m)
        af[m] = *(const short8b*)&As[(wr + m * 16 + rl) * 64 +
                                     ((((kk * 4 + lg) ^ rx)) << 3)];
#pragma unroll
      for (int nn = 0; nn < 4; ++nn)
        bfr[nn] = *(const short8b*)&Bs[(wc + nn * 16 + rl) * 64 +
                                       ((((kk * 4 + lg) ^ rx)) << 3)];
#pragma unroll
      for (int m = 0; m < 4; ++m)
#pragma unroll
        for (int nn = 0; nn < 4; ++nn)
          acc[m][nn] = __builtin_amdgcn_mfma_f32_16x16x32_bf16(
              af[m], bfr[nn], acc[m][nn], 0, 0, 0);
    }
  }
  const int rrow = lg * 4;
  float bv[4];
#pragma unroll
  for (int nn = 0; nn < 4; ++nn)
    bv[nn] = g.bias ? g.bias[n0 + wc + nn * 16 + rl] * g.bscale : 0.f;
  const bool vt_layout = (CMODE == 2) || (CMODE == 4 && g.mode == 2);
  if (CMODE == 2 || CMODE == 4) {
    if (vt_layout) {
#pragma unroll
      for (int m = 0; m < 4; ++m)
#pragma unroll
        for (int nn = 0; nn < 4; ++nn) {
          const int row = m0 + wr + m * 16 + rrow;
          const int col = n0 + wc + nn * 16 + rl;
          us4 o;
#pragma unroll
          for (int r = 0; r < 4; ++r) {
            float v = alpha * acc[m][nn][r] + bv[nn];
            if (ACT == 1) v = LEAKY(v);
            o[r] = f2b(v);
          }
          const long off = g.coff + (long)(row >> 10) * 524288 +
                           (long)col * 1024 + (row & 1023);
          *(us4*)&((unsigned short*)Cv)[off] = o;
        }
    } else {
#pragma unroll
      for (int m = 0; m < 4; ++m)
#pragma unroll
        for (int nn = 0; nn < 4; ++nn)
#pragma unroll
          for (int r = 0; r < 4; ++r) {
            float v = alpha * acc[m][nn][r] + bv[nn];
            if (ACT == 1) v = LEAKY(v);
            const long off = g.coff +
                             (long)(m0 + wr + m * 16 + rrow + r) * ldc + n0 +
                             wc + nn * 16 + rl;
            ((unsigned short*)Cv)[off] = f2b(v);
          }
    }
  } else if (CMODE == 3) {
#pragma unroll
    for (int m = 0; m < 4; ++m)
#pragma unroll
      for (int nn = 0; nn < 4; ++nn) {
        const int row = m0 + wr + m * 16 + rrow;
        const int col = n0 + wc + nn * 16 + rl;
        us4 o;
#pragma unroll
        for (int r = 0; r < 4; ++r) {
          float v = alpha * acc[m][nn][r] + bv[nn];
          if (ACT == 1) v = LEAKY(v);
          o[r] = f2b(v);
        }
        *(us4*)&((unsigned short*)Cv)[g.coff + (long)col * ldc + row] = o;
      }
  } else {
#pragma unroll
    for (int m = 0; m < 4; ++m)
#pragma unroll
      for (int nn = 0; nn < 4; ++nn)
#pragma unroll
        for (int r = 0; r < 4; ++r) {
          float v = alpha * acc[m][nn][r] + bv[nn];
          if (ACT == 1) v = LEAKY(v);
          long off = g.coff + (long)s * sC2 +
                     (long)(m0 + wr + m * 16 + rrow + r) * ldc + n0 + wc +
                     nn * 16 + rl;
          if (CMODE == 1)
            ((unsigned short*)Cv)[off] = f2b(v);
          else
            ((float*)Cv)[off] = v;
        }
  }
}

// ---------------------------------------------------------------------------
// Fused BatchNorm on h^T (512 features x 16384 samples), bf16, in-place.
// One block per (feature, branch): stats in registers, then apply.
// ---------------------------------------------------------------------------
__global__ __launch_bounds__(256) void bn_fused(
    unsigned short* __restrict__ X,
    const float* __restrict__ g1, const float* __restrict__ be1,
    const float* __restrict__ g2, const float* __restrict__ be2) {
  const int f = blockIdx.x;
  const int z = blockIdx.z;
  unsigned short* p = X + (long)z * (8L << 20) + (long)f * 16384;
  const int tid = threadIdx.x;
  us4 v[16];
  float s = 0.f, q = 0.f;
#pragma unroll
  for (int k = 0; k < 16; ++k) {
    v[k] = *(const us4*)&p[(k * 256 + tid) * 4];
#pragma unroll
    for (int j = 0; j < 4; ++j) {
      const float x = b2f(v[k][j]);
      s += x; q += x * x;
    }
  }
#pragma unroll
  for (int mask = 1; mask < 64; mask <<= 1) {
    s += __shfl_xor(s, mask, 64);
    q += __shfl_xor(q, mask, 64);
  }
  __shared__ float rs[8];
  const int wv = tid >> 6;
  if ((tid & 63) == 0) { rs[wv] = s; rs[4 + wv] = q; }
  __syncthreads();
  s = rs[0] + rs[1] + rs[2] + rs[3];
  q = rs[4] + rs[5] + rs[6] + rs[7];
  const float mu = s * (1.f / 16384.f);
  const float var = q * (1.f / 16384.f) - mu * mu;
  const float gg = (z ? g2 : g1)[f];
  const float bb0 = (z ? be2 : be1)[f];
  const float rstd = rsqrtf(var + 1e-5f) * gg;
  const float bb = bb0 - mu * rstd;
#pragma unroll
  for (int k = 0; k < 16; ++k) {
    us4 o;
#pragma unroll
    for (int j = 0; j < 4; ++j) {
      const float y = b2f(v[k][j]) * rstd + bb;
      o[j] = f2b(LEAKY(y));
    }
    *(us4*)&p[(k * 256 + tid) * 4] = o;
  }
}

// ---------------------------------------------------------------------------
// bf16 MFMA flash attention, both attentions in one dispatch (z = 8).
// NO-MAX softmax: logits bounded, Q pre-scaled by 0.125*log2e at projection,
// so P = exp2(S) directly; l accumulates in f32; O = acc/l.
// ---------------------------------------------------------------------------
__global__ __launch_bounds__(256) void attn_mfma(
    const unsigned short* __restrict__ Q, const unsigned short* __restrict__ K,
    const unsigned short* __restrict__ Vt, unsigned short* __restrict__ O) {
  const int qb = blockIdx.x, h = blockIdx.y;
  const int n = blockIdx.z & 3, sel = blockIdx.z >> 2;
  Q += (long)sel * 4194304;
  K += (long)sel * 4194304;
  Vt += (long)sel * 2097152;
  O += (long)sel * 2097152;
  const int tid = threadIdx.x;
  const int lane = tid & 63, w = tid >> 6;
  const int rl = lane & 15, lg = lane >> 4;
  __shared__ unsigned short Qs[4096];
  __shared__ unsigned short Ks[4096];
  __shared__ unsigned short Vs[4096];
  __shared__ unsigned short Ps[4096];
  stage64(Q + ((long)n * 1024 + qb * 64) * 512 + h * 64, 512, Qs, lane, w);
  float l_r = 0.f;
  f32x4 po[4];
#pragma unroll
  for (int i = 0; i < 4; ++i) po[i] = (f32x4){0.f, 0.f, 0.f, 0.f};
  const unsigned short* Kg0 = K + ((long)n * 1024) * 512 + h * 64;
  const unsigned short* Vg0 = Vt + (long)n * 524288 + (long)(h * 64) * 1024;
  for (int kt = 0; kt < 16; ++kt) {
    __syncthreads();
    stage64(Kg0 + (long)(kt * 64) * 512, 512, Ks, lane, w);
    stage64(Vg0 + kt * 64, 1024, Vs, lane, w);
    __syncthreads();
    f32x4 sa[4];
#pragma unroll
    for (int i = 0; i < 4; ++i) sa[i] = (f32x4){0.f, 0.f, 0.f, 0.f};
#pragma unroll
    for (int kk = 0; kk < 2; ++kk) {
      const short8b qf = ldsw(Qs, w * 16 + rl, 4 * kk + lg);
#pragma unroll
      for (int mt = 0; mt < 4; ++mt) {
        const short8b kf = ldsw(Ks, mt * 16 + rl, 4 * kk + lg);
        sa[mt] = __builtin_amdgcn_mfma_f32_16x16x32_bf16(kf, qf, sa[mt], 0, 0, 0);
      }
    }
    float ps = 0.f;
    const int q = w * 16 + rl;
#pragma unroll
    for (int mt = 0; mt < 4; ++mt) {
      us4 o;
#pragma unroll
      for (int r = 0; r < 4; ++r) {
        const float p = exp2f(sa[mt][r]);
        ps += p;
        o[r] = f2b(p);
      }
      const int c16 = (4 * mt + lg) >> 1;
      *(us4*)&Ps[q * 64 + ((c16 ^ (q & 7)) << 3) + ((lg & 1) << 2)] = o;
    }
    ps += __shfl_xor(ps, 16, 64);
    ps += __shfl_xor(ps, 32, 64);
    l_r += ps;
#pragma unroll
    for (int kk = 0; kk < 2; ++kk) {
      const short8b pf = ldsw(Ps, w * 16 + rl, 4 * kk + lg);
#pragma unroll
      for (int nt = 0; nt < 4; ++nt) {
        const short8b vf = ldsw(Vs, nt * 16 + rl, 4 * kk + lg);
        po[nt] = __builtin_amdgcn_mfma_f32_16x16x32_bf16(pf, vf, po[nt], 0, 0, 0);
      }
    }
  }
  float invr[4];
#pragma unroll
  for (int r = 0; r < 4; ++r) invr[r] = 1.f / __shfl(l_r, lg * 4 + r, 64);
  const long ob = ((long)n * 1024 + qb * 64 + w * 16) * 512 + h * 64;
#pragma unroll
  for (int nt = 0; nt < 4; ++nt)
#pragma unroll
    for (int r = 0; r < 4; ++r)
      O[ob + (long)(lg * 4 + r) * 512 + nt * 16 + rl] = f2b(po[nt][r] * invr[r]);
}

// ---------------------------------------------------------------------------
// Softmax pass 1: per-row max & 1/sum, plus column sums of softmax(A).
// ---------------------------------------------------------------------------
__global__ __launch_bounds__(256) void softmax_cs(const float* __restrict__ D,
                                                  float* __restrict__ RS,
                                                  float* __restrict__ CS) {
  __shared__ float colacc[2048];
  __shared__ float red[8];
  const int tid = threadIdx.x;
  const int wv = tid >> 6, ln = tid & 63;
#pragma unroll
  for (int k = 0; k < 8; ++k) colacc[tid + k * 256] = 0.f;
  __syncthreads();
  const int r0 = blockIdx.x * 8;
  const int n = r0 >> 11;
  for (int rr = 0; rr < 8; ++rr) {
    const float* p = D + (long)(r0 + rr) * 2048;
    float v[8];
    float mx = -1e30f;
#pragma unroll
    for (int k = 0; k < 8; ++k) {
      v[k] = p[tid + k * 256];
      mx = fmaxf(mx, v[k]);
    }
#pragma unroll
    for (int mask = 1; mask < 64; mask <<= 1) mx = fmaxf(mx, __shfl_xor(mx, mask, 64));
    if (ln == 0) red[wv] = mx;
    __syncthreads();
    mx = fmaxf(fmaxf(red[0], red[1]), fmaxf(red[2], red[3]));
    float sum = 0.f;
#pragma unroll
    for (int k = 0; k < 8; ++k) {
      v[k] = __expf(v[k] - mx);
      sum += v[k];
    }
#pragma unroll
    for (int mask = 1; mask < 64; mask <<= 1) sum += __shfl_xor(sum, mask, 64);
    if (ln == 0) red[4 + wv] = sum;
    __syncthreads();
    sum = red[4] + red[5] + red[6] + red[7];
    const float inv = 1.f / sum;
    if (tid == 0) {
      RS[(r0 + rr) * 2] = mx;
      RS[(r0 + rr) * 2 + 1] = inv;
    }
#pragma unroll
    for (int k = 0; k < 8; ++k) colacc[tid + k * 256] += v[k] * inv;
    __syncthreads();
  }
#pragma unroll
  for (int k = 0; k < 8; ++k)
    atomicAdd(&CS[n * 2048 + tid + k * 256], colacc[tid + k * 256]);
}

// Pass 2: recompute softmax from logits + row stats, apply column normalize.
__global__ __launch_bounds__(256) void final_scale(float* __restrict__ D,
                                                   const float* __restrict__ RS,
                                                   const float* __restrict__ CS) {
  const long i = ((long)blockIdx.x * 256 + threadIdx.x) * 4;
  const long row = i >> 11;
  const int n = (int)(row >> 11);
  const int j = (int)(i & 2047);
  const float mx = RS[row * 2];
  const float inv = RS[row * 2 + 1];
  float4 v = *(float4*)&D[i];
  const float* c = &CS[n * 2048 + j];
  v.x = __expf(v.x - mx) * inv * (c[0] > 0.f ? 1.f / c[0] : 0.f);
  v.y = __expf(v.y - mx) * inv * (c[1] > 0.f ? 1.f / c[1] : 0.f);
  v.z = __expf(v.z - mx) * inv * (c[2] > 0.f ? 1.f / c[2] : 0.f);
  v.w = __expf(v.w - mx) * inv * (c[3] > 0.f ? 1.f / c[3] : 0.f);
  *(float4*)&D[i] = v;
}

// ---------------------------------------------------------------------------
extern "C" void kernel_launch(void* const* d_in, const int* in_sizes, int n_in,
                              void* d_out, int out_size, void* d_ws,
                              size_t ws_size, hipStream_t stream) {
  const float* x1 = (const float*)d_in[0];
  const float* x2 = (const float*)d_in[1];
  const float* enc1 = (const float*)d_in[2];
  const float* enc2 = (const float*)d_in[3];
  const float* mlp_b1 = (const float*)d_in[5];
  const float* mlp_b2 = (const float*)d_in[7];
  const float* mlp_g = (const float*)d_in[8];
  const float* mlp_be = (const float*)d_in[9];
  const float* nlp_b1 = (const float*)d_in[11];
  const float* nlp_b2 = (const float*)d_in[13];
  const float* nlp_g = (const float*)d_in[14];
  const float* nlp_be = (const float*)d_in[15];
  float* out = (float*)d_out;

  unsigned short* W = (unsigned short*)d_ws;
  const long M1 = 1L << 20;
  const long S = 262144;
  const float K2 = 0.18033688f;  // 0.125 * log2(e)
  // Rolling layout (us units), lifetimes disjoint-in-time (see R6 audit).
  unsigned short* Pt = W;
  unsigned short* ENC = W + 4 * M1;
  unsigned short* E1T = W + 12 * M1;
  unsigned short* WT = W + 16 * M1;
  unsigned short* NE = W + 20 * M1;
  unsigned short* H1T = W + 20 * M1;
  unsigned short* MID = W + 36 * M1;
  float* Sprep = (float*)(W + 36 * M1);
  float* P0f = (float*)(W + 36 * M1);
  unsigned short* E1 = W + 4 * M1;
  unsigned short* E2 = W + 6 * M1;
  unsigned short* QKV = W + 36 * M1;
  unsigned short* VT = W + 44 * M1;
  unsigned short* AO = W + 48 * M1;
  unsigned short* A1P = W + 8 * M1;
  unsigned short* A2P = W + 10 * M1;
  float* ST = (float*)(W + 56 * M1);
  float* CS = ST + 2048;
  float* RS = CS + 8192;

  const dim3 T(256);
  const long sP = 262144;
  const long sNE = 2097152;
  const long sE = 524288;
  const long sD = 4194304;

  // --- prep (2-stage pooled^T) + operand conversion ---
  prep_partial<<<dim3(64, 16, 8), T, 0, stream>>>(x1, x2, Sprep);
  prep_finish<<<dim3(64, 4, 8), T, 0, stream>>>(Sprep, Pt);
  convert2_f2b<<<dim3(4096, 1, 2), T, 0, stream>>>(enc1, enc2, ENC);
  transpose_f2b<<<dim3(16, 64), T, 0, stream>>>(enc1, E1T, 4096, 1024);
  WPtrs wp;
  wp.p[0] = (const float*)d_in[4];   wp.sc[0] = 1.f;   // mlp_w1
  wp.p[1] = (const float*)d_in[6];   wp.sc[1] = 1.f;   // mlp_w2
  wp.p[2] = (const float*)d_in[10];  wp.sc[2] = 1.f;   // nlp_w1
  wp.p[3] = (const float*)d_in[12];  wp.sc[3] = 1.f;   // nlp_w2
  wp.p[4] = (const float*)d_in[16];  wp.sc[4] = K2;    // a1_wq (log2-scaled)
  wp.p[5] = (const float*)d_in[18];  wp.sc[5] = 1.f;   // a1_wk
  wp.p[6] = (const float*)d_in[24];  wp.sc[6] = K2;    // a2_wq (log2-scaled)
  wp.p[7] = (const float*)d_in[26];  wp.sc[7] = 1.f;   // a2_wk
  wp.p[8] = (const float*)d_in[20];  wp.sc[8] = 1.f;   // a1_wv
  wp.p[9] = (const float*)d_in[28];  wp.sc[9] = 1.f;   // a2_wv
  wp.p[10] = (const float*)d_in[22]; wp.sc[10] = 1.f;  // a1_fc
  wp.p[11] = (const float*)d_in[30]; wp.sc[11] = 1.f;  // a2_fc
  wtrans<<<dim3(8, 8, 12), T, 0, stream>>>(wp, WT);

  // --- node_enc for BOTH branches: z=16 (inp x pr x n) -> NE ---
  {
    GDescs g{};
    for (int inp = 0; inp < 2; ++inp)
      for (int pr = 0; pr < 2; ++pr)
        for (int nn = 0; nn < 4; ++nn)
          g.d[inp * 8 + pr * 4 + nn] = {
              ENC + (long)pr * (4 * M1), Pt + (long)inp * M1 + nn * sP,
              (long)inp * (8 * M1) + (long)nn * sNE + pr * 256, nullptr, 0, 1.f};
    gemm_z<0, 1, 1><<<dim3(2, 32, 16), T, 0, stream>>>(g, NE, 1024, 1024,
                                                       1024, 512, 0, 1.f);
  }
  // --- lin1 both branches (z=2) -> MID ---
  {
    GDescs g{};
    g.d[0] = {NE, WT + 0 * S, 0, mlp_b1, 0, 1.f};
    g.d[1] = {NE + 8 * M1, WT + 2 * S, 8 * M1, nlp_b1, 0, 1.f};
    gemm_z<1, 1, 1><<<dim3(4, 128, 2), T, 0, stream>>>(g, MID, 512, 512, 512,
                                                       512, 0, 1.f);
  }
  // --- lin2^T both branches (z=2) -> H1T/H2T (over NE, dead) ---
  {
    GDescs g{};
    g.d[0] = {MID, WT + 1 * S, 0, mlp_b2, 0, 1.f};
    g.d[1] = {MID + 8 * M1, WT + 3 * S, 8 * M1, nlp_b2, 0, 1.f};
    gemm_z<0, 3, 1><<<dim3(4, 128, 2), T, 0, stream>>>(g, H1T, 512, 512, 512,
                                                       16384, 0, 1.f);
  }
  bn_fused<<<dim3(512, 1, 2), T, 0, stream>>>(H1T, mlp_g, mlp_be, nlp_g, nlp_be);

  // --- edge decode: z = 8 descs x split-K 2, fp32 partials in MID region ---
  {
    GDescs g{};
    for (int d = 0; d < 8; ++d)
      g.d[d] = {E1T, H1T + (long)(d >> 2) * (8 * M1) + (d & 3) * 4096,
                (long)d * 524288, nullptr, 0, 1.f};
    gemm_z<0, 0, 2><<<dim3(4, 8, 16), T, 0, stream>>>(g, P0f, 2048, 4096,
                                                      16384, 512, 4194304, 1.f);
  }
  addcvt<<<4096, T, 0, stream>>>(P0f, P0f + 4194304, E1, 1.f / 1024.f);

  // --- projections: Q1,K1,Q2,K2,V1,V2 in ONE dispatch (z=6, per-desc mode).
  //     Q weights/biases pre-scaled to log2 domain (bscale=K2). ---
  {
    GDescs g{};
    g.d[0] = {E2, WT + 4 * S, 0, (const float*)d_in[17], 1, K2};
    g.d[1] = {E1, WT + 5 * S, 2 * M1, (const float*)d_in[19], 1, 1.f};
    g.d[2] = {E1, WT + 6 * S, 4 * M1, (const float*)d_in[25], 1, K2};
    g.d[3] = {E2, WT + 7 * S, 6 * M1, (const float*)d_in[27], 1, 1.f};
    g.d[4] = {E1, WT + 8 * S, 8 * M1, (const float*)d_in[21], 2, 1.f};
    g.d[5] = {E2, WT + 9 * S, 10 * M1, (const float*)d_in[29], 2, 1.f};
    gemm_z<0, 4, 1><<<dim3(4, 32, 6), T, 0, stream>>>(g, QKV, 512, 512, 512,
                                                      512, 0, 1.f);
  }

  // --- both attentions ---
  attn_mfma<<<dim3(16, 8, 8), T, 0, stream>>>(QKV, QKV + 2 * M1, VT, AO);

  // --- fc for both attentions -> A1P/A2P ---
  {
    GDescs g{};
    g.d[0] = {AO, WT + 10 * S, 0, (const float*)d_in[23], 0, 1.f};
    g.d[1] = {AO + 2 * M1, WT + 11 * S, 2 * M1, (const float*)d_in[31], 0, 1.f};
    gemm_z<0, 1, 1><<<dim3(4, 32, 2), T, 0, stream>>>(g, A1P, 512, 512, 512,
                                                      512, 0, 1.f);
  }

  // --- logits: all 4 quadrants x 4 n in one dispatch (z=16) ---
  {
    GDescs g{};
    for (int q = 0; q < 4; ++q)
      for (int n = 0; n < 4; ++n) {
        const unsigned short* A = (q < 2 ? A1P : A2P) + n * sE;
        const unsigned short* B = ((q == 0 || q == 2) ? A2P : A1P) + n * sE;
        const long coff =
            (long)n * sD + (q & 1) * 1024 + (long)(q >> 1) * 2097152;
        g.d[q * 4 + n] = {A, B, coff, nullptr, 0, 1.f};
      }
    gemm_z<0, 0, 1><<<dim3(8, 8, 16), T, 0, stream>>>(g, out, 512, 512, 512,
                                                      2048, 0, 1.f);
  }

  // --- softmax + column normalization (2 passes, no middle write) ---
  hipMemsetAsync(CS, 0, 8192 * sizeof(float), stream);
  softmax_cs<<<1024, T, 0, stream>>>(out, RS, CS);
  final_scale<<<16384, T, 0, stream>>>(out, RS, CS);
}

// Round 10
// 378.469 us; speedup vs baseline: 6.5424x; 1.0028x over previous
//
#include <hip/hip_runtime.h>
#include <hip/hip_bf16.h>

#define LEAKY(v) ((v) >= 0.f ? (v) : 0.01f * (v))

typedef __attribute__((ext_vector_type(8))) short short8b;
typedef __attribute__((ext_vector_type(4))) float f32x4;
typedef __attribute__((ext_vector_type(4))) unsigned short us4;

__device__ __forceinline__ unsigned short f2b(float f) {
  unsigned int u = __builtin_bit_cast(unsigned int, f);
  return (unsigned short)((u + 0x7FFFu + ((u >> 16) & 1u)) >> 16);
}
__device__ __forceinline__ float b2f(unsigned short s) {
  return __builtin_bit_cast(float, (unsigned int)s << 16);
}

__device__ __forceinline__ void gload16(const unsigned short* g, unsigned short* l) {
  __builtin_amdgcn_global_load_lds(
      (const __attribute__((address_space(1))) unsigned int*)(g),
      (__attribute__((address_space(3))) unsigned int*)(l), 16, 0, 0);
}

// Stage a 64x64 bf16 tile (rows of 128B) global->LDS, XOR-swizzled source.
__device__ __forceinline__ void stage64(const unsigned short* g, int ldg,
                                        unsigned short* lds, int lane, int w) {
  const int r8 = lane >> 3;
  const int ce = ((lane & 7) ^ r8) << 3;
  const int r0 = w * 8 + r8;
  gload16(g + (long)r0 * ldg + ce, lds + w * 512);
  gload16(g + (long)(r0 + 32) * ldg + ce, lds + 2048 + w * 512);
}

// Swizzled 16B read: row, c4 = 16B-column index 0..7
__device__ __forceinline__ short8b ldsw(const unsigned short* base, int row, int c4) {
  return *(const short8b*)&base[row * 64 + (((c4 ^ (row & 7)) << 3))];
}

// ---------------------------------------------------------------------------
// Fused prologue: independent prep/convert/transpose work in ONE dispatch.
//  blocks [0,8192)      : prep stage A (depth-4 channel partial sums)
//  blocks [8192,16384)  : enc1/enc2 fp32->bf16 convert
//  blocks [16384,17408) : enc1 fp32 (4096x1024) -> bf16 transpose (1024x4096)
//  blocks [17408,18176) : 12x 512x512 weight transpose+convert (w/ scale)
// ---------------------------------------------------------------------------
struct WPtrs { const float* p[12]; float sc[12]; };

__global__ __launch_bounds__(256) void prologue_misc(
    const float* __restrict__ X1, const float* __restrict__ X2,
    float* __restrict__ S, const float* __restrict__ enc1,
    const float* __restrict__ enc2, unsigned short* __restrict__ ENC,
    unsigned short* __restrict__ E1T, WPtrs wp,
    unsigned short* __restrict__ WT) {
  __shared__ float t[64][65];
  const int b = blockIdx.x;
  const int tid = threadIdx.x;
  if (b < 8192) {
    // prep stage A
    const int tt = b & 63, y = (b >> 6) & 15, z = b >> 10;
    const float* X = (z >> 2) ? X2 : X1;
    const int n = z & 3;
    const long base = (((long)n * 64 + y * 4) * 64 + tt) * 1024 + tid * 4;
    const float4 a = *(const float4*)&X[base];
    const float4 bb = *(const float4*)&X[base + 65536];
    const float4 c = *(const float4*)&X[base + 2 * 65536];
    const float4 d = *(const float4*)&X[base + 3 * 65536];
    float4 o;
    o.x = (a.x + bb.x) + (c.x + d.x);
    o.y = (a.y + bb.y) + (c.y + d.y);
    o.z = (a.z + bb.z) + (c.z + d.z);
    o.w = (a.w + bb.w) + (c.w + d.w);
    *(float4*)&S[(((long)z * 16 + y) * 64 + tt) * 1024 + tid * 4] = o;
  } else if (b < 16384) {
    // enc convert
    const int b2 = b - 8192;
    const int z = b2 >> 12;
    const float* in = z ? enc2 : enc1;
    unsigned short* o = ENC + (long)z * (4L << 20);
    const long i = (long)(b2 & 4095) * 256 + tid;
    const float4 v = ((const float4*)in)[i];
    us4 q;
    q[0] = f2b(v.x); q[1] = f2b(v.y); q[2] = f2b(v.z); q[3] = f2b(v.w);
    ((us4*)o)[i] = q;
  } else if (b < 17408) {
    // enc1 transpose -> E1T (out 1024 x 4096)
    const int b3 = b - 16384;
    const int c0 = (b3 & 15) * 64, r0 = (b3 >> 4) * 64;
#pragma unroll
    for (int it = 0; it < 4; ++it) {
      int idx = tid + it * 256;
      int r = idx >> 4, c4 = (idx & 15) * 4;
      float4 v = *(const float4*)&enc1[(long)(r0 + r) * 1024 + c0 + c4];
      t[c4 + 0][r] = v.x; t[c4 + 1][r] = v.y;
      t[c4 + 2][r] = v.z; t[c4 + 3][r] = v.w;
    }
    __syncthreads();
#pragma unroll
    for (int it = 0; it < 4; ++it) {
      int idx = tid + it * 256;
      int c = idx >> 4, r4 = (idx & 15) * 4;
      us4 o;
      o[0] = f2b(t[c][r4 + 0]); o[1] = f2b(t[c][r4 + 1]);
      o[2] = f2b(t[c][r4 + 2]); o[3] = f2b(t[c][r4 + 3]);
      *(us4*)&E1T[(long)(c0 + c) * 4096 + r0 + r4] = o;
    }
  } else {
    // weight transpose+convert
    const int b4 = b - 17408;
    const int x = b4 & 7, y = (b4 >> 3) & 7, z = b4 >> 6;
    const float* in = wp.p[z];
    const float s = wp.sc[z];
    unsigned short* ob = WT + (long)z * 262144;
    const int c0 = x * 64, r0 = y * 64;
#pragma unroll
    for (int it = 0; it < 4; ++it) {
      int idx = tid + it * 256;
      int r = idx >> 4, c4 = (idx & 15) * 4;
      float4 v = *(const float4*)&in[(long)(r0 + r) * 512 + c0 + c4];
      t[c4 + 0][r] = v.x; t[c4 + 1][r] = v.y;
      t[c4 + 2][r] = v.z; t[c4 + 3][r] = v.w;
    }
    __syncthreads();
#pragma unroll
    for (int it = 0; it < 4; ++it) {
      int idx = tid + it * 256;
      int c = idx >> 4, r4 = (idx & 15) * 4;
      us4 o;
      o[0] = f2b(t[c][r4 + 0] * s); o[1] = f2b(t[c][r4 + 1] * s);
      o[2] = f2b(t[c][r4 + 2] * s); o[3] = f2b(t[c][r4 + 3] * s);
      *(us4*)&ob[(long)(c0 + c) * 512 + r0 + r4] = o;
    }
  }
}

// ---------------------------------------------------------------------------
// prep stage B: combine 4 sub-window partials, write pooled^T bf16.
// ---------------------------------------------------------------------------
__global__ __launch_bounds__(256) void prep_finish(const float* __restrict__ S,
                                                   unsigned short* __restrict__ Pt) {
  const int t = blockIdx.x;   // 0..63
  const int cbi = blockIdx.y; // 0..3
  const int z = blockIdx.z;   // inp*4+n
  const int n = z & 3, inp = z >> 2;
  const int tid = threadIdx.x;
  __shared__ unsigned short sacc[64][20];
  const long sb = (((long)z * 16 + cbi * 4) * 64 + t) * 1024 + tid * 4;
  const float4 a = *(const float4*)&S[sb];
  const float4 b = *(const float4*)&S[sb + 65536];
  const float4 c = *(const float4*)&S[sb + 2 * 65536];
  const float4 d = *(const float4*)&S[sb + 3 * 65536];
  float acc[4];
  acc[0] = (a.x + b.x) + (c.x + d.x);
  acc[1] = (a.y + b.y) + (c.y + d.y);
  acc[2] = (a.z + b.z) + (c.z + d.z);
  acc[3] = (a.w + b.w) + (c.w + d.w);
  const int q = tid & 15, vb = tid >> 4;
#pragma unroll
  for (int j = 0; j < 4; ++j)
    sacc[q * 4 + j][vb] = f2b(acc[j] * (1.f / 16.f));
  __syncthreads();
  const int vvv = tid >> 2, iq = tid & 3;
  const us4 o = *(const us4*)&sacc[vvv][iq * 4];
  *(us4*)&Pt[(long)inp * (1L << 20) + (long)n * 262144 +
             (long)(vvv * 4 + cbi) * 1024 + t * 16 + iq * 4] = o;
}

// sum 4 bf16 split-K partials (stride sSp elems), convert to bf16
__global__ __launch_bounds__(256) void addcvt4(const unsigned short* __restrict__ P,
                                               unsigned short* __restrict__ out) {
  const long i = ((long)blockIdx.x * 256 + threadIdx.x) * 4;
  const us4 a = *(const us4*)&P[i];
  const us4 b = *(const us4*)&P[i + 4194304];
  const us4 c = *(const us4*)&P[i + 2 * 4194304];
  const us4 d = *(const us4*)&P[i + 3 * 4194304];
  us4 o;
#pragma unroll
  for (int j = 0; j < 4; ++j)
    o[j] = f2b((b2f(a[j]) + b2f(b[j])) + (b2f(c[j]) + b2f(d[j])));
  *(us4*)&out[i] = o;
}

// ---------------------------------------------------------------------------
// bf16 MFMA GEMM, 128x128 tile, BK=64, 4 waves; XOR-swizzled LDS.
// Per-z descriptor: A, B, C offset, bias (scaled by bscale), mode.
// CMODE: 0 fp32; 1 bf16; 2 V^T layout; 3 C^T; 4 per-desc (mode==2 -> V^T).
// KSPLIT: s = bz%KSPLIT shifts A/B cols by s*K and C by s*sC2.
// ---------------------------------------------------------------------------
struct GDesc { const unsigned short* A; const unsigned short* B; long coff;
               const float* bias; int mode; float bscale; };
struct GDescs { GDesc d[16]; };

template <int ACT, int CMODE, int KSPLIT>
__global__ __launch_bounds__(256) void gemm_z(
    GDescs ga, void* __restrict__ Cv, int K, int lda, int ldb, int ldc,
    long sC2, float alpha) {
  const int bz = blockIdx.z;
  const int s = (KSPLIT > 1) ? (bz % KSPLIT) : 0;
  const int zb = (KSPLIT > 1) ? (bz / KSPLIT) : bz;
  const GDesc g = ga.d[zb];
  const unsigned short* Ab = g.A + (long)s * K;
  const unsigned short* Bb = g.B + (long)s * K;
  const int m0 = blockIdx.y * 128, n0 = blockIdx.x * 128;
  const int tid = threadIdx.x;
  const int lane = tid & 63, w = tid >> 6;
  const int wr = (w >> 1) * 64, wc = (w & 1) * 64;
  __shared__ unsigned short As[128 * 64];
  __shared__ unsigned short Bs[128 * 64];
  f32x4 acc[4][4];
#pragma unroll
  for (int i = 0; i < 4; ++i)
#pragma unroll
    for (int j = 0; j < 4; ++j) acc[i][j] = (f32x4){0.f, 0.f, 0.f, 0.f};
  const int srow = tid >> 3;
  const int scol = (((tid & 7) ^ ((tid >> 3) & 7)) << 3);
  const int rl = lane & 15, lg = lane >> 4, rx = rl & 7;
  for (int k0 = 0; k0 < K; k0 += 64) {
    __syncthreads();
#pragma unroll
    for (int it = 0; it < 4; ++it) {
      gload16(Ab + (long)(m0 + it * 32 + srow) * lda + k0 + scol,
              As + w * 512 + it * 2048);
      gload16(Bb + (long)(n0 + it * 32 + srow) * ldb + k0 + scol,
              Bs + w * 512 + it * 2048);
    }
    __syncthreads();
#pragma unroll
    for (int kk = 0; kk < 2; ++kk) {
      short8b af[4], bfr[4];
#pragma unroll
      for (int m = 0; m < 4; ++m)
        af[m] = *(const short8b*)&As[(wr + m * 16 + rl) * 64 +
                                     ((((kk * 4 + lg) ^ rx)) << 3)];
#pragma unroll
      for (int nn = 0; nn < 4; ++nn)
        bfr[nn] = *(const short8b*)&Bs[(wc + nn * 16 + rl) * 64 +
                                       ((((kk * 4 + lg) ^ rx)) << 3)];
#pragma unroll
      for (int m = 0; m < 4; ++m)
#pragma unroll
        for (int nn = 0; nn < 4; ++nn)
          acc[m][nn] = __builtin_amdgcn_mfma_f32_16x16x32_bf16(
              af[m], bfr[nn], acc[m][nn], 0, 0, 0);
    }
  }
  const int rrow = lg * 4;
  float bv[4];
#pragma unroll
  for (int nn = 0; nn < 4; ++nn)
    bv[nn] = g.bias ? g.bias[n0 + wc + nn * 16 + rl] * g.bscale : 0.f;
  const bool vt_layout = (CMODE == 2) || (CMODE == 4 && g.mode == 2);
  if (CMODE == 2 || CMODE == 4) {
    if (vt_layout) {
#pragma unroll
      for (int m = 0; m < 4; ++m)
#pragma unroll
        for (int nn = 0; nn < 4; ++nn) {
          const int row = m0 + wr + m * 16 + rrow;
          const int col = n0 + wc + nn * 16 + rl;
          us4 o;
#pragma unroll
          for (int r = 0; r < 4; ++r) {
            float v = alpha * acc[m][nn][r] + bv[nn];
            if (ACT == 1) v = LEAKY(v);
            o[r] = f2b(v);
          }
          const long off = g.coff + (long)(row >> 10) * 524288 +
                           (long)col * 1024 + (row & 1023);
          *(us4*)&((unsigned short*)Cv)[off] = o;
        }
    } else {
#pragma unroll
      for (int m = 0; m < 4; ++m)
#pragma unroll
        for (int nn = 0; nn < 4; ++nn)
#pragma unroll
          for (int r = 0; r < 4; ++r) {
            float v = alpha * acc[m][nn][r] + bv[nn];
            if (ACT == 1) v = LEAKY(v);
            const long off = g.coff +
                             (long)(m0 + wr + m * 16 + rrow + r) * ldc + n0 +
                             wc + nn * 16 + rl;
            ((unsigned short*)Cv)[off] = f2b(v);
          }
    }
  } else if (CMODE == 3) {
#pragma unroll
    for (int m = 0; m < 4; ++m)
#pragma unroll
      for (int nn = 0; nn < 4; ++nn) {
        const int row = m0 + wr + m * 16 + rrow;
        const int col = n0 + wc + nn * 16 + rl;
        us4 o;
#pragma unroll
        for (int r = 0; r < 4; ++r) {
          float v = alpha * acc[m][nn][r] + bv[nn];
          if (ACT == 1) v = LEAKY(v);
          o[r] = f2b(v);
        }
        *(us4*)&((unsigned short*)Cv)[g.coff + (long)col * ldc + row] = o;
      }
  } else {
#pragma unroll
    for (int m = 0; m < 4; ++m)
#pragma unroll
      for (int nn = 0; nn < 4; ++nn)
#pragma unroll
        for (int r = 0; r < 4; ++r) {
          float v = alpha * acc[m][nn][r] + bv[nn];
          if (ACT == 1) v = LEAKY(v);
          long off = g.coff + (long)s * sC2 +
                     (long)(m0 + wr + m * 16 + rrow + r) * ldc + n0 + wc +
                     nn * 16 + rl;
          if (CMODE == 1)
            ((unsigned short*)Cv)[off] = f2b(v);
          else
            ((float*)Cv)[off] = v;
        }
  }
}

// ---------------------------------------------------------------------------
// Fused BatchNorm on h^T (512 features x 16384 samples), bf16, in-place.
// ---------------------------------------------------------------------------
__global__ __launch_bounds__(256) void bn_fused(
    unsigned short* __restrict__ X,
    const float* __restrict__ g1, const float* __restrict__ be1,
    const float* __restrict__ g2, const float* __restrict__ be2) {
  const int f = blockIdx.x;
  const int z = blockIdx.z;
  unsigned short* p = X + (long)z * (8L << 20) + (long)f * 16384;
  const int tid = threadIdx.x;
  us4 v[16];
  float s = 0.f, q = 0.f;
#pragma unroll
  for (int k = 0; k < 16; ++k) {
    v[k] = *(const us4*)&p[(k * 256 + tid) * 4];
#pragma unroll
    for (int j = 0; j < 4; ++j) {
      const float x = b2f(v[k][j]);
      s += x; q += x * x;
    }
  }
#pragma unroll
  for (int mask = 1; mask < 64; mask <<= 1) {
    s += __shfl_xor(s, mask, 64);
    q += __shfl_xor(q, mask, 64);
  }
  __shared__ float rs[8];
  const int wv = tid >> 6;
  if ((tid & 63) == 0) { rs[wv] = s; rs[4 + wv] = q; }
  __syncthreads();
  s = rs[0] + rs[1] + rs[2] + rs[3];
  q = rs[4] + rs[5] + rs[6] + rs[7];
  const float mu = s * (1.f / 16384.f);
  const float var = q * (1.f / 16384.f) - mu * mu;
  const float gg = (z ? g2 : g1)[f];
  const float bb0 = (z ? be2 : be1)[f];
  const float rstd = rsqrtf(var + 1e-5f) * gg;
  const float bb = bb0 - mu * rstd;
#pragma unroll
  for (int k = 0; k < 16; ++k) {
    us4 o;
#pragma unroll
    for (int j = 0; j < 4; ++j) {
      const float y = b2f(v[k][j]) * rstd + bb;
      o[j] = f2b(LEAKY(y));
    }
    *(us4*)&p[(k * 256 + tid) * 4] = o;
  }
}

// ---------------------------------------------------------------------------
// bf16 MFMA flash attention, both attentions in one dispatch (z = 8).
// NO-MAX softmax (Q pre-scaled to log2 domain); Q fragments hoisted to regs.
// ---------------------------------------------------------------------------
__global__ __launch_bounds__(256) void attn_mfma(
    const unsigned short* __restrict__ Q, const unsigned short* __restrict__ K,
    const unsigned short* __restrict__ Vt, unsigned short* __restrict__ O) {
  const int qb = blockIdx.x, h = blockIdx.y;
  const int n = blockIdx.z & 3, sel = blockIdx.z >> 2;
  Q += (long)sel * 4194304;
  K += (long)sel * 4194304;
  Vt += (long)sel * 2097152;
  O += (long)sel * 2097152;
  const int tid = threadIdx.x;
  const int lane = tid & 63, w = tid >> 6;
  const int rl = lane & 15, lg = lane >> 4;
  __shared__ unsigned short Qs[4096];
  __shared__ unsigned short Ks[4096];
  __shared__ unsigned short Vs[4096];
  __shared__ unsigned short Ps[4096];
  stage64(Q + ((long)n * 1024 + qb * 64) * 512 + h * 64, 512, Qs, lane, w);
  __syncthreads();
  const int q = w * 16 + rl;
  const short8b qr0 = ldsw(Qs, q, lg);
  const short8b qr1 = ldsw(Qs, q, 4 + lg);
  float l_r = 0.f;
  f32x4 po[4];
#pragma unroll
  for (int i = 0; i < 4; ++i) po[i] = (f32x4){0.f, 0.f, 0.f, 0.f};
  const unsigned short* Kg0 = K + ((long)n * 1024) * 512 + h * 64;
  const unsigned short* Vg0 = Vt + (long)n * 524288 + (long)(h * 64) * 1024;
  for (int kt = 0; kt < 16; ++kt) {
    __syncthreads();
    stage64(Kg0 + (long)(kt * 64) * 512, 512, Ks, lane, w);
    stage64(Vg0 + kt * 64, 1024, Vs, lane, w);
    __syncthreads();
    f32x4 sa[4];
#pragma unroll
    for (int i = 0; i < 4; ++i) sa[i] = (f32x4){0.f, 0.f, 0.f, 0.f};
#pragma unroll
    for (int kk = 0; kk < 2; ++kk) {
      const short8b qf = kk ? qr1 : qr0;
#pragma unroll
      for (int mt = 0; mt < 4; ++mt) {
        const short8b kf = ldsw(Ks, mt * 16 + rl, 4 * kk + lg);
        sa[mt] = __builtin_amdgcn_mfma_f32_16x16x32_bf16(kf, qf, sa[mt], 0, 0, 0);
      }
    }
    float ps = 0.f;
#pragma unroll
    for (int mt = 0; mt < 4; ++mt) {
      us4 o;
#pragma unroll
      for (int r = 0; r < 4; ++r) {
        const float p = exp2f(sa[mt][r]);
        ps += p;
        o[r] = f2b(p);
      }
      const int c16 = (4 * mt + lg) >> 1;
      *(us4*)&Ps[q * 64 + ((c16 ^ (q & 7)) << 3) + ((lg & 1) << 2)] = o;
    }
    ps += __shfl_xor(ps, 16, 64);
    ps += __shfl_xor(ps, 32, 64);
    l_r += ps;
#pragma unroll
    for (int kk = 0; kk < 2; ++kk) {
      const short8b pf = ldsw(Ps, q, 4 * kk + lg);
#pragma unroll
      for (int nt = 0; nt < 4; ++nt) {
        const short8b vf = ldsw(Vs, nt * 16 + rl, 4 * kk + lg);
        po[nt] = __builtin_amdgcn_mfma_f32_16x16x32_bf16(pf, vf, po[nt], 0, 0, 0);
      }
    }
  }
  float invr[4];
#pragma unroll
  for (int r = 0; r < 4; ++r) invr[r] = 1.f / __shfl(l_r, lg * 4 + r, 64);
  const long ob = ((long)n * 1024 + qb * 64 + w * 16) * 512 + h * 64;
#pragma unroll
  for (int nt = 0; nt < 4; ++nt)
#pragma unroll
    for (int r = 0; r < 4; ++r)
      O[ob + (long)(lg * 4 + r) * 512 + nt * 16 + rl] = f2b(po[nt][r] * invr[r]);
}

// ---------------------------------------------------------------------------
// Softmax pass 1: per-row max & 1/sum, plus column sums of softmax(A).
// ---------------------------------------------------------------------------
__global__ __launch_bounds__(256) void softmax_cs(const float* __restrict__ D,
                                                  float* __restrict__ RS,
                                                  float* __restrict__ CS) {
  __shared__ float colacc[2048];
  __shared__ float red[8];
  const int tid = threadIdx.x;
  const int wv = tid >> 6, ln = tid & 63;
#pragma unroll
  for (int k = 0; k < 8; ++k) colacc[tid + k * 256] = 0.f;
  __syncthreads();
  const int r0 = blockIdx.x * 8;
  const int n = r0 >> 11;
  for (int rr = 0; rr < 8; ++rr) {
    const float* p = D + (long)(r0 + rr) * 2048;
    float v[8];
    float mx = -1e30f;
#pragma unroll
    for (int k = 0; k < 8; ++k) {
      v[k] = p[tid + k * 256];
      mx = fmaxf(mx, v[k]);
    }
#pragma unroll
    for (int mask = 1; mask < 64; mask <<= 1) mx = fmaxf(mx, __shfl_xor(mx, mask, 64));
    if (ln == 0) red[wv] = mx;
    __syncthreads();
    mx = fmaxf(fmaxf(red[0], red[1]), fmaxf(red[2], red[3]));
    float sum = 0.f;
#pragma unroll
    for (int k = 0; k < 8; ++k) {
      v[k] = __expf(v[k] - mx);
      sum += v[k];
    }
#pragma unroll
    for (int mask = 1; mask < 64; mask <<= 1) sum += __shfl_xor(sum, mask, 64);
    if (ln == 0) red[4 + wv] = sum;
    __syncthreads();
    sum = red[4] + red[5] + red[6] + red[7];
    const float inv = 1.f / sum;
    if (tid == 0) {
      RS[(r0 + rr) * 2] = mx;
      RS[(r0 + rr) * 2 + 1] = inv;
    }
#pragma unroll
    for (int k = 0; k < 8; ++k) colacc[tid + k * 256] += v[k] * inv;
    __syncthreads();
  }
#pragma unroll
  for (int k = 0; k < 8; ++k)
    atomicAdd(&CS[n * 2048 + tid + k * 256], colacc[tid + k * 256]);
}

// Pass 2: recompute softmax from logits + row stats, apply column normalize.
__global__ __launch_bounds__(256) void final_scale(float* __restrict__ D,
                                                   const float* __restrict__ RS,
                                                   const float* __restrict__ CS) {
  const long i = ((long)blockIdx.x * 256 + threadIdx.x) * 4;
  const long row = i >> 11;
  const int n = (int)(row >> 11);
  const int j = (int)(i & 2047);
  const float mx = RS[row * 2];
  const float inv = RS[row * 2 + 1];
  float4 v = *(float4*)&D[i];
  const float* c = &CS[n * 2048 + j];
  v.x = __expf(v.x - mx) * inv * (c[0] > 0.f ? 1.f / c[0] : 0.f);
  v.y = __expf(v.y - mx) * inv * (c[1] > 0.f ? 1.f / c[1] : 0.f);
  v.z = __expf(v.z - mx) * inv * (c[2] > 0.f ? 1.f / c[2] : 0.f);
  v.w = __expf(v.w - mx) * inv * (c[3] > 0.f ? 1.f / c[3] : 0.f);
  *(float4*)&D[i] = v;
}

// ---------------------------------------------------------------------------
extern "C" void kernel_launch(void* const* d_in, const int* in_sizes, int n_in,
                              void* d_out, int out_size, void* d_ws,
                              size_t ws_size, hipStream_t stream) {
  const float* x1 = (const float*)d_in[0];
  const float* x2 = (const float*)d_in[1];
  const float* enc1 = (const float*)d_in[2];
  const float* enc2 = (const float*)d_in[3];
  const float* mlp_b1 = (const float*)d_in[5];
  const float* mlp_b2 = (const float*)d_in[7];
  const float* mlp_g = (const float*)d_in[8];
  const float* mlp_be = (const float*)d_in[9];
  const float* nlp_b1 = (const float*)d_in[11];
  const float* nlp_b2 = (const float*)d_in[13];
  const float* nlp_g = (const float*)d_in[14];
  const float* nlp_be = (const float*)d_in[15];
  float* out = (float*)d_out;

  unsigned short* W = (unsigned short*)d_ws;
  const long M1 = 1L << 20;
  const long S = 262144;
  const float K2 = 0.18033688f;  // 0.125 * log2(e)
  // Rolling layout (us units), lifetimes disjoint-in-time (R6 audit + R9):
  //  0.. 2M : Pt                               [dead after node_enc]
  //  4..12M : ENC -> E1/E2 (4..8M) -> A1P/A2P (8..12M)
  // 12..16M : E1T                              [dead after edge decode]
  // 16..19M : WT                               [dead after fc]
  // 20..36M : NE -> H1T/H2T                    [dead after edge decode]
  // 36..52M : Sprep (32MB) -> MID (lin1) -> edge bf16 partials (16M us)
  //           -> QKQK (36..44M), V^T (44..48M), AO (48..52M)
  unsigned short* Pt = W;
  unsigned short* ENC = W + 4 * M1;
  unsigned short* E1T = W + 12 * M1;
  unsigned short* WT = W + 16 * M1;
  unsigned short* NE = W + 20 * M1;
  unsigned short* H1T = W + 20 * M1;
  unsigned short* MID = W + 36 * M1;
  float* Sprep = (float*)(W + 36 * M1);
  unsigned short* PB = W + 36 * M1;   // edge bf16 split-K partials (16M us)
  unsigned short* E1 = W + 4 * M1;
  unsigned short* E2 = W + 6 * M1;
  unsigned short* QKV = W + 36 * M1;
  unsigned short* VT = W + 44 * M1;
  unsigned short* AO = W + 48 * M1;
  unsigned short* A1P = W + 8 * M1;
  unsigned short* A2P = W + 10 * M1;
  float* ST = (float*)(W + 56 * M1);
  float* CS = ST + 2048;
  float* RS = CS + 8192;

  const dim3 T(256);
  const long sP = 262144;
  const long sNE = 2097152;
  const long sE = 524288;
  const long sD = 4194304;

  // --- fused prologue (prep stage A + enc convert + enc^T + weights^T) ---
  WPtrs wp;
  wp.p[0] = (const float*)d_in[4];   wp.sc[0] = 1.f;   // mlp_w1
  wp.p[1] = (const float*)d_in[6];   wp.sc[1] = 1.f;   // mlp_w2
  wp.p[2] = (const float*)d_in[10];  wp.sc[2] = 1.f;   // nlp_w1
  wp.p[3] = (const float*)d_in[12];  wp.sc[3] = 1.f;   // nlp_w2
  wp.p[4] = (const float*)d_in[16];  wp.sc[4] = K2;    // a1_wq (log2-scaled)
  wp.p[5] = (const float*)d_in[18];  wp.sc[5] = 1.f;   // a1_wk
  wp.p[6] = (const float*)d_in[24];  wp.sc[6] = K2;    // a2_wq (log2-scaled)
  wp.p[7] = (const float*)d_in[26];  wp.sc[7] = 1.f;   // a2_wk
  wp.p[8] = (const float*)d_in[20];  wp.sc[8] = 1.f;   // a1_wv
  wp.p[9] = (const float*)d_in[28];  wp.sc[9] = 1.f;   // a2_wv
  wp.p[10] = (const float*)d_in[22]; wp.sc[10] = 1.f;  // a1_fc
  wp.p[11] = (const float*)d_in[30]; wp.sc[11] = 1.f;  // a2_fc
  prologue_misc<<<18176, T, 0, stream>>>(x1, x2, Sprep, enc1, enc2, ENC, E1T,
                                         wp, WT);
  prep_finish<<<dim3(64, 4, 8), T, 0, stream>>>(Sprep, Pt);

  // --- node_enc for BOTH branches: z=16 (inp x pr x n) -> NE ---
  {
    GDescs g{};
    for (int inp = 0; inp < 2; ++inp)
      for (int pr = 0; pr < 2; ++pr)
        for (int nn = 0; nn < 4; ++nn)
          g.d[inp * 8 + pr * 4 + nn] = {
              ENC + (long)pr * (4 * M1), Pt + (long)inp * M1 + nn * sP,
              (long)inp * (8 * M1) + (long)nn * sNE + pr * 256, nullptr, 0, 1.f};
    gemm_z<0, 1, 1><<<dim3(2, 32, 16), T, 0, stream>>>(g, NE, 1024, 1024,
                                                       1024, 512, 0, 1.f);
  }
  // --- lin1 both branches (z=2) -> MID ---
  {
    GDescs g{};
    g.d[0] = {NE, WT + 0 * S, 0, mlp_b1, 0, 1.f};
    g.d[1] = {NE + 8 * M1, WT + 2 * S, 8 * M1, nlp_b1, 0, 1.f};
    gemm_z<1, 1, 1><<<dim3(4, 128, 2), T, 0, stream>>>(g, MID, 512, 512, 512,
                                                       512, 0, 1.f);
  }
  // --- lin2^T both branches (z=2) -> H1T/H2T (over NE, dead) ---
  {
    GDescs g{};
    g.d[0] = {MID, WT + 1 * S, 0, mlp_b2, 0, 1.f};
    g.d[1] = {MID + 8 * M1, WT + 3 * S, 8 * M1, nlp_b2, 0, 1.f};
    gemm_z<0, 3, 1><<<dim3(4, 128, 2), T, 0, stream>>>(g, H1T, 512, 512, 512,
                                                       16384, 0, 1.f);
  }
  bn_fused<<<dim3(512, 1, 2), T, 0, stream>>>(H1T, mlp_g, mlp_be, nlp_g, nlp_be);

  // --- edge decode: z = 8 descs x split-K 4, bf16 partials in MID region ---
  {
    GDescs g{};
    for (int d = 0; d < 8; ++d)
      g.d[d] = {E1T, H1T + (long)(d >> 2) * (8 * M1) + (d & 3) * 4096,
                (long)d * 524288, nullptr, 0, 1.f};
    gemm_z<0, 1, 4><<<dim3(4, 8, 32), T, 0, stream>>>(g, PB, 1024, 4096,
                                                      16384, 512, 4194304,
                                                      1.f / 1024.f);
  }
  addcvt4<<<4096, T, 0, stream>>>(PB, E1);

  // --- projections: Q1,K1,Q2,K2,V1,V2 in ONE dispatch (z=6, per-desc mode).
  //     Q weights/biases pre-scaled to log2 domain (bscale=K2). ---
  {
    GDescs g{};
    g.d[0] = {E2, WT + 4 * S, 0, (const float*)d_in[17], 1, K2};
    g.d[1] = {E1, WT + 5 * S, 2 * M1, (const float*)d_in[19], 1, 1.f};
    g.d[2] = {E1, WT + 6 * S, 4 * M1, (const float*)d_in[25], 1, K2};
    g.d[3] = {E2, WT + 7 * S, 6 * M1, (const float*)d_in[27], 1, 1.f};
    g.d[4] = {E1, WT + 8 * S, 8 * M1, (const float*)d_in[21], 2, 1.f};
    g.d[5] = {E2, WT + 9 * S, 10 * M1, (const float*)d_in[29], 2, 1.f};
    gemm_z<0, 4, 1><<<dim3(4, 32, 6), T, 0, stream>>>(g, QKV, 512, 512, 512,
                                                      512, 0, 1.f);
  }

  // --- both attentions ---
  attn_mfma<<<dim3(16, 8, 8), T, 0, stream>>>(QKV, QKV + 2 * M1, VT, AO);

  // --- fc for both attentions -> A1P/A2P ---
  {
    GDescs g{};
    g.d[0] = {AO, WT + 10 * S, 0, (const float*)d_in[23], 0, 1.f};
    g.d[1] = {AO + 2 * M1, WT + 11 * S, 2 * M1, (const float*)d_in[31], 0, 1.f};
    gemm_z<0, 1, 1><<<dim3(4, 32, 2), T, 0, stream>>>(g, A1P, 512, 512, 512,
                                                      512, 0, 1.f);
  }

  // --- logits: all 4 quadrants x 4 n in one dispatch (z=16) ---
  {
    GDescs g{};
    for (int q = 0; q < 4; ++q)
      for (int n = 0; n < 4; ++n) {
        const unsigned short* A = (q < 2 ? A1P : A2P) + n * sE;
        const unsigned short* B = ((q == 0 || q == 2) ? A2P : A1P) + n * sE;
        const long coff =
            (long)n * sD + (q & 1) * 1024 + (long)(q >> 1) * 2097152;
        g.d[q * 4 + n] = {A, B, coff, nullptr, 0, 1.f};
      }
    gemm_z<0, 0, 1><<<dim3(8, 8, 16), T, 0, stream>>>(g, out, 512, 512, 512,
                                                      2048, 0, 1.f);
  }

  // --- softmax + column normalization (2 passes, no middle write) ---
  hipMemsetAsync(CS, 0, 8192 * sizeof(float), stream);
  softmax_cs<<<1024, T, 0, stream>>>(out, RS, CS);
  final_scale<<<16384, T, 0, stream>>>(out, RS, CS);
}